// Round 2
// baseline (336.494 us; speedup 1.0000x reference)
//
#include <hip/hip_runtime.h>
#include <stdint.h>

// ---------------------------------------------------------------------------
// MoELatent: B=2048 D=1024 H=2048 E=16 W=4 R=8, top_k=2, cand_k=8
// ---------------------------------------------------------------------------
#define NTOK 2048
#define DDIM 1024
#define HDIM 2048
#define NEXP 16

// output (float) element offsets, in reference return order
#define O_PROBS 2097152   // [2048,16]
#define O_USED  2129920   // [2048,16]
#define O_AIDX  2162688   // [2048,2]
#define O_AW    2166784   // [2048,2]
#define O_HIT   2170880   // scalar
#define O_EVE   2170881   // [2,2048] slot-major
#define O_EVA   2174977   // [2,2048]

// workspace byte offsets — constexpr chain (round-1 bug: hand-typed literals
// under-sized cvals by 2048B, aliasing scores -> race; never hand-type these)
static constexpr size_t WS_ZBF    = 0;
static constexpr size_t WS_FC1WBF = WS_ZBF    + (size_t)NTOK * DDIM * 2;
static constexpr size_t WS_FC2WBF = WS_FC1WBF + (size_t)HDIM * DDIM * 2;
static constexpr size_t WS_HPREBF = WS_FC2WBF + (size_t)DDIM * HDIM * 2;
static constexpr size_t WS_OUTPRE = WS_HPREBF + (size_t)NTOK * HDIM * 2;
static constexpr size_t WS_A1BF   = WS_OUTPRE + (size_t)NTOK * DDIM * 4;
static constexpr size_t WS_B1BF   = WS_A1BF   + (size_t)16 * 4 * 8 * 1024 * 2;
static constexpr size_t WS_A2BF   = WS_B1BF   + (size_t)16 * 4 * 2048 * 8 * 2;
static constexpr size_t WS_B2BF   = WS_A2BF   + (size_t)16 * 4 * 8 * 2048 * 2;
static constexpr size_t WS_CANDS  = WS_B2BF   + (size_t)16 * 4 * 1024 * 8 * 2;
static constexpr size_t WS_CVALS  = WS_CANDS  + (size_t)NTOK * 4;
static constexpr size_t WS_SCORES = WS_CVALS  + (size_t)NTOK * 8 * 4;
static constexpr size_t WS_ASGN   = WS_SCORES + (size_t)NTOK * 64 * 4;
static constexpr size_t WS_ASGNW  = WS_ASGN   + (size_t)NTOK * 2 * 4;

typedef __bf16 v8bf __attribute__((ext_vector_type(8)));
typedef float v4f __attribute__((ext_vector_type(4)));
typedef unsigned short us8v __attribute__((ext_vector_type(8)));

__device__ __forceinline__ unsigned short f2bf(float f) {
  unsigned u = __float_as_uint(f);
  u = u + 0x7fffu + ((u >> 16) & 1u);          // round-to-nearest-even
  return (unsigned short)(u >> 16);
}
__device__ __forceinline__ float bf2f(unsigned short s) {
  return __uint_as_float(((unsigned)s) << 16);
}
__device__ __forceinline__ void gload_lds16(const void* g, void* l) {
  __builtin_amdgcn_global_load_lds(
      (const __attribute__((address_space(1))) void*)g,
      (__attribute__((address_space(3))) void*)l, 16, 0, 0);
}

// ---------------------------------------------------------------------------
// K1: router probs + top-8 candidates + adapter scores (all e,w) + z->bf16
// grid 256 blocks x 256 thr, 8 tokens/block
// ---------------------------------------------------------------------------
__global__ __launch_bounds__(256) void k1_probs_scores(
    const float* __restrict__ z, const float* __restrict__ proto,
    const float* __restrict__ ebias, const float* __restrict__ ak,
    const float* __restrict__ p_tau, const float* __restrict__ p_eps,
    const int* __restrict__ p_ban,
    unsigned short* __restrict__ zbf, float* __restrict__ out,
    unsigned* __restrict__ cands, float* __restrict__ cvals,
    float* __restrict__ scores)
{
  __shared__ float zs[8][DDIM];
  const int tid = threadIdx.x;
  const int tb = blockIdx.x * 8;
#pragma unroll
  for (int i = 0; i < 8; ++i) {
    const int col = tid * 4;
    float4 v = *(const float4*)&z[(size_t)(tb + i) * DDIM + col];
    *(float4*)&zs[i][col] = v;
    ushort4 bv;
    bv.x = f2bf(v.x); bv.y = f2bf(v.y); bv.z = f2bf(v.z); bv.w = f2bf(v.w);
    *(ushort4*)&zbf[(size_t)(tb + i) * DDIM + col] = bv;
  }
  __syncthreads();
  const int wv = tid >> 6, l = tid & 63;
  const float tau = fmaxf(p_tau[0], 1e-6f);
  const float eps = p_eps[0];
  const int ban = p_ban[0];

  for (int it = 0; it < 2; ++it) {
    const int trow = wv * 2 + it;
    const int t = tb + trow;
    float lg_mine = -3.0e38f;
    for (int e = 0; e < NEXP; ++e) {
      float s = 0.f;
#pragma unroll
      for (int i = 0; i < 16; ++i)
        s += zs[trow][l + 64 * i] * proto[(size_t)e * DDIM + l + 64 * i];
#pragma unroll
      for (int o = 32; o; o >>= 1) s += __shfl_xor(s, o, 64);
      float lg = s / tau + ebias[e];
      if (e == ban) lg = -1e9f;
      if (l == e) lg_mine = lg;
    }
    // softmax over lanes 0..15
    float v0 = (l < NEXP) ? lg_mine : -3.0e38f;
    float mx = v0;
#pragma unroll
    for (int o = 8; o; o >>= 1) mx = fmaxf(mx, __shfl_xor(mx, o, 64));
    float ex = (l < NEXP) ? expf(v0 - mx) : 0.f;
    float sm = ex;
#pragma unroll
    for (int o = 8; o; o >>= 1) sm += __shfl_xor(sm, o, 64);
    float p = (1.f - eps) * (ex / sm) + eps / (float)NEXP;
    if (l < NEXP) out[O_PROBS + (size_t)t * NEXP + l] = p;
    // top-8 selection, jax.lax.top_k tie-break: value desc, index asc
    float cur = (l < NEXP) ? p : -1.f;
    unsigned pack = 0;
    float myv = 0.f;
    for (int r = 0; r < 8; ++r) {
      float bv = cur; int bi = l;
#pragma unroll
      for (int o = 32; o; o >>= 1) {
        float ov = __shfl_xor(bv, o, 64);
        int oi = __shfl_xor(bi, o, 64);
        if (ov > bv || (ov == bv && oi < bi)) { bv = ov; bi = oi; }
      }
      pack |= ((unsigned)bi) << (4 * r);
      if (l == r) myv = bv;
      if (l == bi) cur = -1.f;
    }
    if (l == 0) cands[t] = pack;
    if (l < 8) cvals[(size_t)t * 8 + l] = myv;
  }
  // adapter scores z . ak[e][w] for ALL 64 (e,w) rows
  const int tok = tid >> 5, l32 = tid & 31;
  for (int r = 0; r < 64; ++r) {
    float s = 0.f;
#pragma unroll
    for (int i = 0; i < 32; ++i)
      s += zs[tok][l32 + 32 * i] * ak[(size_t)r * DDIM + l32 + 32 * i];
#pragma unroll
    for (int o = 16; o; o >>= 1) s += __shfl_xor(s, o, 64);
    if (l32 == 0) scores[(size_t)(tb + tok) * 64 + r] = s;
  }
}

// ---------------------------------------------------------------------------
// K2: block 0 = exact capacity routing (parallel speculative rounds);
//     blocks 1..CONVB = f32->bf16 weight conversions
// ---------------------------------------------------------------------------
#define CONVB 96

__device__ __forceinline__ void route_decide(unsigned c, int avail,
                                             unsigned& m, int& dec) {
  m = 0;
  int sc = 0, e0 = 0, e1 = 0, r0 = 0, r1 = 0;
#pragma unroll
  for (int j = 0; j < 8; ++j) {
    const int e = (c >> (4 * j)) & 15;
    const bool take = (((avail >> e) & 1) != 0) && (sc < 2);
    if (take) {
      if (sc == 0) { e0 = e; r0 = j; } else { e1 = e; r1 = j; }
      m |= 1u << e;
      ++sc;
    }
  }
  dec = e0 | (e1 << 4) | (r0 << 8) | (r1 << 11) | (sc << 14);
}

__device__ __forceinline__ void route_finalize(
    int t, int t0, int tfin, unsigned m, int dec,
    const float* __restrict__ cvals, const float* __restrict__ scores,
    float* __restrict__ out, int* __restrict__ asgn,
    float* __restrict__ asgnw, int& hits)
{
  if (t < t0 || t > tfin) return;
  const int e0 = dec & 15, e1 = (dec >> 4) & 15;
  const int r0 = (dec >> 8) & 7, r1 = (dec >> 11) & 7;
  const int sc = (dec >> 14) & 3;
  const int v0 = sc > 0, v1 = sc > 1;
  const float w0 = v0 ? cvals[(size_t)t * 8 + r0] : 0.f;
  const float w1 = v1 ? cvals[(size_t)t * 8 + r1] : 0.f;
  out[O_AIDX + (size_t)t * 2 + 0] = v0 ? (float)e0 : -1.f;
  out[O_AIDX + (size_t)t * 2 + 1] = v1 ? (float)e1 : -1.f;
  out[O_AW + (size_t)t * 2 + 0] = w0;
  out[O_AW + (size_t)t * 2 + 1] = w1;
  out[O_EVE + t] = v0 ? (float)e0 : -1.f;
  out[O_EVE + NTOK + t] = v1 ? (float)e1 : -1.f;
  // adapter argmax (first max on ties, like jnp.argmax)
  const float* s0 = &scores[(size_t)t * 64 + e0 * 4];
  float b0 = s0[0]; int a0 = 0;
#pragma unroll
  for (int q = 1; q < 4; ++q) if (s0[q] > b0) { b0 = s0[q]; a0 = q; }
  const float* s1 = &scores[(size_t)t * 64 + e1 * 4];
  float b1v = s1[0]; int a1i = 0;
#pragma unroll
  for (int q = 1; q < 4; ++q) if (s1[q] > b1v) { b1v = s1[q]; a1i = q; }
  out[O_EVA + t] = v0 ? (float)a0 : -1.f;
  out[O_EVA + NTOK + t] = v1 ? (float)a1i : -1.f;
#pragma unroll
  for (int e = 0; e < 16; ++e)
    out[O_USED + (size_t)t * 16 + e] = (float)((m >> e) & 1);
  asgn[t * 2 + 0] = v0 ? (e0 | (a0 << 8)) : -1;
  asgn[t * 2 + 1] = v1 ? (e1 | (a1i << 8)) : -1;
  asgnw[t * 2 + 0] = w0;
  asgnw[t * 2 + 1] = w1;
  hits += (v0 && r0 > 0) + (v1 && r1 > 0);
}

__global__ __launch_bounds__(1024) void k2_route_conv(
    const unsigned* __restrict__ cands, const float* __restrict__ cvals,
    const float* __restrict__ scores, const int* __restrict__ p_cap,
    float* __restrict__ out, int* __restrict__ asgn, float* __restrict__ asgnw,
    const float* __restrict__ fc1w, const float* __restrict__ fc2w,
    const float* __restrict__ a1, const float* __restrict__ b1,
    const float* __restrict__ a2, const float* __restrict__ b2,
    unsigned short* __restrict__ fc1wbf, unsigned short* __restrict__ fc2wbf,
    unsigned short* __restrict__ a1bf, unsigned short* __restrict__ b1bf,
    unsigned short* __restrict__ a2bf, unsigned short* __restrict__ b2bf)
{
  const int tid = threadIdx.x;
  if (blockIdx.x != 0) {
    // weight conversions, float4-granular grid-stride over 1835008 float4s
    size_t j = (size_t)(blockIdx.x - 1) * 1024 + tid;
    const size_t stride = (size_t)CONVB * 1024;
    for (; j < 1835008ull; j += stride) {
      const float* src; unsigned short* dst; size_t off;
      if (j < 524288) { src = fc1w; dst = fc1wbf; off = j; }
      else if (j < 1048576) { src = fc2w; dst = fc2wbf; off = j - 524288; }
      else if (j < 1179648) { src = a1; dst = a1bf; off = j - 1048576; }
      else if (j < 1441792) { src = b1; dst = b1bf; off = j - 1179648; }
      else if (j < 1703936) { src = a2; dst = a2bf; off = j - 1441792; }
      else { src = b2; dst = b2bf; off = j - 1703936; }
      float4 v = *(const float4*)&src[off * 4];
      ushort4 bv;
      bv.x = f2bf(v.x); bv.y = f2bf(v.y); bv.z = f2bf(v.z); bv.w = f2bf(v.w);
      *(ushort4*)&dst[off * 4] = bv;
    }
    return;
  }
  // ---- routing: greedy order-dependent, exact via crossing-rounds ----
  __shared__ unsigned sh_cands[NTOK];
  __shared__ unsigned long long sh_bal[2][16 * 16];  // [half][chunk*16+e]
  __shared__ int sh_cap[16], sh_T[16];
  __shared__ int sh_avail, sh_t0, sh_tfin, sh_done, sh_hits;
  const int wv = tid >> 6, l = tid & 63;
  sh_cands[tid] = cands[tid];
  sh_cands[tid + 1024] = cands[tid + 1024];
  if (tid == 0) { sh_avail = 0xFFFF; sh_t0 = 0; sh_done = 0; sh_hits = 0; }
  if (tid < 16) sh_cap[tid] = 0;
  const int capl = max(1, p_cap[0]);
  int hits = 0;
  __syncthreads();
  const int tA = tid, tB = tid + 1024;        // wave w <-> tokens [w*64,w*64+64)
  const unsigned cA = sh_cands[tA], cB = sh_cands[tB];

  for (int round = 0; round < 48; ++round) {
    const int t0 = sh_t0;
    const int avail = sh_avail;
    unsigned mA = 0, mB = 0;
    int dA = 0, dB = 0;
    if (tA >= t0) route_decide(cA, avail, mA, dA);
    if (tB >= t0) route_decide(cB, avail, mB, dB);
    // per-expert take ballots (bit <-> token within 64-token chunk)
    unsigned long long keep0 = 0, keep1 = 0;
    for (int e = 0; e < 16; ++e) {
      unsigned long long ba = __ballot((mA >> e) & 1);
      unsigned long long bb = __ballot((mB >> e) & 1);
      if (l == e) { keep0 = ba; keep1 = bb; }
    }
    if (l < 16) { sh_bal[0][wv * 16 + l] = keep0; sh_bal[1][wv * 16 + l] = keep1; }
    __syncthreads();
    // wave e finds its capacity-crossing token T_e
    const int e = wv;
    unsigned long long bm = 0;
    int cnt = 0;
    if (l < 32) {
      bm = sh_bal[l >> 4][(l & 15) * 16 + e];
      cnt = __popcll(bm);
    }
    int incl = cnt;
#pragma unroll
    for (int o = 1; o < 64; o <<= 1) {
      int u = __shfl_up(incl, o, 64);
      if (l >= o) incl += u;
    }
    int myT = 0x7FFFFFFF;
    if (l < 32 && ((avail >> e) & 1)) {
      const int need = (capl - sh_cap[e]) - (incl - cnt);
      if (need >= 1 && need <= cnt) {
        unsigned long long bb = bm;
        for (int i = 1; i < need; ++i) bb &= bb - 1;
        myT = ((l >> 4) ? 1024 : 0) + (l & 15) * 64 +
              (__ffsll((unsigned long long)bb) - 1);
      }
    }
#pragma unroll
    for (int o = 32; o; o >>= 1) myT = min(myT, __shfl_xor(myT, o, 64));
    if (l == 0) sh_T[e] = myT;
    __syncthreads();
    if (wv == 0) {
      int v = (l < 16) ? sh_T[l] : 0x7FFFFFFF;
      int ts = v;
#pragma unroll
      for (int o = 32; o; o >>= 1) ts = min(ts, __shfl_xor(ts, o, 64));
      const int done = (ts == 0x7FFFFFFF);
      const int tf = done ? (NTOK - 1) : ts;
      if (l == 0) { sh_tfin = tf; sh_done = done; sh_t0 = tf + 1; }
      if (l < 16 && v == ts) atomicAnd(&sh_avail, ~(1 << l));
    }
    __syncthreads();
    const int tfin = sh_tfin;
    {   // cap[e] += takes in [t0, tfin]
      int c2 = 0;
      if (l < 32) {
        const int base = ((l >> 4) ? 1024 : 0) + (l & 15) * 64;
        const int hi = tfin - base;
        unsigned long long mk =
            (hi < 0) ? 0ull : (hi >= 63 ? ~0ull : ((1ull << (hi + 1)) - 1ull));
        c2 = __popcll(bm & mk);
      }
#pragma unroll
      for (int o = 32; o; o >>= 1) c2 += __shfl_xor(c2, o, 64);
      if (l == 0) sh_cap[e] += c2;
    }
    route_finalize(tA, t0, tfin, mA, dA, cvals, scores, out, asgn, asgnw, hits);
    route_finalize(tB, t0, tfin, mB, dB, cvals, scores, out, asgn, asgnw, hits);
    __syncthreads();
    if (sh_done || sh_t0 >= NTOK) break;
  }
#pragma unroll
  for (int o = 32; o; o >>= 1) hits += __shfl_xor(hits, o, 64);
  if (l == 0) atomicAdd(&sh_hits, hits);
  __syncthreads();
  if (tid == 0) out[O_HIT] = (float)sh_hits / (float)(NTOK * 2);
}

// ---------------------------------------------------------------------------
// bf16 GEMM C = A[M,K] * B[N,K]^T, 128x128 tile, BK=64, 4 waves,
// mfma_f32_16x16x32_bf16, global_load_lds width 16 (m97 structure).
// EPI 0: silu(x+bias) -> bf16 store. EPI 1: x+bias -> f32 store.
// ---------------------------------------------------------------------------
template <int EPI>
__global__ __launch_bounds__(256) void gemm_bt(
    const unsigned short* __restrict__ A, const unsigned short* __restrict__ Bm,
    const float* __restrict__ bias, void* __restrict__ Cout,
    int M, int N, int K)
{
  __shared__ unsigned short As[128 * 64];
  __shared__ unsigned short Bs[128 * 64];
  const int tid = threadIdx.x;
  const int wv = tid >> 6, l = tid & 63;
  const int ntile = N >> 7;
  const int trow = (blockIdx.x / ntile) << 7;
  const int tcol = (blockIdx.x % ntile) << 7;
  const int wr = wv >> 1, wc = wv & 1;
  v4f acc[4][4];
#pragma unroll
  for (int m = 0; m < 4; ++m)
#pragma unroll
    for (int n = 0; n < 4; ++n) acc[m][n] = (v4f){0.f, 0.f, 0.f, 0.f};

  const int lrow8 = l >> 3;
  const int lcol8 = (l & 7) << 3;
  const unsigned short* gA = A + (size_t)trow * K;
  const unsigned short* gB = Bm + (size_t)tcol * K;
  const int fr = l & 15, kof = (l >> 4) << 3;

  for (int k0 = 0; k0 < K; k0 += 64) {
    __syncthreads();
#pragma unroll
    for (int i = 0; i < 4; ++i) {
      const int s = (wv << 2) + i;  // segment 0..15 = 8 rows each
      gload_lds16(gA + (size_t)(s * 8 + lrow8) * K + k0 + lcol8, &As[s * 512]);
      gload_lds16(gB + (size_t)(s * 8 + lrow8) * K + k0 + lcol8, &Bs[s * 512]);
    }
    __syncthreads();
    v8bf af[4][2], bf[4][2];
#pragma unroll
    for (int m = 0; m < 4; ++m) {
      const int row = wr * 64 + m * 16 + fr;
      af[m][0] = *(const v8bf*)&As[row * 64 + kof];
      af[m][1] = *(const v8bf*)&As[row * 64 + 32 + kof];
    }
#pragma unroll
    for (int n = 0; n < 4; ++n) {
      const int row = wc * 64 + n * 16 + fr;
      bf[n][0] = *(const v8bf*)&Bs[row * 64 + kof];
      bf[n][1] = *(const v8bf*)&Bs[row * 64 + 32 + kof];
    }
#pragma unroll
    for (int ks = 0; ks < 2; ++ks)
#pragma unroll
      for (int m = 0; m < 4; ++m)
#pragma unroll
        for (int n = 0; n < 4; ++n)
          acc[m][n] = __builtin_amdgcn_mfma_f32_16x16x32_bf16(
              af[m][ks], bf[n][ks], acc[m][n], 0, 0, 0);
  }
  // epilogue: C/D layout col=lane&15, row=(lane>>4)*4+j  [m89/m91]
  const int fq = l >> 4;
#pragma unroll
  for (int m = 0; m < 4; ++m)
#pragma unroll
    for (int n = 0; n < 4; ++n) {
      const int col = tcol + wc * 64 + n * 16 + fr;
      const float bc = bias[col];
#pragma unroll
      for (int j = 0; j < 4; ++j) {
        const int row = trow + wr * 64 + m * 16 + fq * 4 + j;
        const float v = acc[m][n][j] + bc;
        if (EPI == 0) {
          const float sv = v / (1.f + __expf(-v));
          ((unsigned short*)Cout)[(size_t)row * N + col] = f2bf(sv);
        } else {
          ((float*)Cout)[(size_t)row * N + col] = v;
        }
      }
    }
}

// ---------------------------------------------------------------------------
// K5: per-token LoRA adapters + final combine
// out0 = z + sum_s w_s * (out_pre + B2(A2 silu(h_pre + B1(A1 z))))
// one block (256 thr) per token, both slots
// ---------------------------------------------------------------------------
__global__ __launch_bounds__(256) void k5_lora(
    const float* __restrict__ z, const unsigned short* __restrict__ hpre,
    const float* __restrict__ outpre, const int* __restrict__ asgn,
    const float* __restrict__ asgnw,
    const unsigned short* __restrict__ a1, const unsigned short* __restrict__ b1,
    const unsigned short* __restrict__ a2, const unsigned short* __restrict__ b2,
    float* __restrict__ out0)
{
  __shared__ float zl[DDIM];
  __shared__ float hl[HDIM];
  __shared__ float t1s[8], t2s[8];
  const int b = blockIdx.x, tid = threadIdx.x;
  {
    float4 v = *(const float4*)&z[(size_t)b * DDIM + tid * 4];
    *(float4*)&zl[tid * 4] = v;
  }
  float acc[4] = {0.f, 0.f, 0.f, 0.f};
  float wsum = 0.f;
  const int r = tid >> 5, l5 = tid & 31;
  __syncthreads();

  for (int s = 0; s < 2; ++s) {
    const int p = asgn[b * 2 + s];
    if (p < 0) continue;  // uniform across block
    const float ww = asgnw[b * 2 + s];
    wsum += ww;
    const int ad = (p & 255) * 4 + ((p >> 8) & 255);
    // t1[r] = z . a1[ad][r][:]
    {
      const unsigned short* pa1 = a1 + ((size_t)ad * 8 + r) * DDIM;
      float sa = 0.f;
      for (int i = 0; i < 32; ++i) sa += zl[l5 + 32 * i] * bf2f(pa1[l5 + 32 * i]);
#pragma unroll
      for (int o = 16; o; o >>= 1) sa += __shfl_xor(sa, o, 64);
      if (l5 == 0) t1s[r] = sa;
    }
    __syncthreads();
    // d1 + h = silu(h_pre + d1)
    {
      float t1r[8];
#pragma unroll
      for (int q = 0; q < 8; ++q) t1r[q] = t1s[q];
      const unsigned short* pb1 = b1 + (size_t)ad * HDIM * 8;
      const unsigned short* ph = hpre + (size_t)b * HDIM;
#pragma unroll
      for (int j = 0; j < 8; ++j) {
        const int h = tid + 256 * j;
        us8v row = *(const us8v*)&pb1[(size_t)h * 8];
        float d1 = 0.f;
#pragma unroll
        for (int q = 0; q < 8; ++q) d1 += t1r[q] * bf2f(row[q]);
        const float hh = bf2f(ph[h]) + d1;  // SCALE = 1
        hl[h] = hh / (1.f + __expf(-hh));
      }
    }
    __syncthreads();
    // t2[r] = h . a2[ad][r][:]
    {
      const unsigned short* pa2 = a2 + ((size_t)ad * 8 + r) * HDIM;
      float sa = 0.f;
      for (int i = 0; i < 64; ++i) sa += hl[l5 + 32 * i] * bf2f(pa2[l5 + 32 * i]);
#pragma unroll
      for (int o = 16; o; o >>= 1) sa += __shfl_xor(sa, o, 64);
      if (l5 == 0) t2s[r] = sa;
    }
    __syncthreads();
    // d2 accumulate
    {
      float t2r[8];
#pragma unroll
      for (int q = 0; q < 8; ++q) t2r[q] = t2s[q];
      const unsigned short* pb2 = b2 + (size_t)ad * DDIM * 8;
#pragma unroll
      for (int j = 0; j < 4; ++j) {
        const int d = tid + 256 * j;
        us8v row = *(const us8v*)&pb2[(size_t)d * 8];
        float d2 = 0.f;
#pragma unroll
        for (int q = 0; q < 8; ++q) d2 += t2r[q] * bf2f(row[q]);
        acc[j] += ww * d2;  // SCALE = 1
      }
    }
    __syncthreads();  // protect t1s/hl/t2s before next slot
  }
#pragma unroll
  for (int j = 0; j < 4; ++j) {
    const int d = tid + 256 * j;
    out0[(size_t)b * DDIM + d] =
        zl[d] + wsum * outpre[(size_t)b * DDIM + d] + acc[j];
  }
}

// ---------------------------------------------------------------------------
extern "C" void kernel_launch(void* const* d_in, const int* in_sizes, int n_in,
                              void* d_out, int out_size, void* d_ws, size_t ws_size,
                              hipStream_t stream)
{
  (void)in_sizes; (void)n_in; (void)out_size; (void)ws_size;
  const float* z     = (const float*)d_in[0];
  const int*   p_cap = (const int*)d_in[2];
  const int*   p_ban = (const int*)d_in[3];
  const float* p_tau = (const float*)d_in[4];
  const float* p_eps = (const float*)d_in[5];
  const float* fc1w  = (const float*)d_in[6];
  const float* fc1b  = (const float*)d_in[7];
  const float* fc2w  = (const float*)d_in[8];
  const float* fc2b  = (const float*)d_in[9];
  const float* proto = (const float*)d_in[10];
  const float* ak    = (const float*)d_in[11];
  const float* ebias = (const float*)d_in[12];
  const float* a1    = (const float*)d_in[13];
  const float* b1    = (const float*)d_in[14];
  const float* a2    = (const float*)d_in[15];
  const float* b2    = (const float*)d_in[16];
  float* out = (float*)d_out;
  char* ws = (char*)d_ws;

  unsigned short* zbf    = (unsigned short*)(ws + WS_ZBF);
  unsigned short* fc1wbf = (unsigned short*)(ws + WS_FC1WBF);
  unsigned short* fc2wbf = (unsigned short*)(ws + WS_FC2WBF);
  unsigned short* hprebf = (unsigned short*)(ws + WS_HPREBF);
  float*          outpre = (float*)(ws + WS_OUTPRE);
  unsigned short* a1bf   = (unsigned short*)(ws + WS_A1BF);
  unsigned short* b1bf   = (unsigned short*)(ws + WS_B1BF);
  unsigned short* a2bf   = (unsigned short*)(ws + WS_A2BF);
  unsigned short* b2bf   = (unsigned short*)(ws + WS_B2BF);
  unsigned*       cands  = (unsigned*)(ws + WS_CANDS);
  float*          cvals  = (float*)(ws + WS_CVALS);
  float*          scores = (float*)(ws + WS_SCORES);
  int*            asgn   = (int*)(ws + WS_ASGN);
  float*          asgnw  = (float*)(ws + WS_ASGNW);

  k1_probs_scores<<<256, 256, 0, stream>>>(
      z, proto, ebias, ak, p_tau, p_eps, p_ban, zbf, out, cands, cvals, scores);

  k2_route_conv<<<1 + CONVB, 1024, 0, stream>>>(
      cands, cvals, scores, p_cap, out, asgn, asgnw,
      fc1w, fc2w, a1, b1, a2, b2,
      fc1wbf, fc2wbf, a1bf, b1bf, a2bf, b2bf);

  // fc1: [2048,1024] x [2048,1024]^T -> silu -> bf16 h_pre
  gemm_bt<0><<<(NTOK / 128) * (HDIM / 128), 256, 0, stream>>>(
      zbf, fc1wbf, fc1b, (void*)hprebf, NTOK, HDIM, DDIM);

  // fc2: [2048,2048] x [1024,2048]^T -> +bias -> f32 out_pre
  gemm_bt<1><<<(NTOK / 128) * (DDIM / 128), 256, 0, stream>>>(
      hprebf, fc2wbf, fc2b, (void*)outpre, NTOK, DDIM, HDIM);

  k5_lora<<<NTOK, 256, 0, stream>>>(
      z, hprebf, outpre, asgn, asgnw, a1bf, b1bf, a2bf, b2bf, out);
}

// Round 3
// 326.268 us; speedup vs baseline: 1.0313x; 1.0313x over previous
//
#include <hip/hip_runtime.h>
#include <stdint.h>

// ---------------------------------------------------------------------------
// MoELatent: B=2048 D=1024 H=2048 E=16 W=4 R=8, top_k=2, cand_k=8
// ---------------------------------------------------------------------------
#define NTOK 2048
#define DDIM 1024
#define HDIM 2048
#define NEXP 16

// output (float) element offsets, in reference return order
#define O_PROBS 2097152   // [2048,16]
#define O_USED  2129920   // [2048,16]
#define O_AIDX  2162688   // [2048,2]
#define O_AW    2166784   // [2048,2]
#define O_HIT   2170880   // scalar
#define O_EVE   2170881   // [2,2048] slot-major
#define O_EVA   2174977   // [2,2048]

// workspace byte offsets — constexpr chain (round-1 lesson: never hand-type)
static constexpr size_t WS_ZBF    = 0;
static constexpr size_t WS_FC1WBF = WS_ZBF    + (size_t)NTOK * DDIM * 2;
static constexpr size_t WS_FC2WBF = WS_FC1WBF + (size_t)HDIM * DDIM * 2;
static constexpr size_t WS_HPREBF = WS_FC2WBF + (size_t)DDIM * HDIM * 2;
static constexpr size_t WS_OUTPRE = WS_HPREBF + (size_t)NTOK * HDIM * 2;
static constexpr size_t WS_A1BF   = WS_OUTPRE + (size_t)NTOK * DDIM * 4;
static constexpr size_t WS_B1BF   = WS_A1BF   + (size_t)16 * 4 * 8 * 1024 * 2;
static constexpr size_t WS_A2BF   = WS_B1BF   + (size_t)16 * 4 * 2048 * 8 * 2;
static constexpr size_t WS_B2BF   = WS_A2BF   + (size_t)16 * 4 * 8 * 2048 * 2;
static constexpr size_t WS_CANDS  = WS_B2BF   + (size_t)16 * 4 * 1024 * 8 * 2;
static constexpr size_t WS_CVALS  = WS_CANDS  + (size_t)NTOK * 4;
static constexpr size_t WS_ARGPK  = WS_CVALS  + (size_t)NTOK * 8 * 4;
static constexpr size_t WS_ASGN   = WS_ARGPK  + (size_t)NTOK * 4;
static constexpr size_t WS_ASGNW  = WS_ASGN   + (size_t)NTOK * 4;

typedef __bf16 v8bf __attribute__((ext_vector_type(8)));
typedef float v4f __attribute__((ext_vector_type(4)));
typedef unsigned short us8v __attribute__((ext_vector_type(8)));

__device__ __forceinline__ unsigned short f2bf(float f) {
  unsigned u = __float_as_uint(f);
  u = u + 0x7fffu + ((u >> 16) & 1u);          // round-to-nearest-even
  return (unsigned short)(u >> 16);
}
__device__ __forceinline__ float bf2f(unsigned short s) {
  return __uint_as_float(((unsigned)s) << 16);
}
__device__ __forceinline__ void gload_lds16(const void* g, void* l) {
  __builtin_amdgcn_global_load_lds(
      (const __attribute__((address_space(1))) void*)g,
      (__attribute__((address_space(3))) void*)l, 16, 0, 0);
}

// ---------------------------------------------------------------------------
// K1: 512 blocks x 256 thr, 4 tokens/block (one token per wave).
// probs + top-8 cands/cvals + adapter-argmax packed (all 16 experts) + z->bf16
// + grid-stride f32->bf16 weight conversion tail (replaces old k2 conv blocks).
// Summation orders identical to the round-2 passing version.
// ---------------------------------------------------------------------------
__global__ __launch_bounds__(256) void k1_probs_scores(
    const float* __restrict__ z, const float* __restrict__ proto,
    const float* __restrict__ ebias, const float* __restrict__ ak,
    const float* __restrict__ p_tau, const float* __restrict__ p_eps,
    const int* __restrict__ p_ban,
    unsigned short* __restrict__ zbf, float* __restrict__ out,
    unsigned* __restrict__ cands, float* __restrict__ cvals,
    unsigned* __restrict__ argpk,
    const float* __restrict__ fc1w, const float* __restrict__ fc2w,
    const float* __restrict__ a1, const float* __restrict__ b1,
    const float* __restrict__ a2, const float* __restrict__ b2,
    unsigned short* __restrict__ fc1wbf, unsigned short* __restrict__ fc2wbf,
    unsigned short* __restrict__ a1bf, unsigned short* __restrict__ b1bf,
    unsigned short* __restrict__ a2bf, unsigned short* __restrict__ b2bf)
{
  __shared__ float zs[4][DDIM];
  const int tid = threadIdx.x;
  const int tb = blockIdx.x * 4;
#pragma unroll
  for (int i = 0; i < 4; ++i) {
    const int col = tid * 4;
    float4 v = *(const float4*)&z[(size_t)(tb + i) * DDIM + col];
    *(float4*)&zs[i][col] = v;
    ushort4 bv;
    bv.x = f2bf(v.x); bv.y = f2bf(v.y); bv.z = f2bf(v.z); bv.w = f2bf(v.w);
    *(ushort4*)&zbf[(size_t)(tb + i) * DDIM + col] = bv;
  }
  __syncthreads();
  const int wv = tid >> 6, l = tid & 63;
  const int t = tb + wv;                       // one token per wave
  const float tau = fmaxf(p_tau[0], 1e-6f);
  const float eps = p_eps[0];
  const int ban = p_ban[0];

  // ---- logits + softmax + top-8 (identical op order to round 2) ----
  float lg_mine = -3.0e38f;
  for (int e = 0; e < NEXP; ++e) {
    float s = 0.f;
#pragma unroll
    for (int i = 0; i < 16; ++i)
      s += zs[wv][l + 64 * i] * proto[(size_t)e * DDIM + l + 64 * i];
#pragma unroll
    for (int o = 32; o; o >>= 1) s += __shfl_xor(s, o, 64);
    float lg = s / tau + ebias[e];
    if (e == ban) lg = -1e9f;
    if (l == e) lg_mine = lg;
  }
  float v0 = (l < NEXP) ? lg_mine : -3.0e38f;
  float mx = v0;
#pragma unroll
  for (int o = 8; o; o >>= 1) mx = fmaxf(mx, __shfl_xor(mx, o, 64));
  float ex = (l < NEXP) ? expf(v0 - mx) : 0.f;
  float sm = ex;
#pragma unroll
  for (int o = 8; o; o >>= 1) sm += __shfl_xor(sm, o, 64);
  float p = (1.f - eps) * (ex / sm) + eps / (float)NEXP;
  if (l < NEXP) out[O_PROBS + (size_t)t * NEXP + l] = p;
  float cur = (l < NEXP) ? p : -1.f;
  unsigned pack = 0;
  float myv = 0.f;
  for (int r = 0; r < 8; ++r) {
    float bv = cur; int bi = l;
#pragma unroll
    for (int o = 32; o; o >>= 1) {
      float ov = __shfl_xor(bv, o, 64);
      int oi = __shfl_xor(bi, o, 64);
      if (ov > bv || (ov == bv && oi < bi)) { bv = ov; bi = oi; }
    }
    pack |= ((unsigned)bi) << (4 * r);
    if (l == r) myv = bv;
    if (l == bi) cur = -1.f;
  }
  if (l == 0) cands[t] = pack;
  if (l < 8) cvals[(size_t)t * 8 + l] = myv;

  // ---- adapter scores + per-expert argmax, packed 2b x 16 ----
  // half-wave h handles rows h*32+j (row = e*4+w); identical reduce order
  const int h = l >> 5, l32 = l & 31;
  unsigned pk = 0;
  float best = -3.0e38f; int bidx = 0;
  for (int j = 0; j < 32; ++j) {
    const int rr = h * 32 + j;
    float s = 0.f;
#pragma unroll
    for (int i = 0; i < 32; ++i)
      s += zs[wv][l32 + 32 * i] * ak[(size_t)rr * DDIM + l32 + 32 * i];
#pragma unroll
    for (int o = 16; o; o >>= 1) s += __shfl_xor(s, o, 64);
    const int w = rr & 3;
    if (w == 0) { best = s; bidx = 0; }
    else if (s > best) { best = s; bidx = w; }
    if (w == 3) pk |= ((unsigned)bidx) << (2 * (rr >> 2));
  }
  unsigned other = __shfl_xor(pk, 32, 64);
  unsigned full = pk | other;
  if (l == 0) argpk[t] = full;

  // ---- conversion tail: grid-stride over 1,835,008 float4s ----
  size_t j = (size_t)blockIdx.x * 256 + tid;
  const size_t stride = (size_t)512 * 256;
  for (; j < 1835008ull; j += stride) {
    const float* src; unsigned short* dst; size_t off;
    if (j < 524288) { src = fc1w; dst = fc1wbf; off = j; }
    else if (j < 1048576) { src = fc2w; dst = fc2wbf; off = j - 524288; }
    else if (j < 1179648) { src = a1; dst = a1bf; off = j - 1048576; }
    else if (j < 1441792) { src = b1; dst = b1bf; off = j - 1179648; }
    else if (j < 1703936) { src = a2; dst = a2bf; off = j - 1441792; }
    else { src = b2; dst = b2bf; off = j - 1703936; }
    float4 v = *(const float4*)&src[off * 4];
    ushort4 bv;
    bv.x = f2bf(v.x); bv.y = f2bf(v.y); bv.z = f2bf(v.z); bv.w = f2bf(v.w);
    *(ushort4*)&dst[off * 4] = bv;
  }
}

// ---------------------------------------------------------------------------
// Router, 256 threads (4 waves), thread t owns tokens {c*256+t}, c=0..7.
// Parallel speculative rounds; each round retires tokens up to the earliest
// capacity-crossing. Writes only packed asgn + asgnw + hit-rate.
// ---------------------------------------------------------------------------
__device__ __forceinline__ void route_decide(unsigned c, int avail,
                                             unsigned& m, int& dec) {
  m = 0;
  int sc = 0, e0 = 0, e1 = 0, r0 = 0, r1 = 0;
#pragma unroll
  for (int j = 0; j < 8; ++j) {
    const int e = (c >> (4 * j)) & 15;
    const bool take = (((avail >> e) & 1) != 0) && (sc < 2);
    if (take) {
      if (sc == 0) { e0 = e; r0 = j; } else { e1 = e; r1 = j; }
      m |= 1u << e;
      ++sc;
    }
  }
  dec = e0 | (e1 << 4) | (r0 << 8) | (r1 << 11) | (sc << 14);
}

struct RouterSm {
  unsigned long long bal[32][16];   // [chunk of 64 tokens][expert]
  int cap[16], T[16];
  int avail, t0, tfin, done, hits;
};

__device__ void router_256(const unsigned* __restrict__ cands,
                           const float* __restrict__ cvals,
                           const unsigned* __restrict__ argpk,
                           const int* __restrict__ p_cap,
                           float* __restrict__ out, int* __restrict__ asgn,
                           float* __restrict__ asgnw, void* smem)
{
  RouterSm* S = (RouterSm*)smem;
  const int tid = threadIdx.x, wv = tid >> 6, l = tid & 63;
  if (tid == 0) { S->avail = 0xFFFF; S->t0 = 0; S->done = 0; S->hits = 0; }
  if (tid < 16) S->cap[tid] = 0;
  const int capl = max(1, p_cap[0]);
  unsigned cnd[8], apk[8];
#pragma unroll
  for (int c = 0; c < 8; ++c) {
    cnd[c] = cands[c * 256 + tid];
    apk[c] = argpk[c * 256 + tid];
  }
  int hits = 0;
  __syncthreads();

  for (int round = 0; round < 20; ++round) {
    const int t0 = S->t0;
    const int avail = S->avail;
    unsigned m[8]; int dec[8];
#pragma unroll
    for (int c = 0; c < 8; ++c) {
      m[c] = 0; dec[c] = 0;
      if (c * 256 + tid >= t0) route_decide(cnd[c], avail, m[c], dec[c]);
    }
    // per-(chunk,expert) take ballots; chunk = c*4+wv covers tokens [chunk*64, +64)
#pragma unroll
    for (int c = 0; c < 8; ++c) {
      unsigned long long keep = 0;
      for (int e = 0; e < 16; ++e) {
        unsigned long long b = __ballot((m[c] >> e) & 1);
        if (l == e) keep = b;
      }
      if (l < 16) S->bal[c * 4 + wv][l] = keep;
    }
    __syncthreads();
    // crossing per expert: wave handles experts wv*4..wv*4+3
#pragma unroll
    for (int q = 0; q < 4; ++q) {
      const int e = wv * 4 + q;
      unsigned long long bm = 0; int cnt = 0;
      if (l < 32) { bm = S->bal[l][e]; cnt = __popcll(bm); }
      int incl = cnt;
#pragma unroll
      for (int o = 1; o < 32; o <<= 1) {
        int u = __shfl_up(incl, o, 64);
        if (l >= o) incl += u;
      }
      int myT = 0x7FFFFFFF;
      if (l < 32 && ((avail >> e) & 1)) {
        const int need = (capl - S->cap[e]) - (incl - cnt);
        if (need >= 1 && need <= cnt) {
          unsigned long long bb = bm;
          for (int i = 1; i < need; ++i) bb &= bb - 1;
          myT = l * 64 + (__ffsll((unsigned long long)bb) - 1);
        }
      }
#pragma unroll
      for (int o = 32; o; o >>= 1) myT = min(myT, __shfl_xor(myT, o, 64));
      if (l == 0) S->T[e] = myT;
    }
    __syncthreads();
    if (wv == 0) {
      int v = (l < 16) ? S->T[l] : 0x7FFFFFFF;
      int ts = v;
#pragma unroll
      for (int o = 32; o; o >>= 1) ts = min(ts, __shfl_xor(ts, o, 64));
      const int done = (ts == 0x7FFFFFFF);
      const int tf = done ? (NTOK - 1) : ts;
      if (l == 0) { S->tfin = tf; S->done = done; S->t0 = tf + 1; }
      if (l < 16 && v == ts) atomicAnd(&S->avail, ~(1 << l));
    }
    __syncthreads();
    const int tfin = S->tfin;
    // cap update: takes in [t0, tfin]
#pragma unroll
    for (int q = 0; q < 4; ++q) {
      const int e = wv * 4 + q;
      int c2 = 0;
      if (l < 32) {
        const int hi = tfin - l * 64;
        unsigned long long mk =
            (hi < 0) ? 0ull : (hi >= 63 ? ~0ull : ((1ull << (hi + 1)) - 1ull));
        c2 = __popcll(S->bal[l][e] & mk);
      }
#pragma unroll
      for (int o = 32; o; o >>= 1) c2 += __shfl_xor(c2, o, 64);
      if (l == 0) S->cap[e] += c2;
    }
    // finalize tokens in [t0, tfin]
#pragma unroll
    for (int c = 0; c < 8; ++c) {
      const int t = c * 256 + tid;
      if (t < t0 || t > tfin) continue;
      const int d = dec[c];
      const int e0 = d & 15, e1 = (d >> 4) & 15;
      const int r0 = (d >> 8) & 7, r1 = (d >> 11) & 7, sc = (d >> 14) & 3;
      const int a0 = (apk[c] >> (2 * e0)) & 3, a1 = (apk[c] >> (2 * e1)) & 3;
      asgn[t] = e0 | (e1 << 4) | (a0 << 8) | (a1 << 10) | (sc << 12);
      asgnw[t * 2 + 0] = sc > 0 ? cvals[(size_t)t * 8 + r0] : 0.f;
      asgnw[t * 2 + 1] = sc > 1 ? cvals[(size_t)t * 8 + r1] : 0.f;
      hits += (sc > 0 && r0 > 0) + (sc > 1 && r1 > 0);
    }
    __syncthreads();
    if (S->done) break;
  }
#pragma unroll
  for (int o = 32; o; o >>= 1) hits += __shfl_xor(hits, o, 64);
  if (l == 0) atomicAdd(&S->hits, hits);
  __syncthreads();
  if (tid == 0) out[O_HIT] = (float)S->hits / (float)(NTOK * 2);
}

// ---------------------------------------------------------------------------
// bf16 GEMM body: C = A[M,K] * B[N,K]^T, 128x128 tile, BK=64, 4 waves,
// mfma_f32_16x16x32_bf16, global_load_lds width 16 (m97 structure).
// EPI 0: silu(x+bias) -> bf16. EPI 1: x+bias -> f32.
// ---------------------------------------------------------------------------
template <int EPI>
__device__ __forceinline__ void gemm_body(
    unsigned short* As, unsigned short* Bs, int bid,
    const unsigned short* __restrict__ A, const unsigned short* __restrict__ Bm,
    const float* __restrict__ bias, void* __restrict__ Cout,
    int M, int N, int K)
{
  const int tid = threadIdx.x;
  const int wv = tid >> 6, l = tid & 63;
  const int ntile = N >> 7;
  const int trow = (bid / ntile) << 7;
  const int tcol = (bid % ntile) << 7;
  const int wr = wv >> 1, wc = wv & 1;
  v4f acc[4][4];
#pragma unroll
  for (int m = 0; m < 4; ++m)
#pragma unroll
    for (int n = 0; n < 4; ++n) acc[m][n] = (v4f){0.f, 0.f, 0.f, 0.f};

  const int lrow8 = l >> 3;
  const int lcol8 = (l & 7) << 3;
  const unsigned short* gA = A + (size_t)trow * K;
  const unsigned short* gB = Bm + (size_t)tcol * K;
  const int fr = l & 15, kof = (l >> 4) << 3;

  for (int k0 = 0; k0 < K; k0 += 64) {
    __syncthreads();
#pragma unroll
    for (int i = 0; i < 4; ++i) {
      const int s = (wv << 2) + i;  // segment 0..15 = 8 rows each
      gload_lds16(gA + (size_t)(s * 8 + lrow8) * K + k0 + lcol8, &As[s * 512]);
      gload_lds16(gB + (size_t)(s * 8 + lrow8) * K + k0 + lcol8, &Bs[s * 512]);
    }
    __syncthreads();
    v8bf af[4][2], bf[4][2];
#pragma unroll
    for (int m = 0; m < 4; ++m) {
      const int row = wr * 64 + m * 16 + fr;
      af[m][0] = *(const v8bf*)&As[row * 64 + kof];
      af[m][1] = *(const v8bf*)&As[row * 64 + 32 + kof];
    }
#pragma unroll
    for (int n = 0; n < 4; ++n) {
      const int row = wc * 64 + n * 16 + fr;
      bf[n][0] = *(const v8bf*)&Bs[row * 64 + kof];
      bf[n][1] = *(const v8bf*)&Bs[row * 64 + 32 + kof];
    }
#pragma unroll
    for (int ks = 0; ks < 2; ++ks)
#pragma unroll
      for (int m = 0; m < 4; ++m)
#pragma unroll
        for (int n = 0; n < 4; ++n)
          acc[m][n] = __builtin_amdgcn_mfma_f32_16x16x32_bf16(
              af[m][ks], bf[n][ks], acc[m][n], 0, 0, 0);
  }
  // epilogue: C/D layout col=lane&15, row=(lane>>4)*4+j  [m89/m91]
  const int fq = l >> 4;
#pragma unroll
  for (int m = 0; m < 4; ++m)
#pragma unroll
    for (int n = 0; n < 4; ++n) {
      const int col = tcol + wc * 64 + n * 16 + fr;
      const float bc = bias[col];
#pragma unroll
      for (int j = 0; j < 4; ++j) {
        const int row = trow + wr * 64 + m * 16 + fq * 4 + j;
        const float v = acc[m][n][j] + bc;
        if (EPI == 0) {
          const float sv = v / (1.f + __expf(-v));
          ((unsigned short*)Cout)[(size_t)row * N + col] = f2bf(sv);
        } else {
          ((float*)Cout)[(size_t)row * N + col] = v;
        }
      }
    }
}

// fc1 kernel: block 0 = router (overlaps with GEMM), blocks 1.. = GEMM tiles
__global__ __launch_bounds__(256) void gemm_router(
    const unsigned short* __restrict__ A, const unsigned short* __restrict__ Bm,
    const float* __restrict__ bias, void* __restrict__ Cout,
    int M, int N, int K,
    const unsigned* __restrict__ cands, const float* __restrict__ cvals,
    const unsigned* __restrict__ argpk, const int* __restrict__ p_cap,
    float* __restrict__ out, int* __restrict__ asgn,
    float* __restrict__ asgnw)
{
  __shared__ __align__(16) char smem[32768];
  if (blockIdx.x == 0) {
    router_256(cands, cvals, argpk, p_cap, out, asgn, asgnw, smem);
    return;
  }
  gemm_body<0>((unsigned short*)smem, (unsigned short*)smem + 8192,
               blockIdx.x - 1, A, Bm, bias, Cout, M, N, K);
}

__global__ __launch_bounds__(256) void gemm_bt1(
    const unsigned short* __restrict__ A, const unsigned short* __restrict__ Bm,
    const float* __restrict__ bias, void* __restrict__ Cout,
    int M, int N, int K)
{
  __shared__ __align__(16) char smem[32768];
  gemm_body<1>((unsigned short*)smem, (unsigned short*)smem + 8192,
               blockIdx.x, A, Bm, bias, Cout, M, N, K);
}

// ---------------------------------------------------------------------------
// K5: per-token LoRA adapters + final combine + bulk routing outputs
// ---------------------------------------------------------------------------
__global__ __launch_bounds__(256) void k5_lora(
    const float* __restrict__ z, const unsigned short* __restrict__ hpre,
    const float* __restrict__ outpre, const int* __restrict__ asgn,
    const float* __restrict__ asgnw,
    const unsigned short* __restrict__ a1, const unsigned short* __restrict__ b1,
    const unsigned short* __restrict__ a2, const unsigned short* __restrict__ b2,
    float* __restrict__ out0, float* __restrict__ out)
{
  __shared__ float zl[DDIM];
  __shared__ float hl[HDIM];
  __shared__ float t1s[8], t2s[8];
  const int b = blockIdx.x, tid = threadIdx.x;
  {
    float4 v = *(const float4*)&z[(size_t)b * DDIM + tid * 4];
    *(float4*)&zl[tid * 4] = v;
  }
  const int pk = asgn[b];
  const int sc = (pk >> 12) & 3;
  const int eA0 = pk & 15, eA1 = (pk >> 4) & 15;
  const int aA0 = (pk >> 8) & 3, aA1 = (pk >> 10) & 3;
  const float w0 = asgnw[b * 2 + 0], w1 = asgnw[b * 2 + 1];
  // bulk routing outputs (moved out of the serial router)
  if (tid < 16)
    out[O_USED + (size_t)b * 16 + tid] =
        (float)((sc > 0 && tid == eA0) || (sc > 1 && tid == eA1));
  if (tid == 0) {
    out[O_AIDX + (size_t)b * 2 + 0] = sc > 0 ? (float)eA0 : -1.f;
    out[O_AIDX + (size_t)b * 2 + 1] = sc > 1 ? (float)eA1 : -1.f;
    out[O_AW + (size_t)b * 2 + 0] = w0;
    out[O_AW + (size_t)b * 2 + 1] = w1;
    out[O_EVE + b] = sc > 0 ? (float)eA0 : -1.f;
    out[O_EVE + NTOK + b] = sc > 1 ? (float)eA1 : -1.f;
    out[O_EVA + b] = sc > 0 ? (float)aA0 : -1.f;
    out[O_EVA + NTOK + b] = sc > 1 ? (float)aA1 : -1.f;
  }
  float acc[4] = {0.f, 0.f, 0.f, 0.f};
  float wsum = 0.f;
  const int r = tid >> 5, l5 = tid & 31;
  __syncthreads();

  for (int s = 0; s < 2; ++s) {
    if (s >= sc) continue;  // uniform across block
    const float ww = (s == 0) ? w0 : w1;
    const int ad = ((s == 0) ? eA0 : eA1) * 4 + ((s == 0) ? aA0 : aA1);
    wsum += ww;
    // t1[r] = z . a1[ad][r][:]
    {
      const unsigned short* pa1 = a1 + ((size_t)ad * 8 + r) * DDIM;
      float sa = 0.f;
      for (int i = 0; i < 32; ++i) sa += zl[l5 + 32 * i] * bf2f(pa1[l5 + 32 * i]);
#pragma unroll
      for (int o = 16; o; o >>= 1) sa += __shfl_xor(sa, o, 64);
      if (l5 == 0) t1s[r] = sa;
    }
    __syncthreads();
    // h = silu(h_pre + B1 t1)
    {
      float t1r[8];
#pragma unroll
      for (int q = 0; q < 8; ++q) t1r[q] = t1s[q];
      const unsigned short* pb1 = b1 + (size_t)ad * HDIM * 8;
      const unsigned short* ph = hpre + (size_t)b * HDIM;
#pragma unroll
      for (int j = 0; j < 8; ++j) {
        const int hh_i = tid + 256 * j;
        us8v row = *(const us8v*)&pb1[(size_t)hh_i * 8];
        float d1 = 0.f;
#pragma unroll
        for (int q = 0; q < 8; ++q) d1 += t1r[q] * bf2f(row[q]);
        const float hh = bf2f(ph[hh_i]) + d1;  // SCALE = 1
        hl[hh_i] = hh / (1.f + __expf(-hh));
      }
    }
    __syncthreads();
    // t2[r] = h . a2[ad][r][:]
    {
      const unsigned short* pa2 = a2 + ((size_t)ad * 8 + r) * HDIM;
      float sa = 0.f;
      for (int i = 0; i < 64; ++i) sa += hl[l5 + 32 * i] * bf2f(pa2[l5 + 32 * i]);
#pragma unroll
      for (int o = 16; o; o >>= 1) sa += __shfl_xor(sa, o, 64);
      if (l5 == 0) t2s[r] = sa;
    }
    __syncthreads();
    // d2 accumulate
    {
      float t2r[8];
#pragma unroll
      for (int q = 0; q < 8; ++q) t2r[q] = t2s[q];
      const unsigned short* pb2 = b2 + (size_t)ad * DDIM * 8;
#pragma unroll
      for (int j = 0; j < 4; ++j) {
        const int d = tid + 256 * j;
        us8v row = *(const us8v*)&pb2[(size_t)d * 8];
        float d2 = 0.f;
#pragma unroll
        for (int q = 0; q < 8; ++q) d2 += t2r[q] * bf2f(row[q]);
        acc[j] += ww * d2;  // SCALE = 1
      }
    }
    __syncthreads();  // protect t1s/hl/t2s before next slot
  }
#pragma unroll
  for (int j = 0; j < 4; ++j) {
    const int d = tid + 256 * j;
    out0[(size_t)b * DDIM + d] =
        zl[d] + wsum * outpre[(size_t)b * DDIM + d] + acc[j];
  }
}

// ---------------------------------------------------------------------------
extern "C" void kernel_launch(void* const* d_in, const int* in_sizes, int n_in,
                              void* d_out, int out_size, void* d_ws, size_t ws_size,
                              hipStream_t stream)
{
  (void)in_sizes; (void)n_in; (void)out_size; (void)ws_size;
  const float* z     = (const float*)d_in[0];
  const int*   p_cap = (const int*)d_in[2];
  const int*   p_ban = (const int*)d_in[3];
  const float* p_tau = (const float*)d_in[4];
  const float* p_eps = (const float*)d_in[5];
  const float* fc1w  = (const float*)d_in[6];
  const float* fc1b  = (const float*)d_in[7];
  const float* fc2w  = (const float*)d_in[8];
  const float* fc2b  = (const float*)d_in[9];
  const float* proto = (const float*)d_in[10];
  const float* ak    = (const float*)d_in[11];
  const float* ebias = (const float*)d_in[12];
  const float* a1    = (const float*)d_in[13];
  const float* b1    = (const float*)d_in[14];
  const float* a2    = (const float*)d_in[15];
  const float* b2    = (const float*)d_in[16];
  float* out = (float*)d_out;
  char* ws = (char*)d_ws;

  unsigned short* zbf    = (unsigned short*)(ws + WS_ZBF);
  unsigned short* fc1wbf = (unsigned short*)(ws + WS_FC1WBF);
  unsigned short* fc2wbf = (unsigned short*)(ws + WS_FC2WBF);
  unsigned short* hprebf = (unsigned short*)(ws + WS_HPREBF);
  float*          outpre = (float*)(ws + WS_OUTPRE);
  unsigned short* a1bf   = (unsigned short*)(ws + WS_A1BF);
  unsigned short* b1bf   = (unsigned short*)(ws + WS_B1BF);
  unsigned short* a2bf   = (unsigned short*)(ws + WS_A2BF);
  unsigned short* b2bf   = (unsigned short*)(ws + WS_B2BF);
  unsigned*       cands  = (unsigned*)(ws + WS_CANDS);
  float*          cvals  = (float*)(ws + WS_CVALS);
  unsigned*       argpk  = (unsigned*)(ws + WS_ARGPK);
  int*            asgn   = (int*)(ws + WS_ASGN);
  float*          asgnw  = (float*)(ws + WS_ASGNW);

  k1_probs_scores<<<512, 256, 0, stream>>>(
      z, proto, ebias, ak, p_tau, p_eps, p_ban, zbf, out, cands, cvals, argpk,
      fc1w, fc2w, a1, b1, a2, b2, fc1wbf, fc2wbf, a1bf, b1bf, a2bf, b2bf);

  // fc1 GEMM (256 tiles) + router (block 0), overlapped
  gemm_router<<<1 + (NTOK / 128) * (HDIM / 128), 256, 0, stream>>>(
      zbf, fc1wbf, fc1b, (void*)hprebf, NTOK, HDIM, DDIM,
      cands, cvals, argpk, p_cap, out, asgn, asgnw);

  // fc2: [2048,2048] x [1024,2048]^T -> +bias -> f32 out_pre
  gemm_bt1<<<(NTOK / 128) * (DDIM / 128), 256, 0, stream>>>(
      hprebf, fc2wbf, fc2b, (void*)outpre, NTOK, DDIM, HDIM);

  k5_lora<<<NTOK, 256, 0, stream>>>(
      z, hprebf, outpre, asgn, asgnw, a1bf, b1bf, a2bf, b2bf, out, out);
}

// Round 4
// 324.614 us; speedup vs baseline: 1.0366x; 1.0051x over previous
//
#include <hip/hip_runtime.h>
#include <stdint.h>

// ---------------------------------------------------------------------------
// MoELatent: B=2048 D=1024 H=2048 E=16 W=4 R=8, top_k=2, cand_k=8
// ---------------------------------------------------------------------------
#define NTOK 2048
#define DDIM 1024
#define HDIM 2048
#define NEXP 16

// output (float) element offsets, in reference return order
#define O_PROBS 2097152   // [2048,16]
#define O_USED  2129920   // [2048,16]
#define O_AIDX  2162688   // [2048,2]
#define O_AW    2166784   // [2048,2]
#define O_HIT   2170880   // scalar
#define O_EVE   2170881   // [2,2048] slot-major
#define O_EVA   2174977   // [2,2048]

// workspace byte offsets — constexpr chain (round-1 lesson: never hand-type)
static constexpr size_t WS_ZBF    = 0;
static constexpr size_t WS_FC1WBF = WS_ZBF    + (size_t)NTOK * DDIM * 2;
static constexpr size_t WS_FC2WBF = WS_FC1WBF + (size_t)HDIM * DDIM * 2;
static constexpr size_t WS_HPREBF = WS_FC2WBF + (size_t)DDIM * HDIM * 2;
static constexpr size_t WS_OUTPRE = WS_HPREBF + (size_t)NTOK * HDIM * 2;
static constexpr size_t WS_A1BF   = WS_OUTPRE + (size_t)NTOK * DDIM * 4;
static constexpr size_t WS_B1BF   = WS_A1BF   + (size_t)16 * 4 * 8 * 1024 * 2;
static constexpr size_t WS_A2BF   = WS_B1BF   + (size_t)16 * 4 * 2048 * 8 * 2;
static constexpr size_t WS_B2BF   = WS_A2BF   + (size_t)16 * 4 * 8 * 2048 * 2;
static constexpr size_t WS_CANDS  = WS_B2BF   + (size_t)16 * 4 * 1024 * 8 * 2;
static constexpr size_t WS_CVALS  = WS_CANDS  + (size_t)NTOK * 4;
static constexpr size_t WS_ARGPK  = WS_CVALS  + (size_t)NTOK * 8 * 4;
static constexpr size_t WS_ASGN   = WS_ARGPK  + (size_t)NTOK * 4;
static constexpr size_t WS_ASGNW  = WS_ASGN   + (size_t)NTOK * 4;

typedef __bf16 v8bf __attribute__((ext_vector_type(8)));
typedef float v4f __attribute__((ext_vector_type(4)));
typedef unsigned short us8v __attribute__((ext_vector_type(8)));

__device__ __forceinline__ unsigned short f2bf(float f) {
  unsigned u = __float_as_uint(f);
  u = u + 0x7fffu + ((u >> 16) & 1u);          // round-to-nearest-even
  return (unsigned short)(u >> 16);
}
__device__ __forceinline__ float bf2f(unsigned short s) {
  return __uint_as_float(((unsigned)s) << 16);
}
__device__ __forceinline__ void gload_lds16(const void* g, void* l) {
  __builtin_amdgcn_global_load_lds(
      (const __attribute__((address_space(1))) void*)g,
      (__attribute__((address_space(3))) void*)l, 16, 0, 0);
}
__device__ __forceinline__ float dot4(float4 a, float4 b) {
  return a.x * b.x + a.y * b.y + a.z * b.z + a.w * b.w;
}

// ---------------------------------------------------------------------------
// K1: 512 blocks x 256 thr, 4 tokens/block (one token per wave).
// probs + top-8 cands/cvals + adapter-argmax packed + z->bf16
// + grid-stride f32->bf16 weight conversion tail. float4 dot products.
// ---------------------------------------------------------------------------
__global__ __launch_bounds__(256) void k1_probs_scores(
    const float* __restrict__ z, const float* __restrict__ proto,
    const float* __restrict__ ebias, const float* __restrict__ ak,
    const float* __restrict__ p_tau, const float* __restrict__ p_eps,
    const int* __restrict__ p_ban,
    unsigned short* __restrict__ zbf, float* __restrict__ out,
    unsigned* __restrict__ cands, float* __restrict__ cvals,
    unsigned* __restrict__ argpk,
    const float* __restrict__ fc1w, const float* __restrict__ fc2w,
    const float* __restrict__ a1, const float* __restrict__ b1,
    const float* __restrict__ a2, const float* __restrict__ b2,
    unsigned short* __restrict__ fc1wbf, unsigned short* __restrict__ fc2wbf,
    unsigned short* __restrict__ a1bf, unsigned short* __restrict__ b1bf,
    unsigned short* __restrict__ a2bf, unsigned short* __restrict__ b2bf)
{
  __shared__ float zs[4][DDIM];
  const int tid = threadIdx.x;
  const int tb = blockIdx.x * 4;
#pragma unroll
  for (int i = 0; i < 4; ++i) {
    const int col = tid * 4;
    float4 v = *(const float4*)&z[(size_t)(tb + i) * DDIM + col];
    *(float4*)&zs[i][col] = v;
    ushort4 bv;
    bv.x = f2bf(v.x); bv.y = f2bf(v.y); bv.z = f2bf(v.z); bv.w = f2bf(v.w);
    *(ushort4*)&zbf[(size_t)(tb + i) * DDIM + col] = bv;
  }
  __syncthreads();
  const int wv = tid >> 6, l = tid & 63;
  const int t = tb + wv;                       // one token per wave
  const float tau = fmaxf(p_tau[0], 1e-6f);
  const float eps = p_eps[0];
  const int ban = p_ban[0];
  const float4* z4 = (const float4*)&zs[wv][0];

  // ---- logits + softmax + top-8 ----
  float lg_mine = -3.0e38f;
  for (int e = 0; e < NEXP; ++e) {
    const float4* pr = (const float4*)&proto[(size_t)e * DDIM];
    float s = 0.f;
#pragma unroll
    for (int i = 0; i < 4; ++i) s += dot4(z4[l + 64 * i], pr[l + 64 * i]);
#pragma unroll
    for (int o = 32; o; o >>= 1) s += __shfl_xor(s, o, 64);
    float lg = s / tau + ebias[e];
    if (e == ban) lg = -1e9f;
    if (l == e) lg_mine = lg;
  }
  float v0 = (l < NEXP) ? lg_mine : -3.0e38f;
  float mx = v0;
#pragma unroll
  for (int o = 8; o; o >>= 1) mx = fmaxf(mx, __shfl_xor(mx, o, 64));
  float ex = (l < NEXP) ? expf(v0 - mx) : 0.f;
  float sm = ex;
#pragma unroll
  for (int o = 8; o; o >>= 1) sm += __shfl_xor(sm, o, 64);
  float p = (1.f - eps) * (ex / sm) + eps / (float)NEXP;
  if (l < NEXP) out[O_PROBS + (size_t)t * NEXP + l] = p;
  // top-8, jax.lax.top_k tie-break: value desc, index asc
  float cur = (l < NEXP) ? p : -1.f;
  unsigned pack = 0;
  float myv = 0.f;
  for (int r = 0; r < 8; ++r) {
    float bv = cur; int bi = l;
#pragma unroll
    for (int o = 32; o; o >>= 1) {
      float ov = __shfl_xor(bv, o, 64);
      int oi = __shfl_xor(bi, o, 64);
      if (ov > bv || (ov == bv && oi < bi)) { bv = ov; bi = oi; }
    }
    pack |= ((unsigned)bi) << (4 * r);
    if (l == r) myv = bv;
    if (l == bi) cur = -1.f;
  }
  if (l == 0) cands[t] = pack;
  if (l < 8) cvals[(size_t)t * 8 + l] = myv;

  // ---- adapter scores + per-expert argmax, packed 2b x 16 ----
  const int h = l >> 5, l32 = l & 31;
  unsigned pk = 0;
  float best = -3.0e38f; int bidx = 0;
  for (int j = 0; j < 32; ++j) {
    const int rr = h * 32 + j;
    const float4* ar = (const float4*)&ak[(size_t)rr * DDIM];
    float s = 0.f;
#pragma unroll
    for (int i = 0; i < 8; ++i) s += dot4(z4[l32 + 32 * i], ar[l32 + 32 * i]);
#pragma unroll
    for (int o = 16; o; o >>= 1) s += __shfl_xor(s, o, 64);
    const int w = rr & 3;
    if (w == 0) { best = s; bidx = 0; }
    else if (s > best) { best = s; bidx = w; }
    if (w == 3) pk |= ((unsigned)bidx) << (2 * (rr >> 2));
  }
  unsigned other = __shfl_xor(pk, 32, 64);
  unsigned full = pk | other;
  if (l == 0) argpk[t] = full;

  // ---- conversion tail: grid-stride over 1,835,008 float4s ----
  size_t j = (size_t)blockIdx.x * 256 + tid;
  const size_t stride = (size_t)512 * 256;
  for (; j < 1835008ull; j += stride) {
    const float* src; unsigned short* dst; size_t off;
    if (j < 524288) { src = fc1w; dst = fc1wbf; off = j; }
    else if (j < 1048576) { src = fc2w; dst = fc2wbf; off = j - 524288; }
    else if (j < 1179648) { src = a1; dst = a1bf; off = j - 1048576; }
    else if (j < 1441792) { src = b1; dst = b1bf; off = j - 1179648; }
    else if (j < 1703936) { src = a2; dst = a2bf; off = j - 1441792; }
    else { src = b2; dst = b2bf; off = j - 1703936; }
    float4 v = *(const float4*)&src[off * 4];
    ushort4 bv;
    bv.x = f2bf(v.x); bv.y = f2bf(v.y); bv.z = f2bf(v.z); bv.w = f2bf(v.w);
    *(ushort4*)&dst[off * 4] = bv;
  }
}

// ---------------------------------------------------------------------------
// Router, 256 threads (4 waves), thread t owns tokens {c*256+t}, c=0..7.
// Fast decide via availability-flags bitmask; ballots only for active chunks
// and still-available experts; ballot masks cached in regs for cap-update.
// ---------------------------------------------------------------------------
__device__ __forceinline__ void route_decide(unsigned c, int avail,
                                             unsigned& m, int& dec) {
  unsigned flags = 0;
#pragma unroll
  for (int j = 0; j < 8; ++j) {
    const int e = (c >> (4 * j)) & 15;
    flags |= ((unsigned)(avail >> e) & 1u) << j;
  }
  const int pc = __popc(flags);
  const int sc = pc < 2 ? pc : 2;
  const int j0 = __ffs(flags) - 1;
  const int j1 = __ffs(flags & (flags - 1)) - 1;
  const int r0 = sc > 0 ? j0 : 0;
  const int r1 = sc > 1 ? j1 : 0;
  const int e0 = (c >> (4 * r0)) & 15;
  const int e1 = (c >> (4 * r1)) & 15;
  m = (sc > 0 ? (1u << e0) : 0u) | (sc > 1 ? (1u << e1) : 0u);
  dec = e0 | (e1 << 4) | (r0 << 8) | (r1 << 11) | (sc << 14);
}

struct RouterSm {
  unsigned long long bal[32][17];   // [chunk of 64 tokens][expert], padded
  int cap[16], T[16];
  int avail, t0, tfin, done, hits;
};

__device__ void router_256(const unsigned* __restrict__ cands,
                           const float* __restrict__ cvals,
                           const unsigned* __restrict__ argpk,
                           const int* __restrict__ p_cap,
                           float* __restrict__ out, int* __restrict__ asgn,
                           float* __restrict__ asgnw, void* smem)
{
  RouterSm* S = (RouterSm*)smem;
  const int tid = threadIdx.x, wv = tid >> 6, l = tid & 63;
  if (tid == 0) { S->avail = 0xFFFF; S->t0 = 0; S->done = 0; S->hits = 0; }
  if (tid < 16) S->cap[tid] = 0;
  const int capl = max(1, p_cap[0]);
  unsigned cnd[8], apk[8];
#pragma unroll
  for (int c = 0; c < 8; ++c) {
    cnd[c] = cands[c * 256 + tid];
    apk[c] = argpk[c * 256 + tid];
  }
  int hits = 0;
  __syncthreads();

  for (int round = 0; round < 24; ++round) {
    const int t0 = S->t0;
    const int avail = S->avail;
    unsigned m[8]; int dec[8];
#pragma unroll
    for (int c = 0; c < 8; ++c) {
      m[c] = 0; dec[c] = 0;
      if (c * 256 + tid >= t0) route_decide(cnd[c], avail, m[c], dec[c]);
    }
    // ballots: chunk q=c*4+wv covers tokens [q*64, q*64+64); token of thread
    // tid in wave wv for c is q*64 + l. Skip dead chunks (store zeros once).
#pragma unroll
    for (int c = 0; c < 8; ++c) {
      const int q = c * 4 + wv;
      if (q * 64 + 63 < t0) {
        if (l < 16) S->bal[q][l] = 0ull;
      } else {
        unsigned long long keep = 0;
        for (int av = avail; av; av &= av - 1) {
          const int e = __ffs(av) - 1;
          unsigned long long b = __ballot((m[c] >> e) & 1);
          if (l == e) keep = b;
        }
        if (l < 16) S->bal[q][l] = keep;
      }
    }
    __syncthreads();
    // crossing per expert (wave handles experts wv*4..wv*4+3), bm cached
    unsigned long long bmq[4];
#pragma unroll
    for (int qq = 0; qq < 4; ++qq) {
      const int e = wv * 4 + qq;
      if (!((avail >> e) & 1)) { if (l == 0) S->T[e] = 0x7FFFFFFF; continue; }
      unsigned long long bm = 0; int cnt = 0;
      if (l < 32) { bm = S->bal[l][e]; cnt = __popcll(bm); }
      bmq[qq] = bm;
      int incl = cnt;
#pragma unroll
      for (int o = 1; o < 32; o <<= 1) {
        int u = __shfl_up(incl, o, 64);
        if (l >= o) incl += u;
      }
      int myT = 0x7FFFFFFF;
      if (l < 32) {
        const int need = (capl - S->cap[e]) - (incl - cnt);
        if (need >= 1 && need <= cnt) {
          unsigned long long bb = bm;
          for (int i = 1; i < need; ++i) bb &= bb - 1;
          myT = l * 64 + (__ffsll((unsigned long long)bb) - 1);
        }
      }
#pragma unroll
      for (int o = 32; o; o >>= 1) myT = min(myT, __shfl_xor(myT, o, 64));
      if (l == 0) S->T[e] = myT;
    }
    __syncthreads();
    if (wv == 0) {
      int v = (l < 16) ? S->T[l] : 0x7FFFFFFF;
      int ts = v;
#pragma unroll
      for (int o = 32; o; o >>= 1) ts = min(ts, __shfl_xor(ts, o, 64));
      const int done = (ts == 0x7FFFFFFF);
      const int tf = done ? (NTOK - 1) : ts;
      if (l == 0) { S->tfin = tf; S->done = done; S->t0 = tf + 1; }
      if (l < 16 && v == ts) atomicAnd(&S->avail, ~(1 << l));
    }
    __syncthreads();
    const int tfin = S->tfin;
    // cap[e] += takes in [t0, tfin] (reuse cached bmq)
#pragma unroll
    for (int qq = 0; qq < 4; ++qq) {
      const int e = wv * 4 + qq;
      if (!((avail >> e) & 1)) continue;
      int c2 = 0;
      if (l < 32) {
        const int hi = tfin - l * 64;
        unsigned long long mk =
            (hi < 0) ? 0ull : (hi >= 63 ? ~0ull : ((1ull << (hi + 1)) - 1ull));
        c2 = __popcll(bmq[qq] & mk);
      }
#pragma unroll
      for (int o = 32; o; o >>= 1) c2 += __shfl_xor(c2, o, 64);
      if (l == 0) S->cap[e] += c2;
    }
    // finalize tokens in [t0, tfin]
#pragma unroll
    for (int c = 0; c < 8; ++c) {
      const int t = c * 256 + tid;
      if (t < t0 || t > tfin) continue;
      const int d = dec[c];
      const int e0 = d & 15, e1 = (d >> 4) & 15;
      const int r0 = (d >> 8) & 7, r1 = (d >> 11) & 7, sc = (d >> 14) & 3;
      const int a0 = (apk[c] >> (2 * e0)) & 3, a1 = (apk[c] >> (2 * e1)) & 3;
      asgn[t] = e0 | (e1 << 4) | (a0 << 8) | (a1 << 10) | (sc << 12);
      asgnw[t * 2 + 0] = sc > 0 ? cvals[(size_t)t * 8 + r0] : 0.f;
      asgnw[t * 2 + 1] = sc > 1 ? cvals[(size_t)t * 8 + r1] : 0.f;
      hits += (sc > 0 && r0 > 0) + (sc > 1 && r1 > 0);
    }
    __syncthreads();
    if (S->done) break;
  }
#pragma unroll
  for (int o = 32; o; o >>= 1) hits += __shfl_xor(hits, o, 64);
  if (l == 0) atomicAdd(&S->hits, hits);
  __syncthreads();
  if (tid == 0) out[O_HIT] = (float)S->hits / (float)(NTOK * 2);
}

// ---------------------------------------------------------------------------
// bf16 GEMM body: C = A[M,K] * B[N,K]^T, 128x128 tile, BK=64, 4 waves,
// mfma_f32_16x16x32_bf16, global_load_lds width 16 (m97 structure).
// EPI 0: silu(x+bias) -> bf16. EPI 1: x+bias -> f32.
// ---------------------------------------------------------------------------
template <int EPI>
__device__ __forceinline__ void gemm_body(
    unsigned short* As, unsigned short* Bs, int bid,
    const unsigned short* __restrict__ A, const unsigned short* __restrict__ Bm,
    const float* __restrict__ bias, void* __restrict__ Cout,
    int M, int N, int K)
{
  const int tid = threadIdx.x;
  const int wv = tid >> 6, l = tid & 63;
  const int ntile = N >> 7;
  const int trow = (bid / ntile) << 7;
  const int tcol = (bid % ntile) << 7;
  const int wr = wv >> 1, wc = wv & 1;
  v4f acc[4][4];
#pragma unroll
  for (int m = 0; m < 4; ++m)
#pragma unroll
    for (int n = 0; n < 4; ++n) acc[m][n] = (v4f){0.f, 0.f, 0.f, 0.f};

  const int lrow8 = l >> 3;
  const int lcol8 = (l & 7) << 3;
  const unsigned short* gA = A + (size_t)trow * K;
  const unsigned short* gB = Bm + (size_t)tcol * K;
  const int fr = l & 15, kof = (l >> 4) << 3;

  for (int k0 = 0; k0 < K; k0 += 64) {
    __syncthreads();
#pragma unroll
    for (int i = 0; i < 4; ++i) {
      const int s = (wv << 2) + i;  // segment 0..15 = 8 rows each
      gload_lds16(gA + (size_t)(s * 8 + lrow8) * K + k0 + lcol8, &As[s * 512]);
      gload_lds16(gB + (size_t)(s * 8 + lrow8) * K + k0 + lcol8, &Bs[s * 512]);
    }
    __syncthreads();
    v8bf af[4][2], bf[4][2];
#pragma unroll
    for (int m = 0; m < 4; ++m) {
      const int row = wr * 64 + m * 16 + fr;
      af[m][0] = *(const v8bf*)&As[row * 64 + kof];
      af[m][1] = *(const v8bf*)&As[row * 64 + 32 + kof];
    }
#pragma unroll
    for (int n = 0; n < 4; ++n) {
      const int row = wc * 64 + n * 16 + fr;
      bf[n][0] = *(const v8bf*)&Bs[row * 64 + kof];
      bf[n][1] = *(const v8bf*)&Bs[row * 64 + 32 + kof];
    }
#pragma unroll
    for (int ks = 0; ks < 2; ++ks)
#pragma unroll
      for (int m = 0; m < 4; ++m)
#pragma unroll
        for (int n = 0; n < 4; ++n)
          acc[m][n] = __builtin_amdgcn_mfma_f32_16x16x32_bf16(
              af[m][ks], bf[n][ks], acc[m][n], 0, 0, 0);
  }
  // epilogue: C/D layout col=lane&15, row=(lane>>4)*4+j  [m89/m91]
  const int fq = l >> 4;
#pragma unroll
  for (int m = 0; m < 4; ++m)
#pragma unroll
    for (int n = 0; n < 4; ++n) {
      const int col = tcol + wc * 64 + n * 16 + fr;
      const float bc = bias[col];
#pragma unroll
      for (int j = 0; j < 4; ++j) {
        const int row = trow + wr * 64 + m * 16 + fq * 4 + j;
        const float v = acc[m][n][j] + bc;
        if (EPI == 0) {
          const float sv = v / (1.f + __expf(-v));
          ((unsigned short*)Cout)[(size_t)row * N + col] = f2bf(sv);
        } else {
          ((float*)Cout)[(size_t)row * N + col] = v;
        }
      }
    }
}

// fc1 kernel: block 0 = router (overlaps with GEMM), blocks 1.. = GEMM tiles
__global__ __launch_bounds__(256) void gemm_router(
    const unsigned short* __restrict__ A, const unsigned short* __restrict__ Bm,
    const float* __restrict__ bias, void* __restrict__ Cout,
    int M, int N, int K,
    const unsigned* __restrict__ cands, const float* __restrict__ cvals,
    const unsigned* __restrict__ argpk, const int* __restrict__ p_cap,
    float* __restrict__ out, int* __restrict__ asgn,
    float* __restrict__ asgnw)
{
  __shared__ __align__(16) char smem[32768];
  if (blockIdx.x == 0) {
    router_256(cands, cvals, argpk, p_cap, out, asgn, asgnw, smem);
    return;
  }
  gemm_body<0>((unsigned short*)smem, (unsigned short*)smem + 8192,
               blockIdx.x - 1, A, Bm, bias, Cout, M, N, K);
}

__global__ __launch_bounds__(256) void gemm_bt1(
    const unsigned short* __restrict__ A, const unsigned short* __restrict__ Bm,
    const float* __restrict__ bias, void* __restrict__ Cout,
    int M, int N, int K)
{
  __shared__ __align__(16) char smem[32768];
  gemm_body<1>((unsigned short*)smem, (unsigned short*)smem + 8192,
               blockIdx.x, A, Bm, bias, Cout, M, N, K);
}

// ---------------------------------------------------------------------------
// K5: per-token LoRA adapters + final combine + bulk routing outputs
// ---------------------------------------------------------------------------
__global__ __launch_bounds__(256) void k5_lora(
    const float* __restrict__ z, const unsigned short* __restrict__ hpre,
    const float* __restrict__ outpre, const int* __restrict__ asgn,
    const float* __restrict__ asgnw,
    const unsigned short* __restrict__ a1, const unsigned short* __restrict__ b1,
    const unsigned short* __restrict__ a2, const unsigned short* __restrict__ b2,
    float* __restrict__ out0, float* __restrict__ out)
{
  __shared__ float zl[DDIM];
  __shared__ float hl[HDIM];
  __shared__ float t1s[8], t2s[8];
  const int b = blockIdx.x, tid = threadIdx.x;
  {
    float4 v = *(const float4*)&z[(size_t)b * DDIM + tid * 4];
    *(float4*)&zl[tid * 4] = v;
  }
  const int pk = asgn[b];
  const int sc = (pk >> 12) & 3;
  const int eA0 = pk & 15, eA1 = (pk >> 4) & 15;
  const int aA0 = (pk >> 8) & 3, aA1 = (pk >> 10) & 3;
  const float w0 = asgnw[b * 2 + 0], w1 = asgnw[b * 2 + 1];
  // bulk routing outputs (kept out of the serial router)
  if (tid < 16)
    out[O_USED + (size_t)b * 16 + tid] =
        (float)((sc > 0 && tid == eA0) || (sc > 1 && tid == eA1));
  if (tid == 0) {
    out[O_AIDX + (size_t)b * 2 + 0] = sc > 0 ? (float)eA0 : -1.f;
    out[O_AIDX + (size_t)b * 2 + 1] = sc > 1 ? (float)eA1 : -1.f;
    out[O_AW + (size_t)b * 2 + 0] = w0;
    out[O_AW + (size_t)b * 2 + 1] = w1;
    out[O_EVE + b] = sc > 0 ? (float)eA0 : -1.f;
    out[O_EVE + NTOK + b] = sc > 1 ? (float)eA1 : -1.f;
    out[O_EVA + b] = sc > 0 ? (float)aA0 : -1.f;
    out[O_EVA + NTOK + b] = sc > 1 ? (float)aA1 : -1.f;
  }
  float acc[4] = {0.f, 0.f, 0.f, 0.f};
  float wsum = 0.f;
  const int r = tid >> 5, l5 = tid & 31;
  const float4* zg = (const float4*)&z[(size_t)b * DDIM];   // L1/L2-hot
  __syncthreads();

  for (int s = 0; s < 2; ++s) {
    if (s >= sc) continue;  // uniform across block
    const float ww = (s == 0) ? w0 : w1;
    const int ad = ((s == 0) ? eA0 : eA1) * 4 + ((s == 0) ? aA0 : aA1);
    wsum += ww;
    // t1[r] = z . a1[ad][r][:]   (bf16x8 coalesced loads)
    {
      const us8v* pa1 = (const us8v*)(a1 + ((size_t)ad * 8 + r) * DDIM);
      float sa = 0.f;
#pragma unroll
      for (int i = 0; i < 4; ++i) {
        const int g = l5 + 32 * i;
        us8v va = pa1[g];
        float4 z0 = zg[g * 2], z1 = zg[g * 2 + 1];
        sa += z0.x * bf2f(va[0]) + z0.y * bf2f(va[1]) +
              z0.z * bf2f(va[2]) + z0.w * bf2f(va[3]) +
              z1.x * bf2f(va[4]) + z1.y * bf2f(va[5]) +
              z1.z * bf2f(va[6]) + z1.w * bf2f(va[7]);
      }
#pragma unroll
      for (int o = 16; o; o >>= 1) sa += __shfl_xor(sa, o, 64);
      if (l5 == 0) t1s[r] = sa;
    }
    __syncthreads();
    // h = silu(h_pre + B1 t1)
    {
      float t1r[8];
#pragma unroll
      for (int q = 0; q < 8; ++q) t1r[q] = t1s[q];
      const unsigned short* pb1 = b1 + (size_t)ad * HDIM * 8;
      const unsigned short* ph = hpre + (size_t)b * HDIM;
#pragma unroll
      for (int j = 0; j < 8; ++j) {
        const int hh_i = tid + 256 * j;
        us8v row = *(const us8v*)&pb1[(size_t)hh_i * 8];
        float d1 = 0.f;
#pragma unroll
        for (int q = 0; q < 8; ++q) d1 += t1r[q] * bf2f(row[q]);
        const float hh = bf2f(ph[hh_i]) + d1;  // SCALE = 1
        hl[hh_i] = hh / (1.f + __expf(-hh));
      }
    }
    __syncthreads();
    // t2[r] = h . a2[ad][r][:]   (bf16x8 coalesced loads)
    {
      const us8v* pa2 = (const us8v*)(a2 + ((size_t)ad * 8 + r) * HDIM);
      float sa = 0.f;
#pragma unroll
      for (int i = 0; i < 8; ++i) {
        const int g = l5 + 32 * i;
        us8v va = pa2[g];
        const float* hp = &hl[g * 8];
        sa += hp[0] * bf2f(va[0]) + hp[1] * bf2f(va[1]) +
              hp[2] * bf2f(va[2]) + hp[3] * bf2f(va[3]) +
              hp[4] * bf2f(va[4]) + hp[5] * bf2f(va[5]) +
              hp[6] * bf2f(va[6]) + hp[7] * bf2f(va[7]);
      }
#pragma unroll
      for (int o = 16; o; o >>= 1) sa += __shfl_xor(sa, o, 64);
      if (l5 == 0) t2s[r] = sa;
    }
    __syncthreads();
    // d2 accumulate
    {
      float t2r[8];
#pragma unroll
      for (int q = 0; q < 8; ++q) t2r[q] = t2s[q];
      const unsigned short* pb2 = b2 + (size_t)ad * DDIM * 8;
#pragma unroll
      for (int j = 0; j < 4; ++j) {
        const int d = tid + 256 * j;
        us8v row = *(const us8v*)&pb2[(size_t)d * 8];
        float d2 = 0.f;
#pragma unroll
        for (int q = 0; q < 8; ++q) d2 += t2r[q] * bf2f(row[q]);
        acc[j] += ww * d2;  // SCALE = 1
      }
    }
    __syncthreads();  // protect t1s/hl/t2s before next slot
  }
#pragma unroll
  for (int j = 0; j < 4; ++j) {
    const int d = tid + 256 * j;
    out0[(size_t)b * DDIM + d] =
        zl[d] + wsum * outpre[(size_t)b * DDIM + d] + acc[j];
  }
}

// ---------------------------------------------------------------------------
extern "C" void kernel_launch(void* const* d_in, const int* in_sizes, int n_in,
                              void* d_out, int out_size, void* d_ws, size_t ws_size,
                              hipStream_t stream)
{
  (void)in_sizes; (void)n_in; (void)out_size; (void)ws_size;
  const float* z     = (const float*)d_in[0];
  const int*   p_cap = (const int*)d_in[2];
  const int*   p_ban = (const int*)d_in[3];
  const float* p_tau = (const float*)d_in[4];
  const float* p_eps = (const float*)d_in[5];
  const float* fc1w  = (const float*)d_in[6];
  const float* fc1b  = (const float*)d_in[7];
  const float* fc2w  = (const float*)d_in[8];
  const float* fc2b  = (const float*)d_in[9];
  const float* proto = (const float*)d_in[10];
  const float* ak    = (const float*)d_in[11];
  const float* ebias = (const float*)d_in[12];
  const float* a1    = (const float*)d_in[13];
  const float* b1    = (const float*)d_in[14];
  const float* a2    = (const float*)d_in[15];
  const float* b2    = (const float*)d_in[16];
  float* out = (float*)d_out;
  char* ws = (char*)d_ws;

  unsigned short* zbf    = (unsigned short*)(ws + WS_ZBF);
  unsigned short* fc1wbf = (unsigned short*)(ws + WS_FC1WBF);
  unsigned short* fc2wbf = (unsigned short*)(ws + WS_FC2WBF);
  unsigned short* hprebf = (unsigned short*)(ws + WS_HPREBF);
  float*          outpre = (float*)(ws + WS_OUTPRE);
  unsigned short* a1bf   = (unsigned short*)(ws + WS_A1BF);
  unsigned short* b1bf   = (unsigned short*)(ws + WS_B1BF);
  unsigned short* a2bf   = (unsigned short*)(ws + WS_A2BF);
  unsigned short* b2bf   = (unsigned short*)(ws + WS_B2BF);
  unsigned*       cands  = (unsigned*)(ws + WS_CANDS);
  float*          cvals  = (float*)(ws + WS_CVALS);
  unsigned*       argpk  = (unsigned*)(ws + WS_ARGPK);
  int*            asgn   = (int*)(ws + WS_ASGN);
  float*          asgnw  = (float*)(ws + WS_ASGNW);

  k1_probs_scores<<<512, 256, 0, stream>>>(
      z, proto, ebias, ak, p_tau, p_eps, p_ban, zbf, out, cands, cvals, argpk,
      fc1w, fc2w, a1, b1, a2, b2, fc1wbf, fc2wbf, a1bf, b1bf, a2bf, b2bf);

  // fc1 GEMM (256 tiles) + router (block 0), overlapped
  gemm_router<<<1 + (NTOK / 128) * (HDIM / 128), 256, 0, stream>>>(
      zbf, fc1wbf, fc1b, (void*)hprebf, NTOK, HDIM, DDIM,
      cands, cvals, argpk, p_cap, out, asgn, asgnw);

  // fc2: [2048,2048] x [1024,2048]^T -> +bias -> f32 out_pre
  gemm_bt1<<<(NTOK / 128) * (DDIM / 128), 256, 0, stream>>>(
      hprebf, fc2wbf, fc2b, (void*)outpre, NTOK, DDIM, HDIM);

  k5_lora<<<NTOK, 256, 0, stream>>>(
      z, hprebf, outpre, asgn, asgnw, a1bf, b1bf, a2bf, b2bf, out, out);
}

// Round 5
// 310.087 us; speedup vs baseline: 1.0852x; 1.0468x over previous
//
#include <hip/hip_runtime.h>
#include <stdint.h>

// ---------------------------------------------------------------------------
// MoELatent: B=2048 D=1024 H=2048 E=16 W=4 R=8, top_k=2, cand_k=8
// ---------------------------------------------------------------------------
#define NTOK 2048
#define DDIM 1024
#define HDIM 2048
#define NEXP 16

// output (float) element offsets, in reference return order
#define O_PROBS 2097152   // [2048,16]
#define O_USED  2129920   // [2048,16]
#define O_AIDX  2162688   // [2048,2]
#define O_AW    2166784   // [2048,2]
#define O_HIT   2170880   // scalar
#define O_EVE   2170881   // [2,2048] slot-major
#define O_EVA   2174977   // [2,2048]

// workspace byte offsets — constexpr chain (round-1 lesson: never hand-type)
static constexpr size_t WS_ZBF    = 0;
static constexpr size_t WS_FC1WBF = WS_ZBF    + (size_t)NTOK * DDIM * 2;
static constexpr size_t WS_FC2WBF = WS_FC1WBF + (size_t)HDIM * DDIM * 2;
static constexpr size_t WS_HPREBF = WS_FC2WBF + (size_t)DDIM * HDIM * 2;
static constexpr size_t WS_OUTPRE = WS_HPREBF + (size_t)NTOK * HDIM * 2;
static constexpr size_t WS_A1BF   = WS_OUTPRE + (size_t)NTOK * DDIM * 4;
static constexpr size_t WS_B1BF   = WS_A1BF   + (size_t)16 * 4 * 8 * 1024 * 2;
static constexpr size_t WS_A2BF   = WS_B1BF   + (size_t)16 * 4 * 2048 * 8 * 2;
static constexpr size_t WS_B2BF   = WS_A2BF   + (size_t)16 * 4 * 8 * 2048 * 2;
static constexpr size_t WS_CANDS  = WS_B2BF   + (size_t)16 * 4 * 1024 * 8 * 2;
static constexpr size_t WS_CVALS  = WS_CANDS  + (size_t)NTOK * 4;
static constexpr size_t WS_ARGPK  = WS_CVALS  + (size_t)NTOK * 8 * 4;
static constexpr size_t WS_ASGN   = WS_ARGPK  + (size_t)NTOK * 4;
static constexpr size_t WS_ASGNW  = WS_ASGN   + (size_t)NTOK * 4;

typedef __bf16 v8bf __attribute__((ext_vector_type(8)));
typedef float v4f __attribute__((ext_vector_type(4)));
typedef unsigned short us8v __attribute__((ext_vector_type(8)));

__device__ __forceinline__ unsigned short f2bf(float f) {
  unsigned u = __float_as_uint(f);
  u = u + 0x7fffu + ((u >> 16) & 1u);          // round-to-nearest-even
  return (unsigned short)(u >> 16);
}
__device__ __forceinline__ float bf2f(unsigned short s) {
  return __uint_as_float(((unsigned)s) << 16);
}
__device__ __forceinline__ void gload_lds16(const void* g, void* l) {
  __builtin_amdgcn_global_load_lds(
      (const __attribute__((address_space(1))) void*)g,
      (__attribute__((address_space(3))) void*)l, 16, 0, 0);
}
__device__ __forceinline__ float dot4(float4 a, float4 b) {
  return a.x * b.x + a.y * b.y + a.z * b.z + a.w * b.w;
}

// ---------------------------------------------------------------------------
// K1: 512 blocks x 256 thr, 4 tokens/block (one token per wave).
// probs + top-8 cands/cvals + adapter-argmax packed + z->bf16.
// ---------------------------------------------------------------------------
__global__ __launch_bounds__(256) void k1_probs_scores(
    const float* __restrict__ z, const float* __restrict__ proto,
    const float* __restrict__ ebias, const float* __restrict__ ak,
    const float* __restrict__ p_tau, const float* __restrict__ p_eps,
    const int* __restrict__ p_ban,
    unsigned short* __restrict__ zbf, float* __restrict__ out,
    unsigned* __restrict__ cands, float* __restrict__ cvals,
    unsigned* __restrict__ argpk)
{
  __shared__ float zs[4][DDIM];
  const int tid = threadIdx.x;
  const int tb = blockIdx.x * 4;
#pragma unroll
  for (int i = 0; i < 4; ++i) {
    const int col = tid * 4;
    float4 v = *(const float4*)&z[(size_t)(tb + i) * DDIM + col];
    *(float4*)&zs[i][col] = v;
    ushort4 bv;
    bv.x = f2bf(v.x); bv.y = f2bf(v.y); bv.z = f2bf(v.z); bv.w = f2bf(v.w);
    *(ushort4*)&zbf[(size_t)(tb + i) * DDIM + col] = bv;
  }
  __syncthreads();
  const int wv = tid >> 6, l = tid & 63;
  const int t = tb + wv;                       // one token per wave
  const float tau = fmaxf(p_tau[0], 1e-6f);
  const float eps = p_eps[0];
  const int ban = p_ban[0];
  const float4* z4 = (const float4*)&zs[wv][0];

  // ---- logits + softmax + top-8 ----
  float lg_mine = -3.0e38f;
  for (int e = 0; e < NEXP; ++e) {
    const float4* pr = (const float4*)&proto[(size_t)e * DDIM];
    float s = 0.f;
#pragma unroll
    for (int i = 0; i < 4; ++i) s += dot4(z4[l + 64 * i], pr[l + 64 * i]);
#pragma unroll
    for (int o = 32; o; o >>= 1) s += __shfl_xor(s, o, 64);
    float lg = s / tau + ebias[e];
    if (e == ban) lg = -1e9f;
    if (l == e) lg_mine = lg;
  }
  float v0 = (l < NEXP) ? lg_mine : -3.0e38f;
  float mx = v0;
#pragma unroll
  for (int o = 8; o; o >>= 1) mx = fmaxf(mx, __shfl_xor(mx, o, 64));
  float ex = (l < NEXP) ? expf(v0 - mx) : 0.f;
  float sm = ex;
#pragma unroll
  for (int o = 8; o; o >>= 1) sm += __shfl_xor(sm, o, 64);
  float p = (1.f - eps) * (ex / sm) + eps / (float)NEXP;
  if (l < NEXP) out[O_PROBS + (size_t)t * NEXP + l] = p;
  // top-8, jax.lax.top_k tie-break: value desc, index asc
  float cur = (l < NEXP) ? p : -1.f;
  unsigned pack = 0;
  float myv = 0.f;
  for (int r = 0; r < 8; ++r) {
    float bv = cur; int bi = l;
#pragma unroll
    for (int o = 32; o; o >>= 1) {
      float ov = __shfl_xor(bv, o, 64);
      int oi = __shfl_xor(bi, o, 64);
      if (ov > bv || (ov == bv && oi < bi)) { bv = ov; bi = oi; }
    }
    pack |= ((unsigned)bi) << (4 * r);
    if (l == r) myv = bv;
    if (l == bi) cur = -1.f;
  }
  if (l == 0) cands[t] = pack;
  if (l < 8) cvals[(size_t)t * 8 + l] = myv;

  // ---- adapter scores + per-expert argmax, packed 2b x 16 ----
  const int h = l >> 5, l32 = l & 31;
  unsigned pk = 0;
  float best = -3.0e38f; int bidx = 0;
  for (int j = 0; j < 32; ++j) {
    const int rr = h * 32 + j;
    const float4* ar = (const float4*)&ak[(size_t)rr * DDIM];
    float s = 0.f;
#pragma unroll
    for (int i = 0; i < 8; ++i) s += dot4(z4[l32 + 32 * i], ar[l32 + 32 * i]);
#pragma unroll
    for (int o = 16; o; o >>= 1) s += __shfl_xor(s, o, 64);
    const int w = rr & 3;
    if (w == 0) { best = s; bidx = 0; }
    else if (s > best) { best = s; bidx = w; }
    if (w == 3) pk |= ((unsigned)bidx) << (2 * (rr >> 2));
  }
  unsigned other = __shfl_xor(pk, 32, 64);
  unsigned full = pk | other;
  if (l == 0) argpk[t] = full;
}

// ---------------------------------------------------------------------------
// K2: block 0 = router (1024 thr, wave-per-expert crossing);
//     blocks 1..CONVB = f32->bf16 weight conversions.
// Thread tid owns tokens {tid, tid+1024}; chunk q covers tokens [q*64,q*64+64)
// (16*64==1024, so chunk(t) == t>>6 uniformly).
// ---------------------------------------------------------------------------
#define CONVB 224

__device__ __forceinline__ void route_decide(unsigned c, int avail,
                                             unsigned& m, int& dec) {
  unsigned flags = 0;
#pragma unroll
  for (int j = 0; j < 8; ++j) {
    const int e = (c >> (4 * j)) & 15;
    flags |= ((unsigned)(avail >> e) & 1u) << j;
  }
  const int pc = __popc(flags);
  const int sc = pc < 2 ? pc : 2;
  const int j0 = __ffs(flags) - 1;
  const int j1 = __ffs(flags & (flags - 1)) - 1;
  const int r0 = sc > 0 ? j0 : 0;
  const int r1 = sc > 1 ? j1 : 0;
  const int e0 = (c >> (4 * r0)) & 15;
  const int e1 = (c >> (4 * r1)) & 15;
  m = (sc > 0 ? (1u << e0) : 0u) | (sc > 1 ? (1u << e1) : 0u);
  dec = e0 | (e1 << 4) | (r0 << 8) | (r1 << 11) | (sc << 14);
}

struct RouterSm {
  unsigned long long bal[32][17];   // [chunk][expert], padded
  int cap[16], T[16];
  int avail, t0, tfin, done, hits;
};

__global__ __launch_bounds__(1024) void k2_route_conv(
    const unsigned* __restrict__ cands, const float* __restrict__ cvals,
    const unsigned* __restrict__ argpk, const int* __restrict__ p_cap,
    float* __restrict__ out, int* __restrict__ asgn, float* __restrict__ asgnw,
    const float* __restrict__ fc1w, const float* __restrict__ fc2w,
    const float* __restrict__ a1, const float* __restrict__ b1,
    const float* __restrict__ a2, const float* __restrict__ b2,
    unsigned short* __restrict__ fc1wbf, unsigned short* __restrict__ fc2wbf,
    unsigned short* __restrict__ a1bf, unsigned short* __restrict__ b1bf,
    unsigned short* __restrict__ a2bf, unsigned short* __restrict__ b2bf)
{
  __shared__ RouterSm S;
  const int tid = threadIdx.x;
  if (blockIdx.x != 0) {
    // weight conversions: 224 blocks x 1024 thr x 8 iters = 1,835,008 float4
    size_t j = (size_t)(blockIdx.x - 1) * 1024 + tid;
    const size_t stride = (size_t)CONVB * 1024;
    for (; j < 1835008ull; j += stride) {
      const float* src; unsigned short* dst; size_t off;
      if (j < 524288) { src = fc1w; dst = fc1wbf; off = j; }
      else if (j < 1048576) { src = fc2w; dst = fc2wbf; off = j - 524288; }
      else if (j < 1179648) { src = a1; dst = a1bf; off = j - 1048576; }
      else if (j < 1441792) { src = b1; dst = b1bf; off = j - 1179648; }
      else if (j < 1703936) { src = a2; dst = a2bf; off = j - 1441792; }
      else { src = b2; dst = b2bf; off = j - 1703936; }
      float4 v = *(const float4*)&src[off * 4];
      ushort4 bv;
      bv.x = f2bf(v.x); bv.y = f2bf(v.y); bv.z = f2bf(v.z); bv.w = f2bf(v.w);
      *(ushort4*)&dst[off * 4] = bv;
    }
    return;
  }
  // ---- router ----
  const int w = tid >> 6, l = tid & 63;
  if (tid == 0) { S.avail = 0xFFFF; S.t0 = 0; S.done = 0; S.hits = 0; }
  if (tid < 16) S.cap[tid] = 0;
  const int capl = max(1, p_cap[0]);
  const unsigned cA = cands[tid], cB = cands[tid + 1024];
  const unsigned aA = argpk[tid], aB = argpk[tid + 1024];
  int hits = 0;
  __syncthreads();

  for (int round = 0; round < 20; ++round) {
    const int t0 = S.t0;
    const int avail = S.avail;
    unsigned mA = 0, mB = 0;
    int dA = 0, dB = 0;
    if (tid >= t0) route_decide(cA, avail, mA, dA);
    if (tid + 1024 >= t0) route_decide(cB, avail, mB, dB);
    // ballots for chunk w (token tid) and chunk w+16 (token tid+1024)
    if (w * 64 + 63 < t0) {
      if (l < 16) S.bal[w][l] = 0ull;
    } else {
      for (int av = avail; av; av &= av - 1) {
        const int e = __ffs(av) - 1;
        unsigned long long b = __ballot((mA >> e) & 1);
        if (l == e) S.bal[w][e] = b;
      }
    }
    if (w * 64 + 1024 + 63 < t0) {
      if (l < 16) S.bal[w + 16][l] = 0ull;
    } else {
      for (int av = avail; av; av &= av - 1) {
        const int e = __ffs(av) - 1;
        unsigned long long b = __ballot((mB >> e) & 1);
        if (l == e) S.bal[w + 16][e] = b;
      }
    }
    __syncthreads();
    // crossing: wave w owns expert w. Quick total-popcount gate, then locate.
    unsigned long long bm = 0;
    const bool eav = (avail >> w) & 1;
    {
      int myT = 0x7FFFFFFF;
      if (eav) {
        int cnt = 0;
        if (l < 32) { bm = S.bal[l][w]; cnt = __popcll(bm); }
        int tot = cnt;
#pragma unroll
        for (int o = 32; o; o >>= 1) tot += __shfl_xor(tot, o, 64);
        const int rem = capl - S.cap[w];
        if (tot >= rem) {
          int incl = cnt;
#pragma unroll
          for (int o = 1; o < 32; o <<= 1) {
            int u = __shfl_up(incl, o, 64);
            if (l >= o) incl += u;
          }
          if (l < 32) {
            const int need = rem - (incl - cnt);
            if (need >= 1 && need <= cnt) {
              unsigned long long bb = bm;
              for (int i = 1; i < need; ++i) bb &= bb - 1;
              myT = l * 64 + (__ffsll((unsigned long long)bb) - 1);
            }
          }
#pragma unroll
          for (int o = 32; o; o >>= 1) myT = min(myT, __shfl_xor(myT, o, 64));
        }
      }
      if (l == 0) S.T[w] = myT;
    }
    __syncthreads();
    if (w == 0) {
      int v = (l < 16) ? S.T[l] : 0x7FFFFFFF;
      int ts = v;
#pragma unroll
      for (int o = 32; o; o >>= 1) ts = min(ts, __shfl_xor(ts, o, 64));
      const int done = (ts == 0x7FFFFFFF);
      const int tf = done ? (NTOK - 1) : ts;
      if (l == 0) { S.tfin = tf; S.done = done; S.t0 = tf + 1; }
      if (l < 16 && v == ts) atomicAnd(&S.avail, ~(1 << l));
    }
    __syncthreads();
    const int tfin = S.tfin;
    // cap[w] += takes in [t0, tfin] (cached bm)
    if (eav) {
      int c2 = 0;
      if (l < 32) {
        const int hi = tfin - l * 64;
        unsigned long long mk =
            (hi < 0) ? 0ull : (hi >= 63 ? ~0ull : ((1ull << (hi + 1)) - 1ull));
        c2 = __popcll(bm & mk);
      }
#pragma unroll
      for (int o = 32; o; o >>= 1) c2 += __shfl_xor(c2, o, 64);
      if (l == 0) S.cap[w] += c2;
    }
    // finalize tokens in [t0, tfin]
#pragma unroll
    for (int half = 0; half < 2; ++half) {
      const int t = tid + half * 1024;
      const int d = half ? dB : dA;
      const unsigned ap = half ? aB : aA;
      if (t < t0 || t > tfin) continue;
      const int e0 = d & 15, e1 = (d >> 4) & 15;
      const int r0 = (d >> 8) & 7, r1 = (d >> 11) & 7, sc = (d >> 14) & 3;
      const int a0 = (ap >> (2 * e0)) & 3, a1i = (ap >> (2 * e1)) & 3;
      asgn[t] = e0 | (e1 << 4) | (a0 << 8) | (a1i << 10) | (sc << 12);
      asgnw[t * 2 + 0] = sc > 0 ? cvals[(size_t)t * 8 + r0] : 0.f;
      asgnw[t * 2 + 1] = sc > 1 ? cvals[(size_t)t * 8 + r1] : 0.f;
      hits += (sc > 0 && r0 > 0) + (sc > 1 && r1 > 0);
    }
    __syncthreads();
    if (S.done) break;
  }
#pragma unroll
  for (int o = 32; o; o >>= 1) hits += __shfl_xor(hits, o, 64);
  if (l == 0) atomicAdd(&S.hits, hits);
  __syncthreads();
  if (tid == 0) out[O_HIT] = (float)S.hits / (float)(NTOK * 2);
}

// ---------------------------------------------------------------------------
// bf16 GEMM body: C = A[M,K] * B[N,K]^T, 128x128 tile, BK=64, 4 waves,
// mfma_f32_16x16x32_bf16, global_load_lds width 16 (m97 structure).
// EPI 0: silu(x+bias) -> bf16. EPI 1: x+bias -> f32.
// ---------------------------------------------------------------------------
template <int EPI>
__device__ __forceinline__ void gemm_body(
    unsigned short* As, unsigned short* Bs, int bid,
    const unsigned short* __restrict__ A, const unsigned short* __restrict__ Bm,
    const float* __restrict__ bias, void* __restrict__ Cout,
    int M, int N, int K)
{
  const int tid = threadIdx.x;
  const int wv = tid >> 6, l = tid & 63;
  const int ntile = N >> 7;
  const int trow = (bid / ntile) << 7;
  const int tcol = (bid % ntile) << 7;
  const int wr = wv >> 1, wc = wv & 1;
  v4f acc[4][4];
#pragma unroll
  for (int m = 0; m < 4; ++m)
#pragma unroll
    for (int n = 0; n < 4; ++n) acc[m][n] = (v4f){0.f, 0.f, 0.f, 0.f};

  const int lrow8 = l >> 3;
  const int lcol8 = (l & 7) << 3;
  const unsigned short* gA = A + (size_t)trow * K;
  const unsigned short* gB = Bm + (size_t)tcol * K;
  const int fr = l & 15, kof = (l >> 4) << 3;

  for (int k0 = 0; k0 < K; k0 += 64) {
    __syncthreads();
#pragma unroll
    for (int i = 0; i < 4; ++i) {
      const int s = (wv << 2) + i;  // segment 0..15 = 8 rows each
      gload_lds16(gA + (size_t)(s * 8 + lrow8) * K + k0 + lcol8, &As[s * 512]);
      gload_lds16(gB + (size_t)(s * 8 + lrow8) * K + k0 + lcol8, &Bs[s * 512]);
    }
    __syncthreads();
    v8bf af[4][2], bf[4][2];
#pragma unroll
    for (int m = 0; m < 4; ++m) {
      const int row = wr * 64 + m * 16 + fr;
      af[m][0] = *(const v8bf*)&As[row * 64 + kof];
      af[m][1] = *(const v8bf*)&As[row * 64 + 32 + kof];
    }
#pragma unroll
    for (int n = 0; n < 4; ++n) {
      const int row = wc * 64 + n * 16 + fr;
      bf[n][0] = *(const v8bf*)&Bs[row * 64 + kof];
      bf[n][1] = *(const v8bf*)&Bs[row * 64 + 32 + kof];
    }
#pragma unroll
    for (int ks = 0; ks < 2; ++ks)
#pragma unroll
      for (int m = 0; m < 4; ++m)
#pragma unroll
        for (int n = 0; n < 4; ++n)
          acc[m][n] = __builtin_amdgcn_mfma_f32_16x16x32_bf16(
              af[m][ks], bf[n][ks], acc[m][n], 0, 0, 0);
  }
  // epilogue: C/D layout col=lane&15, row=(lane>>4)*4+j  [m89/m91]
  const int fq = l >> 4;
#pragma unroll
  for (int m = 0; m < 4; ++m)
#pragma unroll
    for (int n = 0; n < 4; ++n) {
      const int col = tcol + wc * 64 + n * 16 + fr;
      const float bc = bias[col];
#pragma unroll
      for (int j = 0; j < 4; ++j) {
        const int row = trow + wr * 64 + m * 16 + fq * 4 + j;
        const float v = acc[m][n][j] + bc;
        if (EPI == 0) {
          const float sv = v / (1.f + __expf(-v));
          ((unsigned short*)Cout)[(size_t)row * N + col] = f2bf(sv);
        } else {
          ((float*)Cout)[(size_t)row * N + col] = v;
        }
      }
    }
}

__global__ __launch_bounds__(256) void gemm_bt0(
    const unsigned short* __restrict__ A, const unsigned short* __restrict__ Bm,
    const float* __restrict__ bias, void* __restrict__ Cout,
    int M, int N, int K)
{
  __shared__ __align__(16) char smem[32768];
  gemm_body<0>((unsigned short*)smem, (unsigned short*)smem + 8192,
               blockIdx.x, A, Bm, bias, Cout, M, N, K);
}

__global__ __launch_bounds__(256) void gemm_bt1(
    const unsigned short* __restrict__ A, const unsigned short* __restrict__ Bm,
    const float* __restrict__ bias, void* __restrict__ Cout,
    int M, int N, int K)
{
  __shared__ __align__(16) char smem[32768];
  gemm_body<1>((unsigned short*)smem, (unsigned short*)smem + 8192,
               blockIdx.x, A, Bm, bias, Cout, M, N, K);
}

// ---------------------------------------------------------------------------
// K5: per-token LoRA adapters + final combine + bulk routing outputs
// ---------------------------------------------------------------------------
__global__ __launch_bounds__(256) void k5_lora(
    const float* __restrict__ z, const unsigned short* __restrict__ hpre,
    const float* __restrict__ outpre, const int* __restrict__ asgn,
    const float* __restrict__ asgnw,
    const unsigned short* __restrict__ a1, const unsigned short* __restrict__ b1,
    const unsigned short* __restrict__ a2, const unsigned short* __restrict__ b2,
    float* __restrict__ out0, float* __restrict__ out)
{
  __shared__ float zl[DDIM];
  __shared__ float hl[HDIM];
  __shared__ float t1s[8], t2s[8];
  const int b = blockIdx.x, tid = threadIdx.x;
  {
    float4 v = *(const float4*)&z[(size_t)b * DDIM + tid * 4];
    *(float4*)&zl[tid * 4] = v;
  }
  const int pk = asgn[b];
  const int sc = (pk >> 12) & 3;
  const int eA0 = pk & 15, eA1 = (pk >> 4) & 15;
  const int aA0 = (pk >> 8) & 3, aA1 = (pk >> 10) & 3;
  const float w0 = asgnw[b * 2 + 0], w1 = asgnw[b * 2 + 1];
  // bulk routing outputs (kept out of the serial router)
  if (tid < 16)
    out[O_USED + (size_t)b * 16 + tid] =
        (float)((sc > 0 && tid == eA0) || (sc > 1 && tid == eA1));
  if (tid == 0) {
    out[O_AIDX + (size_t)b * 2 + 0] = sc > 0 ? (float)eA0 : -1.f;
    out[O_AIDX + (size_t)b * 2 + 1] = sc > 1 ? (float)eA1 : -1.f;
    out[O_AW + (size_t)b * 2 + 0] = w0;
    out[O_AW + (size_t)b * 2 + 1] = w1;
    out[O_EVE + b] = sc > 0 ? (float)eA0 : -1.f;
    out[O_EVE + NTOK + b] = sc > 1 ? (float)eA1 : -1.f;
    out[O_EVA + b] = sc > 0 ? (float)aA0 : -1.f;
    out[O_EVA + NTOK + b] = sc > 1 ? (float)aA1 : -1.f;
  }
  float acc[4] = {0.f, 0.f, 0.f, 0.f};
  float wsum = 0.f;
  const int r = tid >> 5, l5 = tid & 31;
  const float4* zg = (const float4*)&z[(size_t)b * DDIM];   // L1/L2-hot
  __syncthreads();

  for (int s = 0; s < 2; ++s) {
    if (s >= sc) continue;  // uniform across block
    const float ww = (s == 0) ? w0 : w1;
    const int ad = ((s == 0) ? eA0 : eA1) * 4 + ((s == 0) ? aA0 : aA1);
    wsum += ww;
    // t1[r] = z . a1[ad][r][:]   (bf16x8 coalesced loads)
    {
      const us8v* pa1 = (const us8v*)(a1 + ((size_t)ad * 8 + r) * DDIM);
      float sa = 0.f;
#pragma unroll
      for (int i = 0; i < 4; ++i) {
        const int g = l5 + 32 * i;
        us8v va = pa1[g];
        float4 z0 = zg[g * 2], z1 = zg[g * 2 + 1];
        sa += z0.x * bf2f(va[0]) + z0.y * bf2f(va[1]) +
              z0.z * bf2f(va[2]) + z0.w * bf2f(va[3]) +
              z1.x * bf2f(va[4]) + z1.y * bf2f(va[5]) +
              z1.z * bf2f(va[6]) + z1.w * bf2f(va[7]);
      }
#pragma unroll
      for (int o = 16; o; o >>= 1) sa += __shfl_xor(sa, o, 64);
      if (l5 == 0) t1s[r] = sa;
    }
    __syncthreads();
    // h = silu(h_pre + B1 t1)
    {
      float t1r[8];
#pragma unroll
      for (int q = 0; q < 8; ++q) t1r[q] = t1s[q];
      const unsigned short* pb1 = b1 + (size_t)ad * HDIM * 8;
      const unsigned short* ph = hpre + (size_t)b * HDIM;
#pragma unroll
      for (int j = 0; j < 8; ++j) {
        const int hh_i = tid + 256 * j;
        us8v row = *(const us8v*)&pb1[(size_t)hh_i * 8];
        float d1 = 0.f;
#pragma unroll
        for (int q = 0; q < 8; ++q) d1 += t1r[q] * bf2f(row[q]);
        const float hh = bf2f(ph[hh_i]) + d1;  // SCALE = 1
        hl[hh_i] = hh / (1.f + __expf(-hh));
      }
    }
    __syncthreads();
    // t2[r] = h . a2[ad][r][:]   (bf16x8 coalesced loads)
    {
      const us8v* pa2 = (const us8v*)(a2 + ((size_t)ad * 8 + r) * HDIM);
      float sa = 0.f;
#pragma unroll
      for (int i = 0; i < 8; ++i) {
        const int g = l5 + 32 * i;
        us8v va = pa2[g];
        const float* hp = &hl[g * 8];
        sa += hp[0] * bf2f(va[0]) + hp[1] * bf2f(va[1]) +
              hp[2] * bf2f(va[2]) + hp[3] * bf2f(va[3]) +
              hp[4] * bf2f(va[4]) + hp[5] * bf2f(va[5]) +
              hp[6] * bf2f(va[6]) + hp[7] * bf2f(va[7]);
      }
#pragma unroll
      for (int o = 16; o; o >>= 1) sa += __shfl_xor(sa, o, 64);
      if (l5 == 0) t2s[r] = sa;
    }
    __syncthreads();
    // d2 accumulate
    {
      float t2r[8];
#pragma unroll
      for (int q = 0; q < 8; ++q) t2r[q] = t2s[q];
      const unsigned short* pb2 = b2 + (size_t)ad * DDIM * 8;
#pragma unroll
      for (int j = 0; j < 4; ++j) {
        const int d = tid + 256 * j;
        us8v row = *(const us8v*)&pb2[(size_t)d * 8];
        float d2 = 0.f;
#pragma unroll
        for (int q = 0; q < 8; ++q) d2 += t2r[q] * bf2f(row[q]);
        acc[j] += ww * d2;  // SCALE = 1
      }
    }
    __syncthreads();  // protect t1s/hl/t2s before next slot
  }
#pragma unroll
  for (int j = 0; j < 4; ++j) {
    const int d = tid + 256 * j;
    out0[(size_t)b * DDIM + d] =
        zl[d] + wsum * outpre[(size_t)b * DDIM + d] + acc[j];
  }
}

// ---------------------------------------------------------------------------
extern "C" void kernel_launch(void* const* d_in, const int* in_sizes, int n_in,
                              void* d_out, int out_size, void* d_ws, size_t ws_size,
                              hipStream_t stream)
{
  (void)in_sizes; (void)n_in; (void)out_size; (void)ws_size;
  const float* z     = (const float*)d_in[0];
  const int*   p_cap = (const int*)d_in[2];
  const int*   p_ban = (const int*)d_in[3];
  const float* p_tau = (const float*)d_in[4];
  const float* p_eps = (const float*)d_in[5];
  const float* fc1w  = (const float*)d_in[6];
  const float* fc1b  = (const float*)d_in[7];
  const float* fc2w  = (const float*)d_in[8];
  const float* fc2b  = (const float*)d_in[9];
  const float* proto = (const float*)d_in[10];
  const float* ak    = (const float*)d_in[11];
  const float* ebias = (const float*)d_in[12];
  const float* a1    = (const float*)d_in[13];
  const float* b1    = (const float*)d_in[14];
  const float* a2    = (const float*)d_in[15];
  const float* b2    = (const float*)d_in[16];
  float* out = (float*)d_out;
  char* ws = (char*)d_ws;

  unsigned short* zbf    = (unsigned short*)(ws + WS_ZBF);
  unsigned short* fc1wbf = (unsigned short*)(ws + WS_FC1WBF);
  unsigned short* fc2wbf = (unsigned short*)(ws + WS_FC2WBF);
  unsigned short* hprebf = (unsigned short*)(ws + WS_HPREBF);
  float*          outpre = (float*)(ws + WS_OUTPRE);
  unsigned short* a1bf   = (unsigned short*)(ws + WS_A1BF);
  unsigned short* b1bf   = (unsigned short*)(ws + WS_B1BF);
  unsigned short* a2bf   = (unsigned short*)(ws + WS_A2BF);
  unsigned short* b2bf   = (unsigned short*)(ws + WS_B2BF);
  unsigned*       cands  = (unsigned*)(ws + WS_CANDS);
  float*          cvals  = (float*)(ws + WS_CVALS);
  unsigned*       argpk  = (unsigned*)(ws + WS_ARGPK);
  int*            asgn   = (int*)(ws + WS_ASGN);
  float*          asgnw  = (float*)(ws + WS_ASGNW);

  k1_probs_scores<<<512, 256, 0, stream>>>(
      z, proto, ebias, ak, p_tau, p_eps, p_ban, zbf, out, cands, cvals, argpk);

  k2_route_conv<<<1 + CONVB, 1024, 0, stream>>>(
      cands, cvals, argpk, p_cap, out, asgn, asgnw,
      fc1w, fc2w, a1, b1, a2, b2,
      fc1wbf, fc2wbf, a1bf, b1bf, a2bf, b2bf);

  // fc1: [2048,1024] x [2048,1024]^T -> silu -> bf16 h_pre
  gemm_bt0<<<(NTOK / 128) * (HDIM / 128), 256, 0, stream>>>(
      zbf, fc1wbf, fc1b, (void*)hprebf, NTOK, HDIM, DDIM);

  // fc2: [2048,2048] x [1024,2048]^T -> +bias -> f32 out_pre
  gemm_bt1<<<(NTOK / 128) * (DDIM / 128), 256, 0, stream>>>(
      hprebf, fc2wbf, fc2b, (void*)outpre, NTOK, DDIM, HDIM);

  k5_lora<<<NTOK, 256, 0, stream>>>(
      z, hprebf, outpre, asgn, asgnw, a1bf, b1bf, a2bf, b2bf, out, out);
}

// Round 6
// 279.495 us; speedup vs baseline: 1.2039x; 1.1095x over previous
//
#include <hip/hip_runtime.h>
#include <stdint.h>

// ---------------------------------------------------------------------------
// MoELatent: B=2048 D=1024 H=2048 E=16 W=4 R=8, top_k=2, cand_k=8
// ---------------------------------------------------------------------------
#define NTOK 2048
#define DDIM 1024
#define HDIM 2048
#define NEXP 16

// output (float) element offsets, in reference return order
#define O_PROBS 2097152   // [2048,16]
#define O_USED  2129920   // [2048,16]
#define O_AIDX  2162688   // [2048,2]
#define O_AW    2166784   // [2048,2]
#define O_HIT   2170880   // scalar
#define O_EVE   2170881   // [2,2048] slot-major
#define O_EVA   2174977   // [2,2048]

// workspace byte offsets — constexpr chain (round-1 lesson: never hand-type)
static constexpr size_t WS_ZBF    = 0;
static constexpr size_t WS_FC1WBF = WS_ZBF    + (size_t)NTOK * DDIM * 2;
static constexpr size_t WS_FC2WBF = WS_FC1WBF + (size_t)HDIM * DDIM * 2;
static constexpr size_t WS_HPREBF = WS_FC2WBF + (size_t)DDIM * HDIM * 2;
static constexpr size_t WS_OUTPRE = WS_HPREBF + (size_t)NTOK * HDIM * 2;
static constexpr size_t WS_A1BF   = WS_OUTPRE + (size_t)NTOK * DDIM * 4;
static constexpr size_t WS_B1BF   = WS_A1BF   + (size_t)16 * 4 * 8 * 1024 * 2;
static constexpr size_t WS_A2BF   = WS_B1BF   + (size_t)16 * 4 * 2048 * 8 * 2;
static constexpr size_t WS_B2BF   = WS_A2BF   + (size_t)16 * 4 * 8 * 2048 * 2;
static constexpr size_t WS_CANDS  = WS_B2BF   + (size_t)16 * 4 * 1024 * 8 * 2;
static constexpr size_t WS_CVALS  = WS_CANDS  + (size_t)NTOK * 4;
static constexpr size_t WS_ARGPK  = WS_CVALS  + (size_t)NTOK * 8 * 4;
static constexpr size_t WS_ASGN   = WS_ARGPK  + (size_t)NTOK * 4;
static constexpr size_t WS_ASGNW  = WS_ASGN   + (size_t)NTOK * 4;
static constexpr size_t WS_OUTPR2 = WS_ASGNW  + (size_t)NTOK * 2 * 4;
static constexpr size_t WS_TOTAL2 = WS_OUTPR2 + (size_t)NTOK * DDIM * 4;

typedef __bf16 v8bf __attribute__((ext_vector_type(8)));
typedef float v4f __attribute__((ext_vector_type(4)));
typedef unsigned short us8v __attribute__((ext_vector_type(8)));

__device__ __forceinline__ unsigned short f2bf(float f) {
  unsigned u = __float_as_uint(f);
  u = u + 0x7fffu + ((u >> 16) & 1u);          // round-to-nearest-even
  return (unsigned short)(u >> 16);
}
__device__ __forceinline__ float bf2f(unsigned short s) {
  return __uint_as_float(((unsigned)s) << 16);
}
__device__ __forceinline__ void gload_lds16(const void* g, void* l) {
  __builtin_amdgcn_global_load_lds(
      (const __attribute__((address_space(1))) void*)g,
      (__attribute__((address_space(3))) void*)l, 16, 0, 0);
}
__device__ __forceinline__ float dot4(float4 a, float4 b) {
  return a.x * b.x + a.y * b.y + a.z * b.z + a.w * b.w;
}

// ---------------------------------------------------------------------------
// K1: 512 blocks x 256 thr, 4 tokens/block.
// Phase 1: lane = weight-row (ak row l; lanes 0-15 also proto row l),
//          wave = d-quarter; 4 tokens share streamed rows via LDS-broadcast z.
//          Serial in-register reduction -> NO cross-lane shuffles.
// Phase 2: thread t<4 does one token's softmax/top-8/argmax fully lane-local.
// Tail: grid-stride f32->bf16 weight conversions (overlaps HBM with compute).
// ---------------------------------------------------------------------------
__global__ __launch_bounds__(256) void k1_scores(
    const float* __restrict__ z, const float* __restrict__ proto,
    const float* __restrict__ ebias, const float* __restrict__ ak,
    const float* __restrict__ p_tau, const float* __restrict__ p_eps,
    const int* __restrict__ p_ban,
    unsigned short* __restrict__ zbf, float* __restrict__ out,
    unsigned* __restrict__ cands, float* __restrict__ cvals,
    unsigned* __restrict__ argpk,
    const float* __restrict__ fc1w, const float* __restrict__ fc2w,
    const float* __restrict__ a1, const float* __restrict__ b1,
    const float* __restrict__ a2, const float* __restrict__ b2,
    unsigned short* __restrict__ fc1wbf, unsigned short* __restrict__ fc2wbf,
    unsigned short* __restrict__ a1bf, unsigned short* __restrict__ b1bf,
    unsigned short* __restrict__ a2bf, unsigned short* __restrict__ b2bf)
{
  __shared__ float zs[4][DDIM];        // 16 KB
  __shared__ float part[80 * 17];      // [row][tk*4+wv], stride 17 kills conflicts
  __shared__ float sc[4 * 80];         // [token][row]; rows 0-63 ak, 64-79 proto
  const int tid = threadIdx.x;
  const int tb = blockIdx.x * 4;
#pragma unroll
  for (int i = 0; i < 4; ++i) {
    const int col = tid * 4;
    float4 v = *(const float4*)&z[(size_t)(tb + i) * DDIM + col];
    *(float4*)&zs[i][col] = v;
    ushort4 bv;
    bv.x = f2bf(v.x); bv.y = f2bf(v.y); bv.z = f2bf(v.z); bv.w = f2bf(v.w);
    *(ushort4*)&zbf[(size_t)(tb + i) * DDIM + col] = bv;
  }
  __syncthreads();
  const int wv = tid >> 6, l = tid & 63;

  // ---- phase 1: ak rows (all lanes) ----
  {
    const float4* akr = (const float4*)(ak + (size_t)l * DDIM + wv * 256);
    const float4* z0 = (const float4*)&zs[0][0] + wv * 64;
    const float4* z1 = (const float4*)&zs[1][0] + wv * 64;
    const float4* z2 = (const float4*)&zs[2][0] + wv * 64;
    const float4* z3 = (const float4*)&zs[3][0] + wv * 64;
    float a0 = 0.f, a1v = 0.f, a2v = 0.f, a3 = 0.f;
#pragma unroll 8
    for (int i = 0; i < 64; ++i) {
      float4 w = akr[i];
      a0 += dot4(z0[i], w); a1v += dot4(z1[i], w);
      a2v += dot4(z2[i], w); a3 += dot4(z3[i], w);
    }
    part[l * 17 + 0 * 4 + wv] = a0;
    part[l * 17 + 1 * 4 + wv] = a1v;
    part[l * 17 + 2 * 4 + wv] = a2v;
    part[l * 17 + 3 * 4 + wv] = a3;
  }
  // ---- phase 1b: proto rows (lanes 0-15) ----
  if (l < 16) {
    const float4* pr = (const float4*)(proto + (size_t)l * DDIM + wv * 256);
    const float4* z0 = (const float4*)&zs[0][0] + wv * 64;
    const float4* z1 = (const float4*)&zs[1][0] + wv * 64;
    const float4* z2 = (const float4*)&zs[2][0] + wv * 64;
    const float4* z3 = (const float4*)&zs[3][0] + wv * 64;
    float a0 = 0.f, a1v = 0.f, a2v = 0.f, a3 = 0.f;
#pragma unroll 8
    for (int i = 0; i < 64; ++i) {
      float4 w = pr[i];
      a0 += dot4(z0[i], w); a1v += dot4(z1[i], w);
      a2v += dot4(z2[i], w); a3 += dot4(z3[i], w);
    }
    part[(64 + l) * 17 + 0 * 4 + wv] = a0;
    part[(64 + l) * 17 + 1 * 4 + wv] = a1v;
    part[(64 + l) * 17 + 2 * 4 + wv] = a2v;
    part[(64 + l) * 17 + 3 * 4 + wv] = a3;
  }
  __syncthreads();
  // combine quarter-partials
  for (int o = tid; o < 320; o += 256) {
    const int row = o >> 2, tk = o & 3;
    sc[tk * 80 + row] =
        ((part[row * 17 + tk * 4 + 0] + part[row * 17 + tk * 4 + 1]) +
         part[row * 17 + tk * 4 + 2]) + part[row * 17 + tk * 4 + 3];
  }
  __syncthreads();
  // ---- phase 2: per-token selection, fully lane-local ----
  if (tid < 4) {
    const int t = tb + tid;
    const float tau = fmaxf(p_tau[0], 1e-6f);
    const float eps = p_eps[0];
    const int ban = p_ban[0];
    float lg[16];
#pragma unroll
    for (int e = 0; e < 16; ++e) {
      float v = sc[tid * 80 + 64 + e] / tau + ebias[e];
      lg[e] = (e == ban) ? -1e9f : v;
    }
    float mx = lg[0];
#pragma unroll
    for (int e = 1; e < 16; ++e) mx = fmaxf(mx, lg[e]);
    float ex[16]; float sm = 0.f;
#pragma unroll
    for (int e = 0; e < 16; ++e) { ex[e] = expf(lg[e] - mx); sm += ex[e]; }
    float p[16];
#pragma unroll
    for (int e = 0; e < 16; ++e) {
      p[e] = (1.f - eps) * (ex[e] / sm) + eps / (float)NEXP;
      out[O_PROBS + (size_t)t * NEXP + e] = p[e];
    }
    // top-8: strict > with ascending e = value-desc, index-asc (lax.top_k)
    unsigned pack = 0, taken = 0;
#pragma unroll
    for (int r = 0; r < 8; ++r) {
      float bv = -1e30f; int bi = 0;
#pragma unroll
      for (int e = 0; e < 16; ++e) {
        const bool c = !((taken >> e) & 1u) && (p[e] > bv);
        bv = c ? p[e] : bv; bi = c ? e : bi;
      }
      taken |= 1u << bi;
      pack |= ((unsigned)bi) << (4 * r);
      cvals[(size_t)t * 8 + r] = bv;
    }
    cands[t] = pack;
    // adapter argmax per expert (first max wins, like jnp.argmax)
    unsigned apk = 0;
#pragma unroll
    for (int e = 0; e < 16; ++e) {
      float b = sc[tid * 80 + e * 4]; int bi = 0;
#pragma unroll
      for (int w = 1; w < 4; ++w) {
        const float v = sc[tid * 80 + e * 4 + w];
        if (v > b) { b = v; bi = w; }
      }
      apk |= ((unsigned)bi) << (2 * e);
    }
    argpk[t] = apk;
  }
  // ---- conversion tail: grid-stride over 1,835,008 float4s ----
  size_t j = (size_t)blockIdx.x * 256 + tid;
  const size_t stride = (size_t)512 * 256;
  for (; j < 1835008ull; j += stride) {
    const float* src; unsigned short* dst; size_t off;
    if (j < 524288) { src = fc1w; dst = fc1wbf; off = j; }
    else if (j < 1048576) { src = fc2w; dst = fc2wbf; off = j - 524288; }
    else if (j < 1179648) { src = a1; dst = a1bf; off = j - 1048576; }
    else if (j < 1441792) { src = b1; dst = b1bf; off = j - 1179648; }
    else if (j < 1703936) { src = a2; dst = a2bf; off = j - 1441792; }
    else { src = b2; dst = b2bf; off = j - 1703936; }
    float4 v = *(const float4*)&src[off * 4];
    ushort4 bv;
    bv.x = f2bf(v.x); bv.y = f2bf(v.y); bv.z = f2bf(v.z); bv.w = f2bf(v.w);
    *(ushort4*)&dst[off * 4] = bv;
  }
}

// ---------------------------------------------------------------------------
// K2: router only (1 block, 1024 thr, wave-per-expert crossing).
// Thread tid owns tokens {tid, tid+1024}; chunk q covers tokens [q*64,q*64+64).
// ---------------------------------------------------------------------------
__device__ __forceinline__ void route_decide(unsigned c, int avail,
                                             unsigned& m, int& dec) {
  unsigned flags = 0;
#pragma unroll
  for (int j = 0; j < 8; ++j) {
    const int e = (c >> (4 * j)) & 15;
    flags |= ((unsigned)(avail >> e) & 1u) << j;
  }
  const int pc = __popc(flags);
  const int sc = pc < 2 ? pc : 2;
  const int j0 = __ffs(flags) - 1;
  const int j1 = __ffs(flags & (flags - 1)) - 1;
  const int r0 = sc > 0 ? j0 : 0;
  const int r1 = sc > 1 ? j1 : 0;
  const int e0 = (c >> (4 * r0)) & 15;
  const int e1 = (c >> (4 * r1)) & 15;
  m = (sc > 0 ? (1u << e0) : 0u) | (sc > 1 ? (1u << e1) : 0u);
  dec = e0 | (e1 << 4) | (r0 << 8) | (r1 << 11) | (sc << 14);
}

struct RouterSm {
  unsigned long long bal[32][17];   // [chunk][expert], padded
  int cap[16], T[16];
  int avail, t0, tfin, done, hits;
};

__global__ __launch_bounds__(1024) void k2_router(
    const unsigned* __restrict__ cands, const float* __restrict__ cvals,
    const unsigned* __restrict__ argpk, const int* __restrict__ p_cap,
    float* __restrict__ out, int* __restrict__ asgn, float* __restrict__ asgnw)
{
  __shared__ RouterSm S;
  const int tid = threadIdx.x;
  const int w = tid >> 6, l = tid & 63;
  if (tid == 0) { S.avail = 0xFFFF; S.t0 = 0; S.done = 0; S.hits = 0; }
  if (tid < 16) S.cap[tid] = 0;
  const int capl = max(1, p_cap[0]);
  const unsigned cA = cands[tid], cB = cands[tid + 1024];
  const unsigned aA = argpk[tid], aB = argpk[tid + 1024];
  int hits = 0;
  __syncthreads();

  for (int round = 0; round < 20; ++round) {
    const int t0 = S.t0;
    const int avail = S.avail;
    unsigned mA = 0, mB = 0;
    int dA = 0, dB = 0;
    if (tid >= t0) route_decide(cA, avail, mA, dA);
    if (tid + 1024 >= t0) route_decide(cB, avail, mB, dB);
    if (w * 64 + 63 < t0) {
      if (l < 16) S.bal[w][l] = 0ull;
    } else {
      for (int av = avail; av; av &= av - 1) {
        const int e = __ffs(av) - 1;
        unsigned long long b = __ballot((mA >> e) & 1);
        if (l == e) S.bal[w][e] = b;
      }
    }
    if (w * 64 + 1024 + 63 < t0) {
      if (l < 16) S.bal[w + 16][l] = 0ull;
    } else {
      for (int av = avail; av; av &= av - 1) {
        const int e = __ffs(av) - 1;
        unsigned long long b = __ballot((mB >> e) & 1);
        if (l == e) S.bal[w + 16][e] = b;
      }
    }
    __syncthreads();
    // crossing: wave w owns expert w; popcount gate then locate
    unsigned long long bm = 0;
    const bool eav = (avail >> w) & 1;
    {
      int myT = 0x7FFFFFFF;
      if (eav) {
        int cnt = 0;
        if (l < 32) { bm = S.bal[l][w]; cnt = __popcll(bm); }
        int tot = cnt;
#pragma unroll
        for (int o = 32; o; o >>= 1) tot += __shfl_xor(tot, o, 64);
        const int rem = capl - S.cap[w];
        if (tot >= rem) {
          int incl = cnt;
#pragma unroll
          for (int o = 1; o < 32; o <<= 1) {
            int u = __shfl_up(incl, o, 64);
            if (l >= o) incl += u;
          }
          if (l < 32) {
            const int need = rem - (incl - cnt);
            if (need >= 1 && need <= cnt) {
              unsigned long long bb = bm;
              for (int i = 1; i < need; ++i) bb &= bb - 1;
              myT = l * 64 + (__ffsll((unsigned long long)bb) - 1);
            }
          }
#pragma unroll
          for (int o = 32; o; o >>= 1) myT = min(myT, __shfl_xor(myT, o, 64));
        }
      }
      if (l == 0) S.T[w] = myT;
    }
    __syncthreads();
    if (w == 0) {
      int v = (l < 16) ? S.T[l] : 0x7FFFFFFF;
      int ts = v;
#pragma unroll
      for (int o = 32; o; o >>= 1) ts = min(ts, __shfl_xor(ts, o, 64));
      const int done = (ts == 0x7FFFFFFF);
      const int tf = done ? (NTOK - 1) : ts;
      if (l == 0) { S.tfin = tf; S.done = done; S.t0 = tf + 1; }
      if (l < 16 && v == ts) atomicAnd(&S.avail, ~(1 << l));
    }
    __syncthreads();
    const int tfin = S.tfin;
    if (eav) {
      int c2 = 0;
      if (l < 32) {
        const int hi = tfin - l * 64;
        unsigned long long mk =
            (hi < 0) ? 0ull : (hi >= 63 ? ~0ull : ((1ull << (hi + 1)) - 1ull));
        c2 = __popcll(bm & mk);
      }
#pragma unroll
      for (int o = 32; o; o >>= 1) c2 += __shfl_xor(c2, o, 64);
      if (l == 0) S.cap[w] += c2;
    }
#pragma unroll
    for (int half = 0; half < 2; ++half) {
      const int t = tid + half * 1024;
      const int d = half ? dB : dA;
      const unsigned ap = half ? aB : aA;
      if (t < t0 || t > tfin) continue;
      const int e0 = d & 15, e1 = (d >> 4) & 15;
      const int r0 = (d >> 8) & 7, r1 = (d >> 11) & 7, sc = (d >> 14) & 3;
      const int a0 = (ap >> (2 * e0)) & 3, a1i = (ap >> (2 * e1)) & 3;
      asgn[t] = e0 | (e1 << 4) | (a0 << 8) | (a1i << 10) | (sc << 12);
      asgnw[t * 2 + 0] = sc > 0 ? cvals[(size_t)t * 8 + r0] : 0.f;
      asgnw[t * 2 + 1] = sc > 1 ? cvals[(size_t)t * 8 + r1] : 0.f;
      hits += (sc > 0 && r0 > 0) + (sc > 1 && r1 > 0);
    }
    __syncthreads();
    if (S.done) break;
  }
#pragma unroll
  for (int o = 32; o; o >>= 1) hits += __shfl_xor(hits, o, 64);
  if (l == 0) atomicAdd(&S.hits, hits);
  __syncthreads();
  if (tid == 0) out[O_HIT] = (float)S.hits / (float)(NTOK * 2);
}

// ---------------------------------------------------------------------------
// bf16 GEMM body: C = A[M,Kloop] * B[N,Kloop]^T (row stride lda), 128x128 tile,
// BK=64, 4 waves, mfma_f32_16x16x32_bf16, global_load_lds width 16.
// EPI 0: silu(x+bias) -> bf16. EPI 1: x+(bias?) -> f32.
// ---------------------------------------------------------------------------
template <int EPI>
__device__ __forceinline__ void gemm_body(
    unsigned short* As, unsigned short* Bs, int bid,
    const unsigned short* __restrict__ A, const unsigned short* __restrict__ Bm,
    const float* __restrict__ bias, void* __restrict__ Cout,
    int M, int N, int Kloop, int lda, int add_bias)
{
  const int tid = threadIdx.x;
  const int wv = tid >> 6, l = tid & 63;
  const int ntile = N >> 7;
  const int trow = (bid / ntile) << 7;
  const int tcol = (bid % ntile) << 7;
  const int wr = wv >> 1, wc = wv & 1;
  v4f acc[4][4];
#pragma unroll
  for (int m = 0; m < 4; ++m)
#pragma unroll
    for (int n = 0; n < 4; ++n) acc[m][n] = (v4f){0.f, 0.f, 0.f, 0.f};

  const int lrow8 = l >> 3;
  const int lcol8 = (l & 7) << 3;
  const unsigned short* gA = A + (size_t)trow * lda;
  const unsigned short* gB = Bm + (size_t)tcol * lda;
  const int fr = l & 15, kof = (l >> 4) << 3;

  for (int k0 = 0; k0 < Kloop; k0 += 64) {
    __syncthreads();
#pragma unroll
    for (int i = 0; i < 4; ++i) {
      const int s = (wv << 2) + i;  // segment 0..15 = 8 rows each
      gload_lds16(gA + (size_t)(s * 8 + lrow8) * lda + k0 + lcol8, &As[s * 512]);
      gload_lds16(gB + (size_t)(s * 8 + lrow8) * lda + k0 + lcol8, &Bs[s * 512]);
    }
    __syncthreads();
    v8bf af[4][2], bf[4][2];
#pragma unroll
    for (int m = 0; m < 4; ++m) {
      const int row = wr * 64 + m * 16 + fr;
      af[m][0] = *(const v8bf*)&As[row * 64 + kof];
      af[m][1] = *(const v8bf*)&As[row * 64 + 32 + kof];
    }
#pragma unroll
    for (int n = 0; n < 4; ++n) {
      const int row = wc * 64 + n * 16 + fr;
      bf[n][0] = *(const v8bf*)&Bs[row * 64 + kof];
      bf[n][1] = *(const v8bf*)&Bs[row * 64 + 32 + kof];
    }
#pragma unroll
    for (int ks = 0; ks < 2; ++ks)
#pragma unroll
      for (int m = 0; m < 4; ++m)
#pragma unroll
        for (int n = 0; n < 4; ++n)
          acc[m][n] = __builtin_amdgcn_mfma_f32_16x16x32_bf16(
              af[m][ks], bf[n][ks], acc[m][n], 0, 0, 0);
  }
  // epilogue: C/D layout col=lane&15, row=(lane>>4)*4+j  [m89/m91]
  const int fq = l >> 4;
#pragma unroll
  for (int m = 0; m < 4; ++m)
#pragma unroll
    for (int n = 0; n < 4; ++n) {
      const int col = tcol + wc * 64 + n * 16 + fr;
      const float bc = add_bias ? bias[col] : 0.f;
#pragma unroll
      for (int j = 0; j < 4; ++j) {
        const int row = trow + wr * 64 + m * 16 + fq * 4 + j;
        const float v = acc[m][n][j] + bc;
        if (EPI == 0) {
          const float sv = v / (1.f + __expf(-v));
          ((unsigned short*)Cout)[(size_t)row * N + col] = f2bf(sv);
        } else {
          ((float*)Cout)[(size_t)row * N + col] = v;
        }
      }
    }
}

__global__ __launch_bounds__(256) void gemm_bt0(
    const unsigned short* __restrict__ A, const unsigned short* __restrict__ Bm,
    const float* __restrict__ bias, void* __restrict__ Cout,
    int M, int N, int K)
{
  __shared__ __align__(16) char smem[32768];
  gemm_body<0>((unsigned short*)smem, (unsigned short*)smem + 8192,
               blockIdx.x, A, Bm, bias, Cout, M, N, K, K, 1);
}

// fc2 split-K x2: blocks [0,128) = K-half 0 (+bias) -> C0; [128,256) -> C1
__global__ __launch_bounds__(256) void gemm_bt1s(
    const unsigned short* __restrict__ A, const unsigned short* __restrict__ Bm,
    const float* __restrict__ bias, float* __restrict__ C0,
    float* __restrict__ C1)
{
  __shared__ __align__(16) char smem[32768];
  const int ntiles = (NTOK / 128) * (DDIM / 128);   // 128
  const int half = blockIdx.x / ntiles;
  const int tile = blockIdx.x % ntiles;
  gemm_body<1>((unsigned short*)smem, (unsigned short*)smem + 8192,
               tile, A + half * 1024, Bm + half * 1024, bias,
               half ? (void*)C1 : (void*)C0,
               NTOK, DDIM, 1024, HDIM, half == 0);
}

__global__ __launch_bounds__(256) void gemm_bt1f(
    const unsigned short* __restrict__ A, const unsigned short* __restrict__ Bm,
    const float* __restrict__ bias, void* __restrict__ Cout,
    int M, int N, int K)
{
  __shared__ __align__(16) char smem[32768];
  gemm_body<1>((unsigned short*)smem, (unsigned short*)smem + 8192,
               blockIdx.x, A, Bm, bias, Cout, M, N, K, K, 1);
}

// ---------------------------------------------------------------------------
// K5: per-token LoRA adapters + final combine + bulk routing outputs
// ---------------------------------------------------------------------------
__global__ __launch_bounds__(256) void k5_lora(
    const float* __restrict__ z, const unsigned short* __restrict__ hpre,
    const float* __restrict__ outpre, const float* __restrict__ outpre2,
    int use2, const int* __restrict__ asgn, const float* __restrict__ asgnw,
    const unsigned short* __restrict__ a1, const unsigned short* __restrict__ b1,
    const unsigned short* __restrict__ a2, const unsigned short* __restrict__ b2,
    float* __restrict__ out0, float* __restrict__ out)
{
  __shared__ float zl[DDIM];
  __shared__ float hl[HDIM];
  __shared__ float t1s[8], t2s[8];
  const int b = blockIdx.x, tid = threadIdx.x;
  {
    float4 v = *(const float4*)&z[(size_t)b * DDIM + tid * 4];
    *(float4*)&zl[tid * 4] = v;
  }
  const int pk = asgn[b];
  const int sc = (pk >> 12) & 3;
  const int eA0 = pk & 15, eA1 = (pk >> 4) & 15;
  const int aA0 = (pk >> 8) & 3, aA1 = (pk >> 10) & 3;
  const float w0 = asgnw[b * 2 + 0], w1 = asgnw[b * 2 + 1];
  if (tid < 16)
    out[O_USED + (size_t)b * 16 + tid] =
        (float)((sc > 0 && tid == eA0) || (sc > 1 && tid == eA1));
  if (tid == 0) {
    out[O_AIDX + (size_t)b * 2 + 0] = sc > 0 ? (float)eA0 : -1.f;
    out[O_AIDX + (size_t)b * 2 + 1] = sc > 1 ? (float)eA1 : -1.f;
    out[O_AW + (size_t)b * 2 + 0] = w0;
    out[O_AW + (size_t)b * 2 + 1] = w1;
    out[O_EVE + b] = sc > 0 ? (float)eA0 : -1.f;
    out[O_EVE + NTOK + b] = sc > 1 ? (float)eA1 : -1.f;
    out[O_EVA + b] = sc > 0 ? (float)aA0 : -1.f;
    out[O_EVA + NTOK + b] = sc > 1 ? (float)aA1 : -1.f;
  }
  float acc[4] = {0.f, 0.f, 0.f, 0.f};
  float wsum = 0.f;
  const int r = tid >> 5, l5 = tid & 31;
  const float4* zg = (const float4*)&z[(size_t)b * DDIM];
  __syncthreads();

  for (int s = 0; s < 2; ++s) {
    if (s >= sc) continue;  // uniform across block
    const float ww = (s == 0) ? w0 : w1;
    const int ad = ((s == 0) ? eA0 : eA1) * 4 + ((s == 0) ? aA0 : aA1);
    wsum += ww;
    {
      const us8v* pa1 = (const us8v*)(a1 + ((size_t)ad * 8 + r) * DDIM);
      float sa = 0.f;
#pragma unroll
      for (int i = 0; i < 4; ++i) {
        const int g = l5 + 32 * i;
        us8v va = pa1[g];
        float4 z0 = zg[g * 2], z1 = zg[g * 2 + 1];
        sa += z0.x * bf2f(va[0]) + z0.y * bf2f(va[1]) +
              z0.z * bf2f(va[2]) + z0.w * bf2f(va[3]) +
              z1.x * bf2f(va[4]) + z1.y * bf2f(va[5]) +
              z1.z * bf2f(va[6]) + z1.w * bf2f(va[7]);
      }
#pragma unroll
      for (int o = 16; o; o >>= 1) sa += __shfl_xor(sa, o, 64);
      if (l5 == 0) t1s[r] = sa;
    }
    __syncthreads();
    {
      float t1r[8];
#pragma unroll
      for (int q = 0; q < 8; ++q) t1r[q] = t1s[q];
      const unsigned short* pb1 = b1 + (size_t)ad * HDIM * 8;
      const unsigned short* ph = hpre + (size_t)b * HDIM;
#pragma unroll
      for (int j = 0; j < 8; ++j) {
        const int hh_i = tid + 256 * j;
        us8v row = *(const us8v*)&pb1[(size_t)hh_i * 8];
        float d1 = 0.f;
#pragma unroll
        for (int q = 0; q < 8; ++q) d1 += t1r[q] * bf2f(row[q]);
        const float hh = bf2f(ph[hh_i]) + d1;  // SCALE = 1
        hl[hh_i] = hh / (1.f + __expf(-hh));
      }
    }
    __syncthreads();
    {
      const us8v* pa2 = (const us8v*)(a2 + ((size_t)ad * 8 + r) * HDIM);
      float sa = 0.f;
#pragma unroll
      for (int i = 0; i < 8; ++i) {
        const int g = l5 + 32 * i;
        us8v va = pa2[g];
        const float* hp = &hl[g * 8];
        sa += hp[0] * bf2f(va[0]) + hp[1] * bf2f(va[1]) +
              hp[2] * bf2f(va[2]) + hp[3] * bf2f(va[3]) +
              hp[4] * bf2f(va[4]) + hp[5] * bf2f(va[5]) +
              hp[6] * bf2f(va[6]) + hp[7] * bf2f(va[7]);
      }
#pragma unroll
      for (int o = 16; o; o >>= 1) sa += __shfl_xor(sa, o, 64);
      if (l5 == 0) t2s[r] = sa;
    }
    __syncthreads();
    {
      float t2r[8];
#pragma unroll
      for (int q = 0; q < 8; ++q) t2r[q] = t2s[q];
      const unsigned short* pb2 = b2 + (size_t)ad * DDIM * 8;
#pragma unroll
      for (int j = 0; j < 4; ++j) {
        const int d = tid + 256 * j;
        us8v row = *(const us8v*)&pb2[(size_t)d * 8];
        float d2 = 0.f;
#pragma unroll
        for (int q = 0; q < 8; ++q) d2 += t2r[q] * bf2f(row[q]);
        acc[j] += ww * d2;  // SCALE = 1
      }
    }
    __syncthreads();
  }
#pragma unroll
  for (int j = 0; j < 4; ++j) {
    const int d = tid + 256 * j;
    float op = outpre[(size_t)b * DDIM + d];
    if (use2) op += outpre2[(size_t)b * DDIM + d];
    out0[(size_t)b * DDIM + d] = zl[d] + wsum * op + acc[j];
  }
}

// ---------------------------------------------------------------------------
extern "C" void kernel_launch(void* const* d_in, const int* in_sizes, int n_in,
                              void* d_out, int out_size, void* d_ws, size_t ws_size,
                              hipStream_t stream)
{
  (void)in_sizes; (void)n_in; (void)out_size;
  const float* z     = (const float*)d_in[0];
  const int*   p_cap = (const int*)d_in[2];
  const int*   p_ban = (const int*)d_in[3];
  const float* p_tau = (const float*)d_in[4];
  const float* p_eps = (const float*)d_in[5];
  const float* fc1w  = (const float*)d_in[6];
  const float* fc1b  = (const float*)d_in[7];
  const float* fc2w  = (const float*)d_in[8];
  const float* fc2b  = (const float*)d_in[9];
  const float* proto = (const float*)d_in[10];
  const float* ak    = (const float*)d_in[11];
  const float* ebias = (const float*)d_in[12];
  const float* a1    = (const float*)d_in[13];
  const float* b1    = (const float*)d_in[14];
  const float* a2    = (const float*)d_in[15];
  const float* b2    = (const float*)d_in[16];
  float* out = (float*)d_out;
  char* ws = (char*)d_ws;

  unsigned short* zbf    = (unsigned short*)(ws + WS_ZBF);
  unsigned short* fc1wbf = (unsigned short*)(ws + WS_FC1WBF);
  unsigned short* fc2wbf = (unsigned short*)(ws + WS_FC2WBF);
  unsigned short* hprebf = (unsigned short*)(ws + WS_HPREBF);
  float*          outpre = (float*)(ws + WS_OUTPRE);
  unsigned short* a1bf   = (unsigned short*)(ws + WS_A1BF);
  unsigned short* b1bf   = (unsigned short*)(ws + WS_B1BF);
  unsigned short* a2bf   = (unsigned short*)(ws + WS_A2BF);
  unsigned short* b2bf   = (unsigned short*)(ws + WS_B2BF);
  unsigned*       cands  = (unsigned*)(ws + WS_CANDS);
  float*          cvals  = (float*)(ws + WS_CVALS);
  unsigned*       argpk  = (unsigned*)(ws + WS_ARGPK);
  int*            asgn   = (int*)(ws + WS_ASGN);
  float*          asgnw  = (float*)(ws + WS_ASGNW);
  float*          outpr2 = (float*)(ws + WS_OUTPR2);
  const int splitk = (ws_size >= WS_TOTAL2) ? 1 : 0;

  k1_scores<<<512, 256, 0, stream>>>(
      z, proto, ebias, ak, p_tau, p_eps, p_ban, zbf, out, cands, cvals, argpk,
      fc1w, fc2w, a1, b1, a2, b2, fc1wbf, fc2wbf, a1bf, b1bf, a2bf, b2bf);

  k2_router<<<1, 1024, 0, stream>>>(
      cands, cvals, argpk, p_cap, out, asgn, asgnw);

  // fc1: [2048,1024] x [2048,1024]^T -> silu -> bf16 h_pre
  gemm_bt0<<<(NTOK / 128) * (HDIM / 128), 256, 0, stream>>>(
      zbf, fc1wbf, fc1b, (void*)hprebf, NTOK, HDIM, DDIM);

  // fc2: [2048,2048] x [1024,2048]^T -> +bias -> f32 out_pre (split-K x2)
  if (splitk) {
    gemm_bt1s<<<2 * (NTOK / 128) * (DDIM / 128), 256, 0, stream>>>(
        hprebf, fc2wbf, fc2b, outpre, outpr2);
  } else {
    gemm_bt1f<<<(NTOK / 128) * (DDIM / 128), 256, 0, stream>>>(
        hprebf, fc2wbf, fc2b, (void*)outpre, NTOK, DDIM, HDIM);
  }

  k5_lora<<<NTOK, 256, 0, stream>>>(
      z, hprebf, outpre, outpr2, splitk, asgn, asgnw,
      a1bf, b1bf, a2bf, b2bf, out, out);
}

// Round 7
// 272.773 us; speedup vs baseline: 1.2336x; 1.0246x over previous
//
#include <hip/hip_runtime.h>
#include <stdint.h>

// ---------------------------------------------------------------------------
// MoELatent: B=2048 D=1024 H=2048 E=16 W=4 R=8, top_k=2, cand_k=8
// ---------------------------------------------------------------------------
#define NTOK 2048
#define DDIM 1024
#define HDIM 2048
#define NEXP 16

// output (float) element offsets, in reference return order
#define O_PROBS 2097152   // [2048,16]
#define O_USED  2129920   // [2048,16]
#define O_AIDX  2162688   // [2048,2]
#define O_AW    2166784   // [2048,2]
#define O_HIT   2170880   // scalar
#define O_EVE   2170881   // [2,2048] slot-major
#define O_EVA   2174977   // [2,2048]

// workspace byte offsets — constexpr chain (round-1 lesson: never hand-type)
static constexpr size_t WS_ZBF    = 0;
static constexpr size_t WS_FC1WBF = WS_ZBF    + (size_t)NTOK * DDIM * 2;
static constexpr size_t WS_FC2WBF = WS_FC1WBF + (size_t)HDIM * DDIM * 2;
static constexpr size_t WS_HPREBF = WS_FC2WBF + (size_t)DDIM * HDIM * 2;
static constexpr size_t WS_OUTPRE = WS_HPREBF + (size_t)NTOK * HDIM * 2;
static constexpr size_t WS_A1BF   = WS_OUTPRE + (size_t)NTOK * DDIM * 4;
static constexpr size_t WS_B1BF   = WS_A1BF   + (size_t)16 * 4 * 8 * 1024 * 2;
static constexpr size_t WS_A2BF   = WS_B1BF   + (size_t)16 * 4 * 2048 * 8 * 2;
static constexpr size_t WS_B2BF   = WS_A2BF   + (size_t)16 * 4 * 8 * 2048 * 2;
static constexpr size_t WS_CANDS  = WS_B2BF   + (size_t)16 * 4 * 1024 * 8 * 2;
static constexpr size_t WS_CVALS  = WS_CANDS  + (size_t)NTOK * 4;
static constexpr size_t WS_ARGPK  = WS_CVALS  + (size_t)NTOK * 8 * 4;
static constexpr size_t WS_ASGN   = WS_ARGPK  + (size_t)NTOK * 4;
static constexpr size_t WS_ASGNW  = WS_ASGN   + (size_t)NTOK * 4;
static constexpr size_t WS_OUTPR2 = WS_ASGNW  + (size_t)NTOK * 2 * 4;
static constexpr size_t WS_TOTAL2 = WS_OUTPR2 + (size_t)NTOK * DDIM * 4;

typedef __bf16 v8bf __attribute__((ext_vector_type(8)));
typedef float v4f __attribute__((ext_vector_type(4)));
typedef unsigned short us8v __attribute__((ext_vector_type(8)));

__device__ __forceinline__ unsigned short f2bf(float f) {
  unsigned u = __float_as_uint(f);
  u = u + 0x7fffu + ((u >> 16) & 1u);          // round-to-nearest-even
  return (unsigned short)(u >> 16);
}
__device__ __forceinline__ float bf2f(unsigned short s) {
  return __uint_as_float(((unsigned)s) << 16);
}
__device__ __forceinline__ void gload_lds16(const void* g, void* l) {
  __builtin_amdgcn_global_load_lds(
      (const __attribute__((address_space(1))) void*)g,
      (__attribute__((address_space(3))) void*)l, 16, 0, 0);
}
__device__ __forceinline__ float dot4(float4 a, float4 b) {
  return a.x * b.x + a.y * b.y + a.z * b.z + a.w * b.w;
}

// ---------------------------------------------------------------------------
// K1: 512 blocks x 256 thr, 4 tokens/block. Scores only (conv moved to K2).
// Phase 1: lane = weight-row, wave = d-quarter, serial in-register reduction.
// Phase 2: thread t<4 does one token's softmax/top-8/argmax fully lane-local.
// ---------------------------------------------------------------------------
__global__ __launch_bounds__(256) void k1_scores(
    const float* __restrict__ z, const float* __restrict__ proto,
    const float* __restrict__ ebias, const float* __restrict__ ak,
    const float* __restrict__ p_tau, const float* __restrict__ p_eps,
    const int* __restrict__ p_ban,
    unsigned short* __restrict__ zbf, float* __restrict__ out,
    unsigned* __restrict__ cands, float* __restrict__ cvals,
    unsigned* __restrict__ argpk)
{
  __shared__ float zs[4][DDIM];        // 16 KB
  __shared__ float part[80 * 17];      // [row][tk*4+wv], stride 17
  __shared__ float sc[4 * 80];         // [token][row]; rows 0-63 ak, 64-79 proto
  const int tid = threadIdx.x;
  const int tb = blockIdx.x * 4;
#pragma unroll
  for (int i = 0; i < 4; ++i) {
    const int col = tid * 4;
    float4 v = *(const float4*)&z[(size_t)(tb + i) * DDIM + col];
    *(float4*)&zs[i][col] = v;
    ushort4 bv;
    bv.x = f2bf(v.x); bv.y = f2bf(v.y); bv.z = f2bf(v.z); bv.w = f2bf(v.w);
    *(ushort4*)&zbf[(size_t)(tb + i) * DDIM + col] = bv;
  }
  __syncthreads();
  const int wv = tid >> 6, l = tid & 63;

  // ---- phase 1: ak rows (all lanes) ----
  {
    const float4* akr = (const float4*)(ak + (size_t)l * DDIM + wv * 256);
    const float4* z0 = (const float4*)&zs[0][0] + wv * 64;
    const float4* z1 = (const float4*)&zs[1][0] + wv * 64;
    const float4* z2 = (const float4*)&zs[2][0] + wv * 64;
    const float4* z3 = (const float4*)&zs[3][0] + wv * 64;
    float a0 = 0.f, a1v = 0.f, a2v = 0.f, a3 = 0.f;
#pragma unroll 8
    for (int i = 0; i < 64; ++i) {
      float4 w = akr[i];
      a0 += dot4(z0[i], w); a1v += dot4(z1[i], w);
      a2v += dot4(z2[i], w); a3 += dot4(z3[i], w);
    }
    part[l * 17 + 0 * 4 + wv] = a0;
    part[l * 17 + 1 * 4 + wv] = a1v;
    part[l * 17 + 2 * 4 + wv] = a2v;
    part[l * 17 + 3 * 4 + wv] = a3;
  }
  // ---- phase 1b: proto rows (lanes 0-15) ----
  if (l < 16) {
    const float4* pr = (const float4*)(proto + (size_t)l * DDIM + wv * 256);
    const float4* z0 = (const float4*)&zs[0][0] + wv * 64;
    const float4* z1 = (const float4*)&zs[1][0] + wv * 64;
    const float4* z2 = (const float4*)&zs[2][0] + wv * 64;
    const float4* z3 = (const float4*)&zs[3][0] + wv * 64;
    float a0 = 0.f, a1v = 0.f, a2v = 0.f, a3 = 0.f;
#pragma unroll 8
    for (int i = 0; i < 64; ++i) {
      float4 w = pr[i];
      a0 += dot4(z0[i], w); a1v += dot4(z1[i], w);
      a2v += dot4(z2[i], w); a3 += dot4(z3[i], w);
    }
    part[(64 + l) * 17 + 0 * 4 + wv] = a0;
    part[(64 + l) * 17 + 1 * 4 + wv] = a1v;
    part[(64 + l) * 17 + 2 * 4 + wv] = a2v;
    part[(64 + l) * 17 + 3 * 4 + wv] = a3;
  }
  __syncthreads();
  for (int o = tid; o < 320; o += 256) {
    const int row = o >> 2, tk = o & 3;
    sc[tk * 80 + row] =
        ((part[row * 17 + tk * 4 + 0] + part[row * 17 + tk * 4 + 1]) +
         part[row * 17 + tk * 4 + 2]) + part[row * 17 + tk * 4 + 3];
  }
  __syncthreads();
  // ---- phase 2: per-token selection, fully lane-local ----
  if (tid < 4) {
    const int t = tb + tid;
    const float tau = fmaxf(p_tau[0], 1e-6f);
    const float eps = p_eps[0];
    const int ban = p_ban[0];
    float lg[16];
#pragma unroll
    for (int e = 0; e < 16; ++e) {
      float v = sc[tid * 80 + 64 + e] / tau + ebias[e];
      lg[e] = (e == ban) ? -1e9f : v;
    }
    float mx = lg[0];
#pragma unroll
    for (int e = 1; e < 16; ++e) mx = fmaxf(mx, lg[e]);
    float ex[16]; float sm = 0.f;
#pragma unroll
    for (int e = 0; e < 16; ++e) { ex[e] = expf(lg[e] - mx); sm += ex[e]; }
    float p[16];
#pragma unroll
    for (int e = 0; e < 16; ++e) {
      p[e] = (1.f - eps) * (ex[e] / sm) + eps / (float)NEXP;
      out[O_PROBS + (size_t)t * NEXP + e] = p[e];
    }
    // top-8: strict > with ascending e = value-desc, index-asc (lax.top_k)
    unsigned pack = 0, taken = 0;
#pragma unroll
    for (int r = 0; r < 8; ++r) {
      float bv = -1e30f; int bi = 0;
#pragma unroll
      for (int e = 0; e < 16; ++e) {
        const bool c = !((taken >> e) & 1u) && (p[e] > bv);
        bv = c ? p[e] : bv; bi = c ? e : bi;
      }
      taken |= 1u << bi;
      pack |= ((unsigned)bi) << (4 * r);
      cvals[(size_t)t * 8 + r] = bv;
    }
    cands[t] = pack;
    // adapter argmax per expert (first max wins, like jnp.argmax)
    unsigned apk = 0;
#pragma unroll
    for (int e = 0; e < 16; ++e) {
      float b = sc[tid * 80 + e * 4]; int bi = 0;
#pragma unroll
      for (int w = 1; w < 4; ++w) {
        const float v = sc[tid * 80 + e * 4 + w];
        if (v > b) { b = v; bi = w; }
      }
      apk |= ((unsigned)bi) << (2 * e);
    }
    argpk[t] = apk;
  }
}

// ---------------------------------------------------------------------------
// K2: block 0 = router (1024 thr, 2 barriers/round, all state in registers);
//     blocks 1..CONVB = f32->bf16 weight conversions (overlap the router).
// Thread tid owns tokens {tid, tid+1024}; chunk q = tokens [q*64, q*64+64).
// ---------------------------------------------------------------------------
#define CONVB 224

__device__ __forceinline__ void route_decide(unsigned c, int avail,
                                             unsigned& m, int& dec) {
  unsigned flags = 0;
#pragma unroll
  for (int j = 0; j < 8; ++j) {
    const int e = (c >> (4 * j)) & 15;
    flags |= ((unsigned)(avail >> e) & 1u) << j;
  }
  const int pc = __popc(flags);
  const int sc = pc < 2 ? pc : 2;
  const int j0 = __ffs(flags) - 1;
  const int j1 = __ffs(flags & (flags - 1)) - 1;
  const int r0 = sc > 0 ? j0 : 0;
  const int r1 = sc > 1 ? j1 : 0;
  const int e0 = (c >> (4 * r0)) & 15;
  const int e1 = (c >> (4 * r1)) & 15;
  m = (sc > 0 ? (1u << e0) : 0u) | (sc > 1 ? (1u << e1) : 0u);
  dec = e0 | (e1 << 4) | (r0 << 8) | (r1 << 11) | (sc << 14);
}

__global__ __launch_bounds__(1024) void k2_route_conv(
    const unsigned* __restrict__ cands, const float* __restrict__ cvals,
    const unsigned* __restrict__ argpk, const int* __restrict__ p_cap,
    float* __restrict__ out, int* __restrict__ asgn, float* __restrict__ asgnw,
    const float* __restrict__ fc1w, const float* __restrict__ fc2w,
    const float* __restrict__ a1, const float* __restrict__ b1,
    const float* __restrict__ a2, const float* __restrict__ b2,
    unsigned short* __restrict__ fc1wbf, unsigned short* __restrict__ fc2wbf,
    unsigned short* __restrict__ a1bf, unsigned short* __restrict__ b1bf,
    unsigned short* __restrict__ a2bf, unsigned short* __restrict__ b2bf)
{
  const int tid = threadIdx.x;
  if (blockIdx.x != 0) {
    // weight conversions: 224 blocks x 1024 thr x 8 iters = 1,835,008 float4
    size_t j = (size_t)(blockIdx.x - 1) * 1024 + tid;
    const size_t stride = (size_t)CONVB * 1024;
    for (; j < 1835008ull; j += stride) {
      const float* src; unsigned short* dst; size_t off;
      if (j < 524288) { src = fc1w; dst = fc1wbf; off = j; }
      else if (j < 1048576) { src = fc2w; dst = fc2wbf; off = j - 524288; }
      else if (j < 1179648) { src = a1; dst = a1bf; off = j - 1048576; }
      else if (j < 1441792) { src = b1; dst = b1bf; off = j - 1179648; }
      else if (j < 1703936) { src = a2; dst = a2bf; off = j - 1441792; }
      else { src = b2; dst = b2bf; off = j - 1703936; }
      float4 v = *(const float4*)&src[off * 4];
      ushort4 bv;
      bv.x = f2bf(v.x); bv.y = f2bf(v.y); bv.z = f2bf(v.z); bv.w = f2bf(v.w);
      *(ushort4*)&dst[off * 4] = bv;
    }
    return;
  }
  // ---- router: 16 waves, wave w owns expert w; 2 barriers/round ----
  __shared__ unsigned long long bal[2][32][17];  // double-buffered ballots
  __shared__ int T[16];
  __shared__ int hitsS;
  const int w = tid >> 6, l = tid & 63;
  if (tid == 0) hitsS = 0;
  const int capl = max(1, p_cap[0]);
  const unsigned cA = cands[tid], cB = cands[tid + 1024];
  const unsigned aA = argpk[tid], aB = argpk[tid + 1024];
  float cvA[8], cvB[8];
#pragma unroll
  for (int q = 0; q < 8; ++q) {
    cvA[q] = cvals[(size_t)tid * 8 + q];
    cvB[q] = cvals[(size_t)(tid + 1024) * 8 + q];
  }
  int avail = 0xFFFF, t0 = 0, capw = 0, hits = 0;

  for (int round = 0; round < 20; ++round) {
    const int p = round & 1;
    // phase A: decide + unconditional ballots (retired tokens ballot 0)
    unsigned mA = 0, mB = 0;
    int dA = 0, dB = 0;
    if (tid >= t0) route_decide(cA, avail, mA, dA);
    if (tid + 1024 >= t0) route_decide(cB, avail, mB, dB);
#pragma unroll
    for (int e = 0; e < 16; ++e) {
      unsigned long long b = __ballot((mA >> e) & 1);
      if (l == e) bal[p][w][l] = b;
    }
#pragma unroll
    for (int e = 0; e < 16; ++e) {
      unsigned long long b = __ballot((mB >> e) & 1);
      if (l == e) bal[p][w + 16][l] = b;
    }
    __syncthreads();                      // barrier 1
    // phase B: wave w computes its expert's crossing T[w]
    unsigned long long bm = 0;
    int myT = 0x7FFFFFFF;
    const bool eav = (avail >> w) & 1;
    if (eav) {
      int cnt = 0;
      if (l < 32) { bm = bal[p][l][w]; cnt = __popcll(bm); }
      int tot = cnt;
#pragma unroll
      for (int o = 32; o; o >>= 1) tot += __shfl_xor(tot, o, 64);
      const int rem = capl - capw;
      if (tot >= rem) {
        int incl = cnt;
#pragma unroll
        for (int o = 1; o < 32; o <<= 1) {
          int u = __shfl_up(incl, o, 64);
          if (l >= o) incl += u;
        }
        if (l < 32) {
          const int need = rem - (incl - cnt);
          if (need >= 1 && need <= cnt) {
            unsigned long long bb = bm;
            for (int i = 1; i < need; ++i) bb &= bb - 1;
            myT = l * 64 + (__ffsll((unsigned long long)bb) - 1);
          }
        }
#pragma unroll
        for (int o = 32; o; o >>= 1) myT = min(myT, __shfl_xor(myT, o, 64));
      }
    }
    if (l == 0) T[w] = myT;
    __syncthreads();                      // barrier 2
    // phase C: every wave derives ts/done/avail/t0 locally
    const int tv = (l < 16) ? T[l] : 0x7FFFFFFF;
    int ts = tv;
#pragma unroll
    for (int o = 32; o; o >>= 1) ts = min(ts, __shfl_xor(ts, o, 64));
    const bool done = (ts == 0x7FFFFFFF);
    const int tfin = done ? (NTOK - 1) : ts;
    unsigned long long crossed = __ballot((l < 16) && !done && (tv == ts));
    // cap update for this wave's expert (register-resident)
    if (eav) {
      int c2 = 0;
      if (l < 32) {
        const int hi = tfin - l * 64;
        unsigned long long mk =
            (hi < 0) ? 0ull : (hi >= 63 ? ~0ull : ((1ull << (hi + 1)) - 1ull));
        c2 = __popcll(bm & mk);
      }
#pragma unroll
      for (int o = 32; o; o >>= 1) c2 += __shfl_xor(c2, o, 64);
      capw += c2;
    }
    // finalize tokens in [t0, tfin] — cvals from registers (static select)
    {
      const int t = tid;
      if (t >= t0 && t <= tfin) {
        const int e0 = dA & 15, e1 = (dA >> 4) & 15;
        const int r0 = (dA >> 8) & 7, r1 = (dA >> 11) & 7, sc = (dA >> 14) & 3;
        const int a0 = (aA >> (2 * e0)) & 3, a1i = (aA >> (2 * e1)) & 3;
        float w0 = 0.f, w1v = 0.f;
#pragma unroll
        for (int q = 0; q < 8; ++q) {
          if (q == r0) w0 = cvA[q];
          if (q == r1) w1v = cvA[q];
        }
        asgn[t] = e0 | (e1 << 4) | (a0 << 8) | (a1i << 10) | (sc << 12);
        asgnw[t * 2 + 0] = sc > 0 ? w0 : 0.f;
        asgnw[t * 2 + 1] = sc > 1 ? w1v : 0.f;
        hits += (sc > 0 && r0 > 0) + (sc > 1 && r1 > 0);
      }
    }
    {
      const int t = tid + 1024;
      if (t >= t0 && t <= tfin) {
        const int e0 = dB & 15, e1 = (dB >> 4) & 15;
        const int r0 = (dB >> 8) & 7, r1 = (dB >> 11) & 7, sc = (dB >> 14) & 3;
        const int a0 = (aB >> (2 * e0)) & 3, a1i = (aB >> (2 * e1)) & 3;
        float w0 = 0.f, w1v = 0.f;
#pragma unroll
        for (int q = 0; q < 8; ++q) {
          if (q == r0) w0 = cvB[q];
          if (q == r1) w1v = cvB[q];
        }
        asgn[t] = e0 | (e1 << 4) | (a0 << 8) | (a1i << 10) | (sc << 12);
        asgnw[t * 2 + 0] = sc > 0 ? w0 : 0.f;
        asgnw[t * 2 + 1] = sc > 1 ? w1v : 0.f;
        hits += (sc > 0 && r0 > 0) + (sc > 1 && r1 > 0);
      }
    }
    avail &= ~(int)(unsigned)(crossed & 0xFFFFull);
    t0 = tfin + 1;
    if (done) break;
    // no 3rd barrier: next round writes bal[p^1]; T rewritten only after
    // the next barrier 1 — both fenced. [hazard audit in journal]
  }
#pragma unroll
  for (int o = 32; o; o >>= 1) hits += __shfl_xor(hits, o, 64);
  if (l == 0) atomicAdd(&hitsS, hits);
  __syncthreads();
  if (tid == 0) out[O_HIT] = (float)hitsS / (float)(NTOK * 2);
}

// ---------------------------------------------------------------------------
// bf16 GEMM body: C = A[M,Kloop] * B[N,Kloop]^T (row stride lda), 128x128 tile,
// BK=64, 4 waves, mfma_f32_16x16x32_bf16, global_load_lds width 16.
// EPI 0: silu(x+bias) -> bf16. EPI 1: x+(bias?) -> f32.
// ---------------------------------------------------------------------------
template <int EPI>
__device__ __forceinline__ void gemm_body(
    unsigned short* As, unsigned short* Bs, int bid,
    const unsigned short* __restrict__ A, const unsigned short* __restrict__ Bm,
    const float* __restrict__ bias, void* __restrict__ Cout,
    int M, int N, int Kloop, int lda, int add_bias)
{
  const int tid = threadIdx.x;
  const int wv = tid >> 6, l = tid & 63;
  const int ntile = N >> 7;
  const int trow = (bid / ntile) << 7;
  const int tcol = (bid % ntile) << 7;
  const int wr = wv >> 1, wc = wv & 1;
  v4f acc[4][4];
#pragma unroll
  for (int m = 0; m < 4; ++m)
#pragma unroll
    for (int n = 0; n < 4; ++n) acc[m][n] = (v4f){0.f, 0.f, 0.f, 0.f};

  const int lrow8 = l >> 3;
  const int lcol8 = (l & 7) << 3;
  const unsigned short* gA = A + (size_t)trow * lda;
  const unsigned short* gB = Bm + (size_t)tcol * lda;
  const int fr = l & 15, kof = (l >> 4) << 3;

  for (int k0 = 0; k0 < Kloop; k0 += 64) {
    __syncthreads();
#pragma unroll
    for (int i = 0; i < 4; ++i) {
      const int s = (wv << 2) + i;  // segment 0..15 = 8 rows each
      gload_lds16(gA + (size_t)(s * 8 + lrow8) * lda + k0 + lcol8, &As[s * 512]);
      gload_lds16(gB + (size_t)(s * 8 + lrow8) * lda + k0 + lcol8, &Bs[s * 512]);
    }
    __syncthreads();
    v8bf af[4][2], bf[4][2];
#pragma unroll
    for (int m = 0; m < 4; ++m) {
      const int row = wr * 64 + m * 16 + fr;
      af[m][0] = *(const v8bf*)&As[row * 64 + kof];
      af[m][1] = *(const v8bf*)&As[row * 64 + 32 + kof];
    }
#pragma unroll
    for (int n = 0; n < 4; ++n) {
      const int row = wc * 64 + n * 16 + fr;
      bf[n][0] = *(const v8bf*)&Bs[row * 64 + kof];
      bf[n][1] = *(const v8bf*)&Bs[row * 64 + 32 + kof];
    }
#pragma unroll
    for (int ks = 0; ks < 2; ++ks)
#pragma unroll
      for (int m = 0; m < 4; ++m)
#pragma unroll
        for (int n = 0; n < 4; ++n)
          acc[m][n] = __builtin_amdgcn_mfma_f32_16x16x32_bf16(
              af[m][ks], bf[n][ks], acc[m][n], 0, 0, 0);
  }
  // epilogue: C/D layout col=lane&15, row=(lane>>4)*4+j  [m89/m91]
  const int fq = l >> 4;
#pragma unroll
  for (int m = 0; m < 4; ++m)
#pragma unroll
    for (int n = 0; n < 4; ++n) {
      const int col = tcol + wc * 64 + n * 16 + fr;
      const float bc = add_bias ? bias[col] : 0.f;
#pragma unroll
      for (int j = 0; j < 4; ++j) {
        const int row = trow + wr * 64 + m * 16 + fq * 4 + j;
        const float v = acc[m][n][j] + bc;
        if (EPI == 0) {
          const float sv = v / (1.f + __expf(-v));
          ((unsigned short*)Cout)[(size_t)row * N + col] = f2bf(sv);
        } else {
          ((float*)Cout)[(size_t)row * N + col] = v;
        }
      }
    }
}

__global__ __launch_bounds__(256) void gemm_bt0(
    const unsigned short* __restrict__ A, const unsigned short* __restrict__ Bm,
    const float* __restrict__ bias, void* __restrict__ Cout,
    int M, int N, int K)
{
  __shared__ __align__(16) char smem[32768];
  gemm_body<0>((unsigned short*)smem, (unsigned short*)smem + 8192,
               blockIdx.x, A, Bm, bias, Cout, M, N, K, K, 1);
}

// fc2 split-K x2: blocks [0,128) = K-half 0 (+bias) -> C0; [128,256) -> C1
__global__ __launch_bounds__(256) void gemm_bt1s(
    const unsigned short* __restrict__ A, const unsigned short* __restrict__ Bm,
    const float* __restrict__ bias, float* __restrict__ C0,
    float* __restrict__ C1)
{
  __shared__ __align__(16) char smem[32768];
  const int ntiles = (NTOK / 128) * (DDIM / 128);   // 128
  const int half = blockIdx.x / ntiles;
  const int tile = blockIdx.x % ntiles;
  gemm_body<1>((unsigned short*)smem, (unsigned short*)smem + 8192,
               tile, A + half * 1024, Bm + half * 1024, bias,
               half ? (void*)C1 : (void*)C0,
               NTOK, DDIM, 1024, HDIM, half == 0);
}

__global__ __launch_bounds__(256) void gemm_bt1f(
    const unsigned short* __restrict__ A, const unsigned short* __restrict__ Bm,
    const float* __restrict__ bias, void* __restrict__ Cout,
    int M, int N, int K)
{
  __shared__ __align__(16) char smem[32768];
  gemm_body<1>((unsigned short*)smem, (unsigned short*)smem + 8192,
               blockIdx.x, A, Bm, bias, Cout, M, N, K, K, 1);
}

// ---------------------------------------------------------------------------
// K5: per-token LoRA adapters + final combine + bulk routing outputs
// ---------------------------------------------------------------------------
__global__ __launch_bounds__(256) void k5_lora(
    const float* __restrict__ z, const unsigned short* __restrict__ hpre,
    const float* __restrict__ outpre, const float* __restrict__ outpre2,
    int use2, const int* __restrict__ asgn, const float* __restrict__ asgnw,
    const unsigned short* __restrict__ a1, const unsigned short* __restrict__ b1,
    const unsigned short* __restrict__ a2, const unsigned short* __restrict__ b2,
    float* __restrict__ out0, float* __restrict__ out)
{
  __shared__ float zl[DDIM];
  __shared__ float hl[HDIM];
  __shared__ float t1s[8], t2s[8];
  const int b = blockIdx.x, tid = threadIdx.x;
  {
    float4 v = *(const float4*)&z[(size_t)b * DDIM + tid * 4];
    *(float4*)&zl[tid * 4] = v;
  }
  const int pk = asgn[b];
  const int sc = (pk >> 12) & 3;
  const int eA0 = pk & 15, eA1 = (pk >> 4) & 15;
  const int aA0 = (pk >> 8) & 3, aA1 = (pk >> 10) & 3;
  const float w0 = asgnw[b * 2 + 0], w1 = asgnw[b * 2 + 1];
  if (tid < 16)
    out[O_USED + (size_t)b * 16 + tid] =
        (float)((sc > 0 && tid == eA0) || (sc > 1 && tid == eA1));
  if (tid == 0) {
    out[O_AIDX + (size_t)b * 2 + 0] = sc > 0 ? (float)eA0 : -1.f;
    out[O_AIDX + (size_t)b * 2 + 1] = sc > 1 ? (float)eA1 : -1.f;
    out[O_AW + (size_t)b * 2 + 0] = w0;
    out[O_AW + (size_t)b * 2 + 1] = w1;
    out[O_EVE + b] = sc > 0 ? (float)eA0 : -1.f;
    out[O_EVE + NTOK + b] = sc > 1 ? (float)eA1 : -1.f;
    out[O_EVA + b] = sc > 0 ? (float)aA0 : -1.f;
    out[O_EVA + NTOK + b] = sc > 1 ? (float)aA1 : -1.f;
  }
  float acc[4] = {0.f, 0.f, 0.f, 0.f};
  float wsum = 0.f;
  const int r = tid >> 5, l5 = tid & 31;
  const float4* zg = (const float4*)&z[(size_t)b * DDIM];
  __syncthreads();

  for (int s = 0; s < 2; ++s) {
    if (s >= sc) continue;  // uniform across block
    const float ww = (s == 0) ? w0 : w1;
    const int ad = ((s == 0) ? eA0 : eA1) * 4 + ((s == 0) ? aA0 : aA1);
    wsum += ww;
    {
      const us8v* pa1 = (const us8v*)(a1 + ((size_t)ad * 8 + r) * DDIM);
      float sa = 0.f;
#pragma unroll
      for (int i = 0; i < 4; ++i) {
        const int g = l5 + 32 * i;
        us8v va = pa1[g];
        float4 z0 = zg[g * 2], z1 = zg[g * 2 + 1];
        sa += z0.x * bf2f(va[0]) + z0.y * bf2f(va[1]) +
              z0.z * bf2f(va[2]) + z0.w * bf2f(va[3]) +
              z1.x * bf2f(va[4]) + z1.y * bf2f(va[5]) +
              z1.z * bf2f(va[6]) + z1.w * bf2f(va[7]);
      }
#pragma unroll
      for (int o = 16; o; o >>= 1) sa += __shfl_xor(sa, o, 64);
      if (l5 == 0) t1s[r] = sa;
    }
    __syncthreads();
    {
      float t1r[8];
#pragma unroll
      for (int q = 0; q < 8; ++q) t1r[q] = t1s[q];
      const unsigned short* pb1 = b1 + (size_t)ad * HDIM * 8;
      const unsigned short* ph = hpre + (size_t)b * HDIM;
#pragma unroll
      for (int j = 0; j < 8; ++j) {
        const int hh_i = tid + 256 * j;
        us8v row = *(const us8v*)&pb1[(size_t)hh_i * 8];
        float d1 = 0.f;
#pragma unroll
        for (int q = 0; q < 8; ++q) d1 += t1r[q] * bf2f(row[q]);
        const float hh = bf2f(ph[hh_i]) + d1;  // SCALE = 1
        hl[hh_i] = hh / (1.f + __expf(-hh));
      }
    }
    __syncthreads();
    {
      const us8v* pa2 = (const us8v*)(a2 + ((size_t)ad * 8 + r) * HDIM);
      float sa = 0.f;
#pragma unroll
      for (int i = 0; i < 8; ++i) {
        const int g = l5 + 32 * i;
        us8v va = pa2[g];
        const float* hp = &hl[g * 8];
        sa += hp[0] * bf2f(va[0]) + hp[1] * bf2f(va[1]) +
              hp[2] * bf2f(va[2]) + hp[3] * bf2f(va[3]) +
              hp[4] * bf2f(va[4]) + hp[5] * bf2f(va[5]) +
              hp[6] * bf2f(va[6]) + hp[7] * bf2f(va[7]);
      }
#pragma unroll
      for (int o = 16; o; o >>= 1) sa += __shfl_xor(sa, o, 64);
      if (l5 == 0) t2s[r] = sa;
    }
    __syncthreads();
    {
      float t2r[8];
#pragma unroll
      for (int q = 0; q < 8; ++q) t2r[q] = t2s[q];
      const unsigned short* pb2 = b2 + (size_t)ad * DDIM * 8;
#pragma unroll
      for (int j = 0; j < 4; ++j) {
        const int d = tid + 256 * j;
        us8v row = *(const us8v*)&pb2[(size_t)d * 8];
        float d2 = 0.f;
#pragma unroll
        for (int q = 0; q < 8; ++q) d2 += t2r[q] * bf2f(row[q]);
        acc[j] += ww * d2;  // SCALE = 1
      }
    }
    __syncthreads();
  }
#pragma unroll
  for (int j = 0; j < 4; ++j) {
    const int d = tid + 256 * j;
    float op = outpre[(size_t)b * DDIM + d];
    if (use2) op += outpre2[(size_t)b * DDIM + d];
    out0[(size_t)b * DDIM + d] = zl[d] + wsum * op + acc[j];
  }
}

// ---------------------------------------------------------------------------
extern "C" void kernel_launch(void* const* d_in, const int* in_sizes, int n_in,
                              void* d_out, int out_size, void* d_ws, size_t ws_size,
                              hipStream_t stream)
{
  (void)in_sizes; (void)n_in; (void)out_size;
  const float* z     = (const float*)d_in[0];
  const int*   p_cap = (const int*)d_in[2];
  const int*   p_ban = (const int*)d_in[3];
  const float* p_tau = (const float*)d_in[4];
  const float* p_eps = (const float*)d_in[5];
  const float* fc1w  = (const float*)d_in[6];
  const float* fc1b  = (const float*)d_in[7];
  const float* fc2w  = (const float*)d_in[8];
  const float* fc2b  = (const float*)d_in[9];
  const float* proto = (const float*)d_in[10];
  const float* ak    = (const float*)d_in[11];
  const float* ebias = (const float*)d_in[12];
  const float* a1    = (const float*)d_in[13];
  const float* b1    = (const float*)d_in[14];
  const float* a2    = (const float*)d_in[15];
  const float* b2    = (const float*)d_in[16];
  float* out = (float*)d_out;
  char* ws = (char*)d_ws;

  unsigned short* zbf    = (unsigned short*)(ws + WS_ZBF);
  unsigned short* fc1wbf = (unsigned short*)(ws + WS_FC1WBF);
  unsigned short* fc2wbf = (unsigned short*)(ws + WS_FC2WBF);
  unsigned short* hprebf = (unsigned short*)(ws + WS_HPREBF);
  float*          outpre = (float*)(ws + WS_OUTPRE);
  unsigned short* a1bf   = (unsigned short*)(ws + WS_A1BF);
  unsigned short* b1bf   = (unsigned short*)(ws + WS_B1BF);
  unsigned short* a2bf   = (unsigned short*)(ws + WS_A2BF);
  unsigned short* b2bf   = (unsigned short*)(ws + WS_B2BF);
  unsigned*       cands  = (unsigned*)(ws + WS_CANDS);
  float*          cvals  = (float*)(ws + WS_CVALS);
  unsigned*       argpk  = (unsigned*)(ws + WS_ARGPK);
  int*            asgn   = (int*)(ws + WS_ASGN);
  float*          asgnw  = (float*)(ws + WS_ASGNW);
  float*          outpr2 = (float*)(ws + WS_OUTPR2);
  const int splitk = (ws_size >= WS_TOTAL2) ? 1 : 0;

  k1_scores<<<512, 256, 0, stream>>>(
      z, proto, ebias, ak, p_tau, p_eps, p_ban, zbf, out, cands, cvals, argpk);

  k2_route_conv<<<1 + CONVB, 1024, 0, stream>>>(
      cands, cvals, argpk, p_cap, out, asgn, asgnw,
      fc1w, fc2w, a1, b1, a2, b2,
      fc1wbf, fc2wbf, a1bf, b1bf, a2bf, b2bf);

  // fc1: [2048,1024] x [2048,1024]^T -> silu -> bf16 h_pre
  gemm_bt0<<<(NTOK / 128) * (HDIM / 128), 256, 0, stream>>>(
      zbf, fc1wbf, fc1b, (void*)hprebf, NTOK, HDIM, DDIM);

  // fc2: [2048,2048] x [1024,2048]^T -> +bias -> f32 out_pre (split-K x2)
  if (splitk) {
    gemm_bt1s<<<2 * (NTOK / 128) * (DDIM / 128), 256, 0, stream>>>(
        hprebf, fc2wbf, fc2b, outpre, outpr2);
  } else {
    gemm_bt1f<<<(NTOK / 128) * (DDIM / 128), 256, 0, stream>>>(
        hprebf, fc2wbf, fc2b, (void*)outpre, NTOK, DDIM, HDIM);
  }

  k5_lora<<<NTOK, 256, 0, stream>>>(
      z, hprebf, outpre, outpr2, splitk, asgn, asgnw,
      a1bf, b1bf, a2bf, b2bf, out, out);
}

// Round 8
// 259.845 us; speedup vs baseline: 1.2950x; 1.0498x over previous
//
#include <hip/hip_runtime.h>
#include <stdint.h>

// ---------------------------------------------------------------------------
// MoELatent: B=2048 D=1024 H=2048 E=16 W=4 R=8, top_k=2, cand_k=8
// ---------------------------------------------------------------------------
#define NTOK 2048
#define DDIM 1024
#define HDIM 2048
#define NEXP 16

// output (float) element offsets, in reference return order
#define O_PROBS 2097152   // [2048,16]
#define O_USED  2129920   // [2048,16]
#define O_AIDX  2162688   // [2048,2]
#define O_AW    2166784   // [2048,2]
#define O_HIT   2170880   // scalar
#define O_EVE   2170881   // [2,2048] slot-major
#define O_EVA   2174977   // [2,2048]

// workspace byte offsets — constexpr chain (round-1 lesson: never hand-type)
static constexpr size_t WS_ZBF    = 0;
static constexpr size_t WS_FC1WBF = WS_ZBF    + (size_t)NTOK * DDIM * 2;
static constexpr size_t WS_FC2WBF = WS_FC1WBF + (size_t)HDIM * DDIM * 2;
static constexpr size_t WS_HPREBF = WS_FC2WBF + (size_t)DDIM * HDIM * 2;
static constexpr size_t WS_OUTPRE = WS_HPREBF + (size_t)NTOK * HDIM * 2;
static constexpr size_t WS_A1BF   = WS_OUTPRE + (size_t)NTOK * DDIM * 4;
static constexpr size_t WS_B1BF   = WS_A1BF   + (size_t)16 * 4 * 8 * 1024 * 2;
static constexpr size_t WS_A2BF   = WS_B1BF   + (size_t)16 * 4 * 2048 * 8 * 2;
static constexpr size_t WS_B2BF   = WS_A2BF   + (size_t)16 * 4 * 8 * 2048 * 2;
static constexpr size_t WS_CANDS  = WS_B2BF   + (size_t)16 * 4 * 1024 * 8 * 2;
static constexpr size_t WS_CVALS  = WS_CANDS  + (size_t)NTOK * 4;
static constexpr size_t WS_ARGPK  = WS_CVALS  + (size_t)NTOK * 8 * 4;
static constexpr size_t WS_ASGN   = WS_ARGPK  + (size_t)NTOK * 4;
static constexpr size_t WS_ASGNW  = WS_ASGN   + (size_t)NTOK * 4;
static constexpr size_t WS_OUTPR2 = WS_ASGNW  + (size_t)NTOK * 2 * 4;
static constexpr size_t WS_TOTAL2 = WS_OUTPR2 + (size_t)NTOK * DDIM * 4;

typedef __bf16 v8bf __attribute__((ext_vector_type(8)));
typedef float v4f __attribute__((ext_vector_type(4)));
typedef unsigned short us8v __attribute__((ext_vector_type(8)));

__device__ __forceinline__ unsigned short f2bf(float f) {
  unsigned u = __float_as_uint(f);
  u = u + 0x7fffu + ((u >> 16) & 1u);          // round-to-nearest-even
  return (unsigned short)(u >> 16);
}
__device__ __forceinline__ float bf2f(unsigned short s) {
  return __uint_as_float(((unsigned)s) << 16);
}
__device__ __forceinline__ void gload_lds16(const void* g, void* l) {
  __builtin_amdgcn_global_load_lds(
      (const __attribute__((address_space(1))) void*)g,
      (__attribute__((address_space(3))) void*)l, 16, 0, 0);
}
__device__ __forceinline__ float dot4(float4 a, float4 b) {
  return a.x * b.x + a.y * b.y + a.z * b.z + a.w * b.w;
}

// ---------------------------------------------------------------------------
// K1: 512 blocks x 256 thr, 4 tokens/block. Scores only.
// Phase 1: lane = weight-row, wave = d-quarter, serial in-register reduction.
// Phase 2: thread t<4 does one token's softmax/top-8/argmax fully lane-local.
// ---------------------------------------------------------------------------
__global__ __launch_bounds__(256) void k1_scores(
    const float* __restrict__ z, const float* __restrict__ proto,
    const float* __restrict__ ebias, const float* __restrict__ ak,
    const float* __restrict__ p_tau, const float* __restrict__ p_eps,
    const int* __restrict__ p_ban,
    unsigned short* __restrict__ zbf, float* __restrict__ out,
    unsigned* __restrict__ cands, float* __restrict__ cvals,
    unsigned* __restrict__ argpk)
{
  __shared__ float zs[4][DDIM];        // 16 KB
  __shared__ float part[80 * 17];      // [row][tk*4+wv], stride 17
  __shared__ float sc[4 * 80];         // [token][row]; rows 0-63 ak, 64-79 proto
  const int tid = threadIdx.x;
  const int tb = blockIdx.x * 4;
#pragma unroll
  for (int i = 0; i < 4; ++i) {
    const int col = tid * 4;
    float4 v = *(const float4*)&z[(size_t)(tb + i) * DDIM + col];
    *(float4*)&zs[i][col] = v;
    ushort4 bv;
    bv.x = f2bf(v.x); bv.y = f2bf(v.y); bv.z = f2bf(v.z); bv.w = f2bf(v.w);
    *(ushort4*)&zbf[(size_t)(tb + i) * DDIM + col] = bv;
  }
  __syncthreads();
  const int wv = tid >> 6, l = tid & 63;

  // ---- phase 1: ak rows (all lanes) ----
  {
    const float4* akr = (const float4*)(ak + (size_t)l * DDIM + wv * 256);
    const float4* z0 = (const float4*)&zs[0][0] + wv * 64;
    const float4* z1 = (const float4*)&zs[1][0] + wv * 64;
    const float4* z2 = (const float4*)&zs[2][0] + wv * 64;
    const float4* z3 = (const float4*)&zs[3][0] + wv * 64;
    float a0 = 0.f, a1v = 0.f, a2v = 0.f, a3 = 0.f;
#pragma unroll 8
    for (int i = 0; i < 64; ++i) {
      float4 w = akr[i];
      a0 += dot4(z0[i], w); a1v += dot4(z1[i], w);
      a2v += dot4(z2[i], w); a3 += dot4(z3[i], w);
    }
    part[l * 17 + 0 * 4 + wv] = a0;
    part[l * 17 + 1 * 4 + wv] = a1v;
    part[l * 17 + 2 * 4 + wv] = a2v;
    part[l * 17 + 3 * 4 + wv] = a3;
  }
  // ---- phase 1b: proto rows (lanes 0-15) ----
  if (l < 16) {
    const float4* pr = (const float4*)(proto + (size_t)l * DDIM + wv * 256);
    const float4* z0 = (const float4*)&zs[0][0] + wv * 64;
    const float4* z1 = (const float4*)&zs[1][0] + wv * 64;
    const float4* z2 = (const float4*)&zs[2][0] + wv * 64;
    const float4* z3 = (const float4*)&zs[3][0] + wv * 64;
    float a0 = 0.f, a1v = 0.f, a2v = 0.f, a3 = 0.f;
#pragma unroll 8
    for (int i = 0; i < 64; ++i) {
      float4 w = pr[i];
      a0 += dot4(z0[i], w); a1v += dot4(z1[i], w);
      a2v += dot4(z2[i], w); a3 += dot4(z3[i], w);
    }
    part[(64 + l) * 17 + 0 * 4 + wv] = a0;
    part[(64 + l) * 17 + 1 * 4 + wv] = a1v;
    part[(64 + l) * 17 + 2 * 4 + wv] = a2v;
    part[(64 + l) * 17 + 3 * 4 + wv] = a3;
  }
  __syncthreads();
  for (int o = tid; o < 320; o += 256) {
    const int row = o >> 2, tk = o & 3;
    sc[tk * 80 + row] =
        ((part[row * 17 + tk * 4 + 0] + part[row * 17 + tk * 4 + 1]) +
         part[row * 17 + tk * 4 + 2]) + part[row * 17 + tk * 4 + 3];
  }
  __syncthreads();
  // ---- phase 2: per-token selection, fully lane-local ----
  if (tid < 4) {
    const int t = tb + tid;
    const float tau = fmaxf(p_tau[0], 1e-6f);
    const float eps = p_eps[0];
    const int ban = p_ban[0];
    float lg[16];
#pragma unroll
    for (int e = 0; e < 16; ++e) {
      float v = sc[tid * 80 + 64 + e] / tau + ebias[e];
      lg[e] = (e == ban) ? -1e9f : v;
    }
    float mx = lg[0];
#pragma unroll
    for (int e = 1; e < 16; ++e) mx = fmaxf(mx, lg[e]);
    float ex[16]; float sm = 0.f;
#pragma unroll
    for (int e = 0; e < 16; ++e) { ex[e] = expf(lg[e] - mx); sm += ex[e]; }
    float p[16];
#pragma unroll
    for (int e = 0; e < 16; ++e) {
      p[e] = (1.f - eps) * (ex[e] / sm) + eps / (float)NEXP;
      out[O_PROBS + (size_t)t * NEXP + e] = p[e];
    }
    // top-8: strict > with ascending e = value-desc, index-asc (lax.top_k)
    unsigned pack = 0, taken = 0;
#pragma unroll
    for (int r = 0; r < 8; ++r) {
      float bv = -1e30f; int bi = 0;
#pragma unroll
      for (int e = 0; e < 16; ++e) {
        const bool c = !((taken >> e) & 1u) && (p[e] > bv);
        bv = c ? p[e] : bv; bi = c ? e : bi;
      }
      taken |= 1u << bi;
      pack |= ((unsigned)bi) << (4 * r);
      cvals[(size_t)t * 8 + r] = bv;
    }
    cands[t] = pack;
    // adapter argmax per expert (first max wins, like jnp.argmax)
    unsigned apk = 0;
#pragma unroll
    for (int e = 0; e < 16; ++e) {
      float b = sc[tid * 80 + e * 4]; int bi = 0;
#pragma unroll
      for (int w = 1; w < 4; ++w) {
        const float v = sc[tid * 80 + e * 4 + w];
        if (v > b) { b = v; bi = w; }
      }
      apk |= ((unsigned)bi) << (2 * e);
    }
    argpk[t] = apk;
  }
}

// ---------------------------------------------------------------------------
// K2: block 0 = router (1024 thr, 2 barriers/round, register state,
//     ballots only for available experts + dead-chunk skip);
//     blocks 1..CONVB = f32->bf16 weight conversions (overlap the router).
// ---------------------------------------------------------------------------
#define CONVB 224

__device__ __forceinline__ void route_decide(unsigned c, int avail,
                                             unsigned& m, int& dec) {
  unsigned flags = 0;
#pragma unroll
  for (int j = 0; j < 8; ++j) {
    const int e = (c >> (4 * j)) & 15;
    flags |= ((unsigned)(avail >> e) & 1u) << j;
  }
  const int pc = __popc(flags);
  const int sc = pc < 2 ? pc : 2;
  const int j0 = __ffs(flags) - 1;
  const int j1 = __ffs(flags & (flags - 1)) - 1;
  const int r0 = sc > 0 ? j0 : 0;
  const int r1 = sc > 1 ? j1 : 0;
  const int e0 = (c >> (4 * r0)) & 15;
  const int e1 = (c >> (4 * r1)) & 15;
  m = (sc > 0 ? (1u << e0) : 0u) | (sc > 1 ? (1u << e1) : 0u);
  dec = e0 | (e1 << 4) | (r0 << 8) | (r1 << 11) | (sc << 14);
}

__global__ __launch_bounds__(1024) void k2_route_conv(
    const unsigned* __restrict__ cands, const float* __restrict__ cvals,
    const unsigned* __restrict__ argpk, const int* __restrict__ p_cap,
    float* __restrict__ out, int* __restrict__ asgn, float* __restrict__ asgnw,
    const float* __restrict__ fc1w, const float* __restrict__ fc2w,
    const float* __restrict__ a1, const float* __restrict__ b1,
    const float* __restrict__ a2, const float* __restrict__ b2,
    unsigned short* __restrict__ fc1wbf, unsigned short* __restrict__ fc2wbf,
    unsigned short* __restrict__ a1bf, unsigned short* __restrict__ b1bf,
    unsigned short* __restrict__ a2bf, unsigned short* __restrict__ b2bf)
{
  const int tid = threadIdx.x;
  if (blockIdx.x != 0) {
    // weight conversions: 224 blocks x 1024 thr x 8 iters = 1,835,008 float4
    size_t j = (size_t)(blockIdx.x - 1) * 1024 + tid;
    const size_t stride = (size_t)CONVB * 1024;
    for (; j < 1835008ull; j += stride) {
      const float* src; unsigned short* dst; size_t off;
      if (j < 524288) { src = fc1w; dst = fc1wbf; off = j; }
      else if (j < 1048576) { src = fc2w; dst = fc2wbf; off = j - 524288; }
      else if (j < 1179648) { src = a1; dst = a1bf; off = j - 1048576; }
      else if (j < 1441792) { src = b1; dst = b1bf; off = j - 1179648; }
      else if (j < 1703936) { src = a2; dst = a2bf; off = j - 1441792; }
      else { src = b2; dst = b2bf; off = j - 1703936; }
      float4 v = *(const float4*)&src[off * 4];
      ushort4 bv;
      bv.x = f2bf(v.x); bv.y = f2bf(v.y); bv.z = f2bf(v.z); bv.w = f2bf(v.w);
      *(ushort4*)&dst[off * 4] = bv;
    }
    return;
  }
  // ---- router: 16 waves, wave w owns expert w; 2 barriers/round ----
  __shared__ unsigned long long bal[2][32][17];  // double-buffered ballots
  __shared__ int T[16];
  __shared__ int hitsS;
  const int w = tid >> 6, l = tid & 63;
  if (tid == 0) hitsS = 0;
  const int capl = max(1, p_cap[0]);
  const unsigned cA = cands[tid], cB = cands[tid + 1024];
  const unsigned aA = argpk[tid], aB = argpk[tid + 1024];
  float cvA[8], cvB[8];
#pragma unroll
  for (int q = 0; q < 8; ++q) {
    cvA[q] = cvals[(size_t)tid * 8 + q];
    cvB[q] = cvals[(size_t)(tid + 1024) * 8 + q];
  }
  int avail = 0xFFFF, t0 = 0, capw = 0, hits = 0;

  for (int round = 0; round < 20; ++round) {
    const int p = round & 1;
    // phase A: decide + ballots for available experts only; skip dead chunks
    unsigned mA = 0, mB = 0;
    int dA = 0, dB = 0;
    if (tid >= t0) route_decide(cA, avail, mA, dA);
    if (tid + 1024 >= t0) route_decide(cB, avail, mB, dB);
    if (w * 64 + 63 >= t0) {
      for (int av = avail; av; av &= av - 1) {
        const int e = __ffs(av) - 1;
        unsigned long long b = __ballot((mA >> e) & 1);
        if (l == e) bal[p][w][l] = b;
      }
    } else if (l < 16) {
      bal[p][w][l] = 0ull;
    }
    {  // second half: chunk w+16 covers tokens [1024 + w*64, +64)
      for (int av = avail; av; av &= av - 1) {
        const int e = __ffs(av) - 1;
        unsigned long long b = __ballot((mB >> e) & 1);
        if (l == e) bal[p][w + 16][l] = b;
      }
    }
    __syncthreads();                      // barrier 1
    // phase B: wave w computes its expert's crossing T[w]
    unsigned long long bm = 0;
    int myT = 0x7FFFFFFF;
    const bool eav = (avail >> w) & 1;
    if (eav) {
      int cnt = 0;
      if (l < 32) { bm = bal[p][l][w]; cnt = __popcll(bm); }
      int tot = cnt;
#pragma unroll
      for (int o = 32; o; o >>= 1) tot += __shfl_xor(tot, o, 64);
      const int rem = capl - capw;
      if (tot >= rem) {
        int incl = cnt;
#pragma unroll
        for (int o = 1; o < 32; o <<= 1) {
          int u = __shfl_up(incl, o, 64);
          if (l >= o) incl += u;
        }
        if (l < 32) {
          const int need = rem - (incl - cnt);
          if (need >= 1 && need <= cnt) {
            unsigned long long bb = bm;
            for (int i = 1; i < need; ++i) bb &= bb - 1;
            myT = l * 64 + (__ffsll((unsigned long long)bb) - 1);
          }
        }
#pragma unroll
        for (int o = 32; o; o >>= 1) myT = min(myT, __shfl_xor(myT, o, 64));
      }
    }
    if (l == 0) T[w] = myT;
    __syncthreads();                      // barrier 2
    // phase C: every wave derives ts/done/avail/t0 locally
    const int tv = (l < 16) ? T[l] : 0x7FFFFFFF;
    int ts = tv;
#pragma unroll
    for (int o = 32; o; o >>= 1) ts = min(ts, __shfl_xor(ts, o, 64));
    const bool done = (ts == 0x7FFFFFFF);
    const int tfin = done ? (NTOK - 1) : ts;
    unsigned long long crossed = __ballot((l < 16) && !done && (tv == ts));
    // cap update for this wave's expert (register-resident)
    if (eav) {
      int c2 = 0;
      if (l < 32) {
        const int hi = tfin - l * 64;
        unsigned long long mk =
            (hi < 0) ? 0ull : (hi >= 63 ? ~0ull : ((1ull << (hi + 1)) - 1ull));
        c2 = __popcll(bm & mk);
      }
#pragma unroll
      for (int o = 32; o; o >>= 1) c2 += __shfl_xor(c2, o, 64);
      capw += c2;
    }
    // finalize tokens in [t0, tfin] — cvals from registers (static select)
    {
      const int t = tid;
      if (t >= t0 && t <= tfin) {
        const int e0 = dA & 15, e1 = (dA >> 4) & 15;
        const int r0 = (dA >> 8) & 7, r1 = (dA >> 11) & 7, sc = (dA >> 14) & 3;
        const int a0 = (aA >> (2 * e0)) & 3, a1i = (aA >> (2 * e1)) & 3;
        float w0 = 0.f, w1v = 0.f;
#pragma unroll
        for (int q = 0; q < 8; ++q) {
          if (q == r0) w0 = cvA[q];
          if (q == r1) w1v = cvA[q];
        }
        asgn[t] = e0 | (e1 << 4) | (a0 << 8) | (a1i << 10) | (sc << 12);
        asgnw[t * 2 + 0] = sc > 0 ? w0 : 0.f;
        asgnw[t * 2 + 1] = sc > 1 ? w1v : 0.f;
        hits += (sc > 0 && r0 > 0) + (sc > 1 && r1 > 0);
      }
    }
    {
      const int t = tid + 1024;
      if (t >= t0 && t <= tfin) {
        const int e0 = dB & 15, e1 = (dB >> 4) & 15;
        const int r0 = (dB >> 8) & 7, r1 = (dB >> 11) & 7, sc = (dB >> 14) & 3;
        const int a0 = (aB >> (2 * e0)) & 3, a1i = (aB >> (2 * e1)) & 3;
        float w0 = 0.f, w1v = 0.f;
#pragma unroll
        for (int q = 0; q < 8; ++q) {
          if (q == r0) w0 = cvB[q];
          if (q == r1) w1v = cvB[q];
        }
        asgn[t] = e0 | (e1 << 4) | (a0 << 8) | (a1i << 10) | (sc << 12);
        asgnw[t * 2 + 0] = sc > 0 ? w0 : 0.f;
        asgnw[t * 2 + 1] = sc > 1 ? w1v : 0.f;
        hits += (sc > 0 && r0 > 0) + (sc > 1 && r1 > 0);
      }
    }
    avail &= ~(int)(unsigned)(crossed & 0xFFFFull);
    t0 = tfin + 1;
    if (done) break;
  }
#pragma unroll
  for (int o = 32; o; o >>= 1) hits += __shfl_xor(hits, o, 64);
  if (l == 0) atomicAdd(&hitsS, hits);
  __syncthreads();
  if (tid == 0) out[O_HIT] = (float)hitsS / (float)(NTOK * 2);
}

// ---------------------------------------------------------------------------
// bf16 GEMM body: C = A[M,Kloop] * B[N,Kloop]^T (row stride lda), 128x128 tile,
// BK=64, 4 waves, mfma_f32_16x16x32_bf16, global_load_lds width 16.
// EPI 0: silu(x+bias) -> bf16. EPI 1: x+(bias?) -> f32.
// ---------------------------------------------------------------------------
template <int EPI>
__device__ __forceinline__ void gemm_body(
    unsigned short* As, unsigned short* Bs, int bid,
    const unsigned short* __restrict__ A, const unsigned short* __restrict__ Bm,
    const float* __restrict__ bias, void* __restrict__ Cout,
    int M, int N, int Kloop, int lda, int add_bias)
{
  const int tid = threadIdx.x;
  const int wv = tid >> 6, l = tid & 63;
  const int ntile = N >> 7;
  const int trow = (bid / ntile) << 7;
  const int tcol = (bid % ntile) << 7;
  const int wr = wv >> 1, wc = wv & 1;
  v4f acc[4][4];
#pragma unroll
  for (int m = 0; m < 4; ++m)
#pragma unroll
    for (int n = 0; n < 4; ++n) acc[m][n] = (v4f){0.f, 0.f, 0.f, 0.f};

  const int lrow8 = l >> 3;
  const int lcol8 = (l & 7) << 3;
  const unsigned short* gA = A + (size_t)trow * lda;
  const unsigned short* gB = Bm + (size_t)tcol * lda;
  const int fr = l & 15, kof = (l >> 4) << 3;

  for (int k0 = 0; k0 < Kloop; k0 += 64) {
    __syncthreads();
#pragma unroll
    for (int i = 0; i < 4; ++i) {
      const int s = (wv << 2) + i;  // segment 0..15 = 8 rows each
      gload_lds16(gA + (size_t)(s * 8 + lrow8) * lda + k0 + lcol8, &As[s * 512]);
      gload_lds16(gB + (size_t)(s * 8 + lrow8) * lda + k0 + lcol8, &Bs[s * 512]);
    }
    __syncthreads();
    v8bf af[4][2], bf[4][2];
#pragma unroll
    for (int m = 0; m < 4; ++m) {
      const int row = wr * 64 + m * 16 + fr;
      af[m][0] = *(const v8bf*)&As[row * 64 + kof];
      af[m][1] = *(const v8bf*)&As[row * 64 + 32 + kof];
    }
#pragma unroll
    for (int n = 0; n < 4; ++n) {
      const int row = wc * 64 + n * 16 + fr;
      bf[n][0] = *(const v8bf*)&Bs[row * 64 + kof];
      bf[n][1] = *(const v8bf*)&Bs[row * 64 + 32 + kof];
    }
#pragma unroll
    for (int ks = 0; ks < 2; ++ks)
#pragma unroll
      for (int m = 0; m < 4; ++m)
#pragma unroll
        for (int n = 0; n < 4; ++n)
          acc[m][n] = __builtin_amdgcn_mfma_f32_16x16x32_bf16(
              af[m][ks], bf[n][ks], acc[m][n], 0, 0, 0);
  }
  // epilogue: C/D layout col=lane&15, row=(lane>>4)*4+j  [m89/m91]
  const int fq = l >> 4;
#pragma unroll
  for (int m = 0; m < 4; ++m)
#pragma unroll
    for (int n = 0; n < 4; ++n) {
      const int col = tcol + wc * 64 + n * 16 + fr;
      const float bc = add_bias ? bias[col] : 0.f;
#pragma unroll
      for (int j = 0; j < 4; ++j) {
        const int row = trow + wr * 64 + m * 16 + fq * 4 + j;
        const float v = acc[m][n][j] + bc;
        if (EPI == 0) {
          const float sv = v / (1.f + __expf(-v));
          ((unsigned short*)Cout)[(size_t)row * N + col] = f2bf(sv);
        } else {
          ((float*)Cout)[(size_t)row * N + col] = v;
        }
      }
    }
}

__global__ __launch_bounds__(256) void gemm_bt0(
    const unsigned short* __restrict__ A, const unsigned short* __restrict__ Bm,
    const float* __restrict__ bias, void* __restrict__ Cout,
    int M, int N, int K)
{
  __shared__ __align__(16) char smem[32768];
  gemm_body<0>((unsigned short*)smem, (unsigned short*)smem + 8192,
               blockIdx.x, A, Bm, bias, Cout, M, N, K, K, 1);
}

// fc2 split-K x2: blocks [0,128) = K-half 0 (+bias) -> C0; [128,256) -> C1
__global__ __launch_bounds__(256) void gemm_bt1s(
    const unsigned short* __restrict__ A, const unsigned short* __restrict__ Bm,
    const float* __restrict__ bias, float* __restrict__ C0,
    float* __restrict__ C1)
{
  __shared__ __align__(16) char smem[32768];
  const int ntiles = (NTOK / 128) * (DDIM / 128);   // 128
  const int half = blockIdx.x / ntiles;
  const int tile = blockIdx.x % ntiles;
  gemm_body<1>((unsigned short*)smem, (unsigned short*)smem + 8192,
               tile, A + half * 1024, Bm + half * 1024, bias,
               half ? (void*)C1 : (void*)C0,
               NTOK, DDIM, 1024, HDIM, half == 0);
}

__global__ __launch_bounds__(256) void gemm_bt1f(
    const unsigned short* __restrict__ A, const unsigned short* __restrict__ Bm,
    const float* __restrict__ bias, void* __restrict__ Cout,
    int M, int N, int K)
{
  __shared__ __align__(16) char smem[32768];
  gemm_body<1>((unsigned short*)smem, (unsigned short*)smem + 8192,
               blockIdx.x, A, Bm, bias, Cout, M, N, K, K, 1);
}

// ---------------------------------------------------------------------------
// K5: per-token LoRA adapters + final combine + bulk routing outputs.
// Slot-parallel: half-block (128 thr) per expert-slot; separate hl/t1s/t2s;
// weighted d2 into zero-init d2a[2][DDIM]; block-wide barriers (non-divergent).
// ---------------------------------------------------------------------------
__global__ __launch_bounds__(256) void k5_lora(
    const float* __restrict__ z, const unsigned short* __restrict__ hpre,
    const float* __restrict__ outpre, const float* __restrict__ outpre2,
    int use2, const int* __restrict__ asgn, const float* __restrict__ asgnw,
    const unsigned short* __restrict__ a1, const unsigned short* __restrict__ b1,
    const unsigned short* __restrict__ a2, const unsigned short* __restrict__ b2,
    float* __restrict__ out0, float* __restrict__ out)
{
  __shared__ float zl[DDIM];            // 4 KB
  __shared__ float hl[2][HDIM];         // 16 KB
  __shared__ float d2a[2][DDIM];        // 8 KB
  __shared__ float t1s[2][8], t2s[2][8];
  const int b = blockIdx.x, tid = threadIdx.x;
  {
    float4 v = *(const float4*)&z[(size_t)b * DDIM + tid * 4];
    *(float4*)&zl[tid * 4] = v;
  }
#pragma unroll
  for (int j = 0; j < 8; ++j) ((float*)d2a)[tid + 256 * j] = 0.f;
  const int pk = asgn[b];
  const int sc = (pk >> 12) & 3;
  const int eA0 = pk & 15, eA1 = (pk >> 4) & 15;
  const int aA0 = (pk >> 8) & 3, aA1 = (pk >> 10) & 3;
  const float w0 = asgnw[b * 2 + 0], w1 = asgnw[b * 2 + 1];
  if (tid < 16)
    out[O_USED + (size_t)b * 16 + tid] =
        (float)((sc > 0 && tid == eA0) || (sc > 1 && tid == eA1));
  if (tid == 0) {
    out[O_AIDX + (size_t)b * 2 + 0] = sc > 0 ? (float)eA0 : -1.f;
    out[O_AIDX + (size_t)b * 2 + 1] = sc > 1 ? (float)eA1 : -1.f;
    out[O_AW + (size_t)b * 2 + 0] = w0;
    out[O_AW + (size_t)b * 2 + 1] = w1;
    out[O_EVE + b] = sc > 0 ? (float)eA0 : -1.f;
    out[O_EVE + NTOK + b] = sc > 1 ? (float)eA1 : -1.f;
    out[O_EVA + b] = sc > 0 ? (float)aA0 : -1.f;
    out[O_EVA + NTOK + b] = sc > 1 ? (float)aA1 : -1.f;
  }
  const int half = tid >> 7;            // slot index
  const int ht = tid & 127;
  const int r4 = ht >> 5, l5 = ht & 31;
  const bool valid = half < sc;         // uniform per half
  const float ww = half ? w1 : w0;
  const int ad = (half ? eA1 : eA0) * 4 + (half ? aA1 : aA0);
  const float4* zg = (const float4*)&z[(size_t)b * DDIM];
  __syncthreads();

  // t1[rr] = z . a1[ad][rr][:]  (4 r-groups x 2 rows per half)
  if (valid) {
#pragma unroll
    for (int rr = r4; rr < 8; rr += 4) {
      const us8v* pa1 = (const us8v*)(a1 + ((size_t)ad * 8 + rr) * DDIM);
      float sa = 0.f;
#pragma unroll
      for (int i = 0; i < 4; ++i) {
        const int g = l5 + 32 * i;
        us8v va = pa1[g];
        float4 z0 = zg[g * 2], z1 = zg[g * 2 + 1];
        sa += z0.x * bf2f(va[0]) + z0.y * bf2f(va[1]) +
              z0.z * bf2f(va[2]) + z0.w * bf2f(va[3]) +
              z1.x * bf2f(va[4]) + z1.y * bf2f(va[5]) +
              z1.z * bf2f(va[6]) + z1.w * bf2f(va[7]);
      }
#pragma unroll
      for (int o = 16; o; o >>= 1) sa += __shfl_xor(sa, o, 64);
      if (l5 == 0) t1s[half][rr] = sa;
    }
  }
  __syncthreads();
  // h = silu(h_pre + B1 t1): 128 thr x 16 h each
  if (valid) {
    float t1r[8];
#pragma unroll
    for (int q = 0; q < 8; ++q) t1r[q] = t1s[half][q];
    const unsigned short* pb1 = b1 + (size_t)ad * HDIM * 8;
    const unsigned short* ph = hpre + (size_t)b * HDIM;
#pragma unroll
    for (int j = 0; j < 16; ++j) {
      const int hh_i = ht + 128 * j;
      us8v row = *(const us8v*)&pb1[(size_t)hh_i * 8];
      float d1 = 0.f;
#pragma unroll
      for (int q = 0; q < 8; ++q) d1 += t1r[q] * bf2f(row[q]);
      const float hh = bf2f(ph[hh_i]) + d1;  // SCALE = 1
      hl[half][hh_i] = hh / (1.f + __expf(-hh));
    }
  }
  __syncthreads();
  // t2[rr] = h . a2[ad][rr][:]
  if (valid) {
#pragma unroll
    for (int rr = r4; rr < 8; rr += 4) {
      const us8v* pa2 = (const us8v*)(a2 + ((size_t)ad * 8 + rr) * HDIM);
      float sa = 0.f;
#pragma unroll
      for (int i = 0; i < 8; ++i) {
        const int g = l5 + 32 * i;
        us8v va = pa2[g];
        const float* hp = &hl[half][g * 8];
        sa += hp[0] * bf2f(va[0]) + hp[1] * bf2f(va[1]) +
              hp[2] * bf2f(va[2]) + hp[3] * bf2f(va[3]) +
              hp[4] * bf2f(va[4]) + hp[5] * bf2f(va[5]) +
              hp[6] * bf2f(va[6]) + hp[7] * bf2f(va[7]);
      }
#pragma unroll
      for (int o = 16; o; o >>= 1) sa += __shfl_xor(sa, o, 64);
      if (l5 == 0) t2s[half][rr] = sa;
    }
  }
  __syncthreads();
  // d2: 128 thr x 8 d each -> d2a[half]
  if (valid) {
    float t2r[8];
#pragma unroll
    for (int q = 0; q < 8; ++q) t2r[q] = t2s[half][q];
    const unsigned short* pb2 = b2 + (size_t)ad * DDIM * 8;
#pragma unroll
    for (int j = 0; j < 8; ++j) {
      const int d = ht + 128 * j;
      us8v row = *(const us8v*)&pb2[(size_t)d * 8];
      float d2 = 0.f;
#pragma unroll
      for (int q = 0; q < 8; ++q) d2 += t2r[q] * bf2f(row[q]);
      d2a[half][d] = ww * d2;  // SCALE = 1
    }
  }
  __syncthreads();
  const float wsum = (sc > 0 ? w0 : 0.f) + (sc > 1 ? w1 : 0.f);
#pragma unroll
  for (int j = 0; j < 4; ++j) {
    const int d = tid + 256 * j;
    float op = outpre[(size_t)b * DDIM + d];
    if (use2) op += outpre2[(size_t)b * DDIM + d];
    out0[(size_t)b * DDIM + d] = zl[d] + wsum * op + d2a[0][d] + d2a[1][d];
  }
}

// ---------------------------------------------------------------------------
extern "C" void kernel_launch(void* const* d_in, const int* in_sizes, int n_in,
                              void* d_out, int out_size, void* d_ws, size_t ws_size,
                              hipStream_t stream)
{
  (void)in_sizes; (void)n_in; (void)out_size;
  const float* z     = (const float*)d_in[0];
  const int*   p_cap = (const int*)d_in[2];
  const int*   p_ban = (const int*)d_in[3];
  const float* p_tau = (const float*)d_in[4];
  const float* p_eps = (const float*)d_in[5];
  const float* fc1w  = (const float*)d_in[6];
  const float* fc1b  = (const float*)d_in[7];
  const float* fc2w  = (const float*)d_in[8];
  const float* fc2b  = (const float*)d_in[9];
  const float* proto = (const float*)d_in[10];
  const float* ak    = (const float*)d_in[11];
  const float* ebias = (const float*)d_in[12];
  const float* a1    = (const float*)d_in[13];
  const float* b1    = (const float*)d_in[14];
  const float* a2    = (const float*)d_in[15];
  const float* b2    = (const float*)d_in[16];
  float* out = (float*)d_out;
  char* ws = (char*)d_ws;

  unsigned short* zbf    = (unsigned short*)(ws + WS_ZBF);
  unsigned short* fc1wbf = (unsigned short*)(ws + WS_FC1WBF);
  unsigned short* fc2wbf = (unsigned short*)(ws + WS_FC2WBF);
  unsigned short* hprebf = (unsigned short*)(ws + WS_HPREBF);
  float*          outpre = (float*)(ws + WS_OUTPRE);
  unsigned short* a1bf   = (unsigned short*)(ws + WS_A1BF);
  unsigned short* b1bf   = (unsigned short*)(ws + WS_B1BF);
  unsigned short* a2bf   = (unsigned short*)(ws + WS_A2BF);
  unsigned short* b2bf   = (unsigned short*)(ws + WS_B2BF);
  unsigned*       cands  = (unsigned*)(ws + WS_CANDS);
  float*          cvals  = (float*)(ws + WS_CVALS);
  unsigned*       argpk  = (unsigned*)(ws + WS_ARGPK);
  int*            asgn   = (int*)(ws + WS_ASGN);
  float*          asgnw  = (float*)(ws + WS_ASGNW);
  float*          outpr2 = (float*)(ws + WS_OUTPR2);
  const int splitk = (ws_size >= WS_TOTAL2) ? 1 : 0;

  k1_scores<<<512, 256, 0, stream>>>(
      z, proto, ebias, ak, p_tau, p_eps, p_ban, zbf, out, cands, cvals, argpk);

  k2_route_conv<<<1 + CONVB, 1024, 0, stream>>>(
      cands, cvals, argpk, p_cap, out, asgn, asgnw,
      fc1w, fc2w, a1, b1, a2, b2,
      fc1wbf, fc2wbf, a1bf, b1bf, a2bf, b2bf);

  // fc1: [2048,1024] x [2048,1024]^T -> silu -> bf16 h_pre
  gemm_bt0<<<(NTOK / 128) * (HDIM / 128), 256, 0, stream>>>(
      zbf, fc1wbf, fc1b, (void*)hprebf, NTOK, HDIM, DDIM);

  // fc2: [2048,2048] x [1024,2048]^T -> +bias -> f32 out_pre (split-K x2)
  if (splitk) {
    gemm_bt1s<<<2 * (NTOK / 128) * (DDIM / 128), 256, 0, stream>>>(
        hprebf, fc2wbf, fc2b, outpre, outpr2);
  } else {
    gemm_bt1f<<<(NTOK / 128) * (DDIM / 128), 256, 0, stream>>>(
        hprebf, fc2wbf, fc2b, (void*)outpre, NTOK, DDIM, HDIM);
  }

  k5_lora<<<NTOK, 256, 0, stream>>>(
      z, hprebf, outpre, outpr2, splitk, asgn, asgnw,
      a1bf, b1bf, a2bf, b2bf, out, out);
}

// Round 9
// 235.452 us; speedup vs baseline: 1.4291x; 1.1036x over previous
//
#include <hip/hip_runtime.h>
#include <stdint.h>

// ---------------------------------------------------------------------------
// MoELatent: B=2048 D=1024 H=2048 E=16 W=4 R=8, top_k=2, cand_k=8
// ---------------------------------------------------------------------------
#define NTOK 2048
#define DDIM 1024
#define HDIM 2048
#define NEXP 16

// output (float) element offsets, in reference return order
#define O_PROBS 2097152   // [2048,16]
#define O_USED  2129920   // [2048,16]
#define O_AIDX  2162688   // [2048,2]
#define O_AW    2166784   // [2048,2]
#define O_HIT   2170880   // scalar
#define O_EVE   2170881   // [2,2048] slot-major
#define O_EVA   2174977   // [2,2048]

// workspace byte offsets — constexpr chain (round-1 lesson: never hand-type)
static constexpr size_t WS_ZBF    = 0;
static constexpr size_t WS_FC1WBF = WS_ZBF    + (size_t)NTOK * DDIM * 2;
static constexpr size_t WS_FC2WBF = WS_FC1WBF + (size_t)HDIM * DDIM * 2;
static constexpr size_t WS_HPREBF = WS_FC2WBF + (size_t)DDIM * HDIM * 2;
static constexpr size_t WS_OUTPRE = WS_HPREBF + (size_t)NTOK * HDIM * 2;
static constexpr size_t WS_A1BF   = WS_OUTPRE + (size_t)NTOK * DDIM * 4;
static constexpr size_t WS_B1BF   = WS_A1BF   + (size_t)16 * 4 * 8 * 1024 * 2;
static constexpr size_t WS_A2BF   = WS_B1BF   + (size_t)16 * 4 * 2048 * 8 * 2;
static constexpr size_t WS_B2BF   = WS_A2BF   + (size_t)16 * 4 * 8 * 2048 * 2;
static constexpr size_t WS_CANDS  = WS_B2BF   + (size_t)16 * 4 * 1024 * 8 * 2;
static constexpr size_t WS_CVALS  = WS_CANDS  + (size_t)NTOK * 4;
static constexpr size_t WS_ARGPK  = WS_CVALS  + (size_t)NTOK * 8 * 4;
static constexpr size_t WS_ASGN   = WS_ARGPK  + (size_t)NTOK * 4;
static constexpr size_t WS_ASGNW  = WS_ASGN   + (size_t)NTOK * 4;
static constexpr size_t WS_OUTPR2 = WS_ASGNW  + (size_t)NTOK * 2 * 4;
static constexpr size_t WS_TOTAL2 = WS_OUTPR2 + (size_t)NTOK * DDIM * 4;

typedef __bf16 v8bf __attribute__((ext_vector_type(8)));
typedef float v4f __attribute__((ext_vector_type(4)));
typedef unsigned short us8v __attribute__((ext_vector_type(8)));

__device__ __forceinline__ unsigned short f2bf(float f) {
  unsigned u = __float_as_uint(f);
  u = u + 0x7fffu + ((u >> 16) & 1u);          // round-to-nearest-even
  return (unsigned short)(u >> 16);
}
__device__ __forceinline__ float bf2f(unsigned short s) {
  return __uint_as_float(((unsigned)s) << 16);
}
__device__ __forceinline__ void gload_lds16(const void* g, void* l) {
  __builtin_amdgcn_global_load_lds(
      (const __attribute__((address_space(1))) void*)g,
      (__attribute__((address_space(3))) void*)l, 16, 0, 0);
}
__device__ __forceinline__ float dot4(float4 a, float4 b) {
  return a.x * b.x + a.y * b.y + a.z * b.z + a.w * b.w;
}

// ---------------------------------------------------------------------------
// K1: 512 blocks x 256 thr, 4 tokens/block. Scores + fc1w conv tail
// (fc1wbf must be ready before the merged fc1 kernel launches).
// ---------------------------------------------------------------------------
__global__ __launch_bounds__(256) void k1_scores(
    const float* __restrict__ z, const float* __restrict__ proto,
    const float* __restrict__ ebias, const float* __restrict__ ak,
    const float* __restrict__ p_tau, const float* __restrict__ p_eps,
    const int* __restrict__ p_ban,
    unsigned short* __restrict__ zbf, float* __restrict__ out,
    unsigned* __restrict__ cands, float* __restrict__ cvals,
    unsigned* __restrict__ argpk,
    const float* __restrict__ fc1w, unsigned short* __restrict__ fc1wbf)
{
  __shared__ float zs[4][DDIM];        // 16 KB
  __shared__ float part[80 * 17];      // [row][tk*4+wv], stride 17
  __shared__ float sc[4 * 80];         // [token][row]; rows 0-63 ak, 64-79 proto
  const int tid = threadIdx.x;
  const int tb = blockIdx.x * 4;
#pragma unroll
  for (int i = 0; i < 4; ++i) {
    const int col = tid * 4;
    float4 v = *(const float4*)&z[(size_t)(tb + i) * DDIM + col];
    *(float4*)&zs[i][col] = v;
    ushort4 bv;
    bv.x = f2bf(v.x); bv.y = f2bf(v.y); bv.z = f2bf(v.z); bv.w = f2bf(v.w);
    *(ushort4*)&zbf[(size_t)(tb + i) * DDIM + col] = bv;
  }
  __syncthreads();
  const int wv = tid >> 6, l = tid & 63;

  // ---- phase 1: ak rows (all lanes) ----
  {
    const float4* akr = (const float4*)(ak + (size_t)l * DDIM + wv * 256);
    const float4* z0 = (const float4*)&zs[0][0] + wv * 64;
    const float4* z1 = (const float4*)&zs[1][0] + wv * 64;
    const float4* z2 = (const float4*)&zs[2][0] + wv * 64;
    const float4* z3 = (const float4*)&zs[3][0] + wv * 64;
    float a0 = 0.f, a1v = 0.f, a2v = 0.f, a3 = 0.f;
#pragma unroll 8
    for (int i = 0; i < 64; ++i) {
      float4 w = akr[i];
      a0 += dot4(z0[i], w); a1v += dot4(z1[i], w);
      a2v += dot4(z2[i], w); a3 += dot4(z3[i], w);
    }
    part[l * 17 + 0 * 4 + wv] = a0;
    part[l * 17 + 1 * 4 + wv] = a1v;
    part[l * 17 + 2 * 4 + wv] = a2v;
    part[l * 17 + 3 * 4 + wv] = a3;
  }
  // ---- phase 1b: proto rows (lanes 0-15) ----
  if (l < 16) {
    const float4* pr = (const float4*)(proto + (size_t)l * DDIM + wv * 256);
    const float4* z0 = (const float4*)&zs[0][0] + wv * 64;
    const float4* z1 = (const float4*)&zs[1][0] + wv * 64;
    const float4* z2 = (const float4*)&zs[2][0] + wv * 64;
    const float4* z3 = (const float4*)&zs[3][0] + wv * 64;
    float a0 = 0.f, a1v = 0.f, a2v = 0.f, a3 = 0.f;
#pragma unroll 8
    for (int i = 0; i < 64; ++i) {
      float4 w = pr[i];
      a0 += dot4(z0[i], w); a1v += dot4(z1[i], w);
      a2v += dot4(z2[i], w); a3 += dot4(z3[i], w);
    }
    part[(64 + l) * 17 + 0 * 4 + wv] = a0;
    part[(64 + l) * 17 + 1 * 4 + wv] = a1v;
    part[(64 + l) * 17 + 2 * 4 + wv] = a2v;
    part[(64 + l) * 17 + 3 * 4 + wv] = a3;
  }
  __syncthreads();
  for (int o = tid; o < 320; o += 256) {
    const int row = o >> 2, tk = o & 3;
    sc[tk * 80 + row] =
        ((part[row * 17 + tk * 4 + 0] + part[row * 17 + tk * 4 + 1]) +
         part[row * 17 + tk * 4 + 2]) + part[row * 17 + tk * 4 + 3];
  }
  __syncthreads();
  // ---- phase 2: per-token selection, fully lane-local ----
  if (tid < 4) {
    const int t = tb + tid;
    const float tau = fmaxf(p_tau[0], 1e-6f);
    const float eps = p_eps[0];
    const int ban = p_ban[0];
    float lg[16];
#pragma unroll
    for (int e = 0; e < 16; ++e) {
      float v = sc[tid * 80 + 64 + e] / tau + ebias[e];
      lg[e] = (e == ban) ? -1e9f : v;
    }
    float mx = lg[0];
#pragma unroll
    for (int e = 1; e < 16; ++e) mx = fmaxf(mx, lg[e]);
    float ex[16]; float sm = 0.f;
#pragma unroll
    for (int e = 0; e < 16; ++e) { ex[e] = expf(lg[e] - mx); sm += ex[e]; }
    float p[16];
#pragma unroll
    for (int e = 0; e < 16; ++e) {
      p[e] = (1.f - eps) * (ex[e] / sm) + eps / (float)NEXP;
      out[O_PROBS + (size_t)t * NEXP + e] = p[e];
    }
    // top-8: strict > with ascending e = value-desc, index-asc (lax.top_k)
    unsigned pack = 0, taken = 0;
#pragma unroll
    for (int r = 0; r < 8; ++r) {
      float bv = -1e30f; int bi = 0;
#pragma unroll
      for (int e = 0; e < 16; ++e) {
        const bool c = !((taken >> e) & 1u) && (p[e] > bv);
        bv = c ? p[e] : bv; bi = c ? e : bi;
      }
      taken |= 1u << bi;
      pack |= ((unsigned)bi) << (4 * r);
      cvals[(size_t)t * 8 + r] = bv;
    }
    cands[t] = pack;
    // adapter argmax per expert (first max wins, like jnp.argmax)
    unsigned apk = 0;
#pragma unroll
    for (int e = 0; e < 16; ++e) {
      float b = sc[tid * 80 + e * 4]; int bi = 0;
#pragma unroll
      for (int w = 1; w < 4; ++w) {
        const float v = sc[tid * 80 + e * 4 + w];
        if (v > b) { b = v; bi = w; }
      }
      apk |= ((unsigned)bi) << (2 * e);
    }
    argpk[t] = apk;
  }
  // ---- fc1w conv tail: 524288 float4s / (512*256) = 4 iters ----
  {
    size_t j = (size_t)blockIdx.x * 256 + tid;
    for (; j < 524288ull; j += (size_t)512 * 256) {
      float4 v = *(const float4*)&fc1w[j * 4];
      ushort4 bv;
      bv.x = f2bf(v.x); bv.y = f2bf(v.y); bv.z = f2bf(v.z); bv.w = f2bf(v.w);
      *(ushort4*)&fc1wbf[j * 4] = bv;
    }
  }
}

// ---------------------------------------------------------------------------
// 1024-thr GEMM body: 256x128 tile, BK=64, 16 waves (8 wr x 2 wc),
// per-wave 32x64 output (acc[2][4]). Same LDS row layout / fragment / C-D
// mapping as the verified 4-wave body, re-parameterized.
// ---------------------------------------------------------------------------
template <int EPI>
__device__ __forceinline__ void gemm_w16(
    unsigned short* As, unsigned short* Bs, int bid,
    const unsigned short* __restrict__ A, const unsigned short* __restrict__ Bm,
    const float* __restrict__ bias, void* __restrict__ Cout,
    int N, int Kloop, int lda, int add_bias)
{
  const int tid = threadIdx.x;
  const int wv = tid >> 6, l = tid & 63;
  const int ntile = N >> 7;
  const int trow = (bid / ntile) << 8;      // 256-row tiles
  const int tcol = (bid % ntile) << 7;      // 128-col tiles
  const int wr = wv >> 1, wc = wv & 1;      // 8 x 2 wave grid
  v4f acc[2][4];
#pragma unroll
  for (int m = 0; m < 2; ++m)
#pragma unroll
    for (int n = 0; n < 4; ++n) acc[m][n] = (v4f){0.f, 0.f, 0.f, 0.f};

  const int lrow8 = l >> 3;
  const int lcol8 = (l & 7) << 3;
  const unsigned short* gA = A + (size_t)trow * lda;
  const unsigned short* gB = Bm + (size_t)tcol * lda;
  const int fr = l & 15, kof = (l >> 4) << 3;

  for (int k0 = 0; k0 < Kloop; k0 += 64) {
    __syncthreads();
#pragma unroll
    for (int i = 0; i < 2; ++i) {
      const int s = wv * 2 + i;             // 0..31, 8 rows each -> 256 rows
      gload_lds16(gA + (size_t)(s * 8 + lrow8) * lda + k0 + lcol8, &As[s * 512]);
    }
    gload_lds16(gB + (size_t)(wv * 8 + lrow8) * lda + k0 + lcol8, &Bs[wv * 512]);
    __syncthreads();
    v8bf af[2][2], bf[4][2];
#pragma unroll
    for (int m = 0; m < 2; ++m) {
      const int row = wr * 32 + m * 16 + fr;
      af[m][0] = *(const v8bf*)&As[row * 64 + kof];
      af[m][1] = *(const v8bf*)&As[row * 64 + 32 + kof];
    }
#pragma unroll
    for (int n = 0; n < 4; ++n) {
      const int row = wc * 64 + n * 16 + fr;
      bf[n][0] = *(const v8bf*)&Bs[row * 64 + kof];
      bf[n][1] = *(const v8bf*)&Bs[row * 64 + 32 + kof];
    }
#pragma unroll
    for (int ks = 0; ks < 2; ++ks)
#pragma unroll
      for (int m = 0; m < 2; ++m)
#pragma unroll
        for (int n = 0; n < 4; ++n)
          acc[m][n] = __builtin_amdgcn_mfma_f32_16x16x32_bf16(
              af[m][ks], bf[n][ks], acc[m][n], 0, 0, 0);
  }
  // epilogue: C/D layout col=lane&15, row=(lane>>4)*4+j  [m89/m91]
  const int fq = l >> 4;
#pragma unroll
  for (int m = 0; m < 2; ++m)
#pragma unroll
    for (int n = 0; n < 4; ++n) {
      const int col = tcol + wc * 64 + n * 16 + fr;
      const float bc = add_bias ? bias[col] : 0.f;
#pragma unroll
      for (int j = 0; j < 4; ++j) {
        const int row = trow + wr * 32 + m * 16 + fq * 4 + j;
        const float v = acc[m][n][j] + bc;
        if (EPI == 0) {
          const float sv = v / (1.f + __expf(-v));
          ((unsigned short*)Cout)[(size_t)row * N + col] = f2bf(sv);
        } else {
          ((float*)Cout)[(size_t)row * N + col] = v;
        }
      }
    }
}

// ---------------------------------------------------------------------------
// K2 merged: block 0 = router (16 waves, round-8 logic verbatim);
// blocks 1..128 = fc1 GEMM (256x128 tiles); blocks 129..192 = conv of
// fc2w + adapters. Router overlaps GEMM+conv; all 193 blocks co-resident.
// ---------------------------------------------------------------------------
__device__ __forceinline__ void route_decide(unsigned c, int avail,
                                             unsigned& m, int& dec) {
  unsigned flags = 0;
#pragma unroll
  for (int j = 0; j < 8; ++j) {
    const int e = (c >> (4 * j)) & 15;
    flags |= ((unsigned)(avail >> e) & 1u) << j;
  }
  const int pc = __popc(flags);
  const int sc = pc < 2 ? pc : 2;
  const int j0 = __ffs(flags) - 1;
  const int j1 = __ffs(flags & (flags - 1)) - 1;
  const int r0 = sc > 0 ? j0 : 0;
  const int r1 = sc > 1 ? j1 : 0;
  const int e0 = (c >> (4 * r0)) & 15;
  const int e1 = (c >> (4 * r1)) & 15;
  m = (sc > 0 ? (1u << e0) : 0u) | (sc > 1 ? (1u << e1) : 0u);
  dec = e0 | (e1 << 4) | (r0 << 8) | (r1 << 11) | (sc << 14);
}

__global__ __launch_bounds__(1024, 1) void k2_fc1_route_conv(
    const unsigned short* __restrict__ Azbf,
    const unsigned short* __restrict__ Bfc1wbf,
    const float* __restrict__ fc1b, unsigned short* __restrict__ hprebf,
    const unsigned* __restrict__ cands, const float* __restrict__ cvals,
    const unsigned* __restrict__ argpk, const int* __restrict__ p_cap,
    float* __restrict__ out, int* __restrict__ asgn, float* __restrict__ asgnw,
    const float* __restrict__ fc2w,
    const float* __restrict__ a1, const float* __restrict__ b1,
    const float* __restrict__ a2, const float* __restrict__ b2,
    unsigned short* __restrict__ fc2wbf,
    unsigned short* __restrict__ a1bf, unsigned short* __restrict__ b1bf,
    unsigned short* __restrict__ a2bf, unsigned short* __restrict__ b2bf)
{
  __shared__ __align__(16) unsigned short As[256 * 64];   // 32 KB
  __shared__ __align__(16) unsigned short Bs[128 * 64];   // 16 KB
  __shared__ unsigned long long bal[2][32][17];           // ~8.7 KB
  __shared__ int T[16];
  __shared__ int hitsS;
  const int tid = threadIdx.x;

  if (blockIdx.x >= 129) {
    // conv: 1,310,720 float4s over 64 blocks x 1024 thr = 20 iters
    size_t j = (size_t)(blockIdx.x - 129) * 1024 + tid;
    const size_t stride = (size_t)64 * 1024;
    for (; j < 1310720ull; j += stride) {
      const float* src; unsigned short* dst; size_t off;
      if (j < 524288) { src = fc2w; dst = fc2wbf; off = j; }
      else if (j < 655360) { src = a1; dst = a1bf; off = j - 524288; }
      else if (j < 917504) { src = b1; dst = b1bf; off = j - 655360; }
      else if (j < 1179648) { src = a2; dst = a2bf; off = j - 917504; }
      else { src = b2; dst = b2bf; off = j - 1179648; }
      float4 v = *(const float4*)&src[off * 4];
      ushort4 bv;
      bv.x = f2bf(v.x); bv.y = f2bf(v.y); bv.z = f2bf(v.z); bv.w = f2bf(v.w);
      *(ushort4*)&dst[off * 4] = bv;
    }
    return;
  }
  if (blockIdx.x >= 1) {
    // fc1: [2048,1024] x [2048,1024]^T -> silu -> bf16 h_pre
    gemm_w16<0>(As, Bs, blockIdx.x - 1, Azbf, Bfc1wbf, fc1b, (void*)hprebf,
                HDIM, DDIM, DDIM, 1);
    return;
  }
  // ---- router: 16 waves, wave w owns expert w; 2 barriers/round ----
  const int w = tid >> 6, l = tid & 63;
  if (tid == 0) hitsS = 0;
  const int capl = max(1, p_cap[0]);
  const unsigned cA = cands[tid], cB = cands[tid + 1024];
  const unsigned aA = argpk[tid], aB = argpk[tid + 1024];
  float cvA[8], cvB[8];
#pragma unroll
  for (int q = 0; q < 8; ++q) {
    cvA[q] = cvals[(size_t)tid * 8 + q];
    cvB[q] = cvals[(size_t)(tid + 1024) * 8 + q];
  }
  int avail = 0xFFFF, t0 = 0, capw = 0, hits = 0;

  for (int round = 0; round < 20; ++round) {
    const int p = round & 1;
    unsigned mA = 0, mB = 0;
    int dA = 0, dB = 0;
    if (tid >= t0) route_decide(cA, avail, mA, dA);
    if (tid + 1024 >= t0) route_decide(cB, avail, mB, dB);
    if (w * 64 + 63 >= t0) {
      for (int av = avail; av; av &= av - 1) {
        const int e = __ffs(av) - 1;
        unsigned long long b = __ballot((mA >> e) & 1);
        if (l == e) bal[p][w][l] = b;
      }
    } else if (l < 16) {
      bal[p][w][l] = 0ull;
    }
    {
      for (int av = avail; av; av &= av - 1) {
        const int e = __ffs(av) - 1;
        unsigned long long b = __ballot((mB >> e) & 1);
        if (l == e) bal[p][w + 16][l] = b;
      }
    }
    __syncthreads();                      // barrier 1
    unsigned long long bm = 0;
    int myT = 0x7FFFFFFF;
    const bool eav = (avail >> w) & 1;
    if (eav) {
      int cnt = 0;
      if (l < 32) { bm = bal[p][l][w]; cnt = __popcll(bm); }
      int tot = cnt;
#pragma unroll
      for (int o = 32; o; o >>= 1) tot += __shfl_xor(tot, o, 64);
      const int rem = capl - capw;
      if (tot >= rem) {
        int incl = cnt;
#pragma unroll
        for (int o = 1; o < 32; o <<= 1) {
          int u = __shfl_up(incl, o, 64);
          if (l >= o) incl += u;
        }
        if (l < 32) {
          const int need = rem - (incl - cnt);
          if (need >= 1 && need <= cnt) {
            unsigned long long bb = bm;
            for (int i = 1; i < need; ++i) bb &= bb - 1;
            myT = l * 64 + (__ffsll((unsigned long long)bb) - 1);
          }
        }
#pragma unroll
        for (int o = 32; o; o >>= 1) myT = min(myT, __shfl_xor(myT, o, 64));
      }
    }
    if (l == 0) T[w] = myT;
    __syncthreads();                      // barrier 2
    const int tv = (l < 16) ? T[l] : 0x7FFFFFFF;
    int ts = tv;
#pragma unroll
    for (int o = 32; o; o >>= 1) ts = min(ts, __shfl_xor(ts, o, 64));
    const bool done = (ts == 0x7FFFFFFF);
    const int tfin = done ? (NTOK - 1) : ts;
    unsigned long long crossed = __ballot((l < 16) && !done && (tv == ts));
    if (eav) {
      int c2 = 0;
      if (l < 32) {
        const int hi = tfin - l * 64;
        unsigned long long mk =
            (hi < 0) ? 0ull : (hi >= 63 ? ~0ull : ((1ull << (hi + 1)) - 1ull));
        c2 = __popcll(bm & mk);
      }
#pragma unroll
      for (int o = 32; o; o >>= 1) c2 += __shfl_xor(c2, o, 64);
      capw += c2;
    }
    {
      const int t = tid;
      if (t >= t0 && t <= tfin) {
        const int e0 = dA & 15, e1 = (dA >> 4) & 15;
        const int r0 = (dA >> 8) & 7, r1 = (dA >> 11) & 7, sc = (dA >> 14) & 3;
        const int a0 = (aA >> (2 * e0)) & 3, a1i = (aA >> (2 * e1)) & 3;
        float w0 = 0.f, w1v = 0.f;
#pragma unroll
        for (int q = 0; q < 8; ++q) {
          if (q == r0) w0 = cvA[q];
          if (q == r1) w1v = cvA[q];
        }
        asgn[t] = e0 | (e1 << 4) | (a0 << 8) | (a1i << 10) | (sc << 12);
        asgnw[t * 2 + 0] = sc > 0 ? w0 : 0.f;
        asgnw[t * 2 + 1] = sc > 1 ? w1v : 0.f;
        hits += (sc > 0 && r0 > 0) + (sc > 1 && r1 > 0);
      }
    }
    {
      const int t = tid + 1024;
      if (t >= t0 && t <= tfin) {
        const int e0 = dB & 15, e1 = (dB >> 4) & 15;
        const int r0 = (dB >> 8) & 7, r1 = (dB >> 11) & 7, sc = (dB >> 14) & 3;
        const int a0 = (aB >> (2 * e0)) & 3, a1i = (aB >> (2 * e1)) & 3;
        float w0 = 0.f, w1v = 0.f;
#pragma unroll
        for (int q = 0; q < 8; ++q) {
          if (q == r0) w0 = cvB[q];
          if (q == r1) w1v = cvB[q];
        }
        asgn[t] = e0 | (e1 << 4) | (a0 << 8) | (a1i << 10) | (sc << 12);
        asgnw[t * 2 + 0] = sc > 0 ? w0 : 0.f;
        asgnw[t * 2 + 1] = sc > 1 ? w1v : 0.f;
        hits += (sc > 0 && r0 > 0) + (sc > 1 && r1 > 0);
      }
    }
    avail &= ~(int)(unsigned)(crossed & 0xFFFFull);
    t0 = tfin + 1;
    if (done) break;
  }
#pragma unroll
  for (int o = 32; o; o >>= 1) hits += __shfl_xor(hits, o, 64);
  if (l == 0) atomicAdd(&hitsS, hits);
  __syncthreads();
  if (tid == 0) out[O_HIT] = (float)hitsS / (float)(NTOK * 2);
}

// ---------------------------------------------------------------------------
// 256-thr 4-wave GEMM body (verified) — used by fc2.
// ---------------------------------------------------------------------------
template <int EPI>
__device__ __forceinline__ void gemm_body(
    unsigned short* As, unsigned short* Bs, int bid,
    const unsigned short* __restrict__ A, const unsigned short* __restrict__ Bm,
    const float* __restrict__ bias, void* __restrict__ Cout,
    int M, int N, int Kloop, int lda, int add_bias)
{
  const int tid = threadIdx.x;
  const int wv = tid >> 6, l = tid & 63;
  const int ntile = N >> 7;
  const int trow = (bid / ntile) << 7;
  const int tcol = (bid % ntile) << 7;
  const int wr = wv >> 1, wc = wv & 1;
  v4f acc[4][4];
#pragma unroll
  for (int m = 0; m < 4; ++m)
#pragma unroll
    for (int n = 0; n < 4; ++n) acc[m][n] = (v4f){0.f, 0.f, 0.f, 0.f};

  const int lrow8 = l >> 3;
  const int lcol8 = (l & 7) << 3;
  const unsigned short* gA = A + (size_t)trow * lda;
  const unsigned short* gB = Bm + (size_t)tcol * lda;
  const int fr = l & 15, kof = (l >> 4) << 3;

  for (int k0 = 0; k0 < Kloop; k0 += 64) {
    __syncthreads();
#pragma unroll
    for (int i = 0; i < 4; ++i) {
      const int s = (wv << 2) + i;
      gload_lds16(gA + (size_t)(s * 8 + lrow8) * lda + k0 + lcol8, &As[s * 512]);
      gload_lds16(gB + (size_t)(s * 8 + lrow8) * lda + k0 + lcol8, &Bs[s * 512]);
    }
    __syncthreads();
    v8bf af[4][2], bf[4][2];
#pragma unroll
    for (int m = 0; m < 4; ++m) {
      const int row = wr * 64 + m * 16 + fr;
      af[m][0] = *(const v8bf*)&As[row * 64 + kof];
      af[m][1] = *(const v8bf*)&As[row * 64 + 32 + kof];
    }
#pragma unroll
    for (int n = 0; n < 4; ++n) {
      const int row = wc * 64 + n * 16 + fr;
      bf[n][0] = *(const v8bf*)&Bs[row * 64 + kof];
      bf[n][1] = *(const v8bf*)&Bs[row * 64 + 32 + kof];
    }
#pragma unroll
    for (int ks = 0; ks < 2; ++ks)
#pragma unroll
      for (int m = 0; m < 4; ++m)
#pragma unroll
        for (int n = 0; n < 4; ++n)
          acc[m][n] = __builtin_amdgcn_mfma_f32_16x16x32_bf16(
              af[m][ks], bf[n][ks], acc[m][n], 0, 0, 0);
  }
  const int fq = l >> 4;
#pragma unroll
  for (int m = 0; m < 4; ++m)
#pragma unroll
    for (int n = 0; n < 4; ++n) {
      const int col = tcol + wc * 64 + n * 16 + fr;
      const float bc = add_bias ? bias[col] : 0.f;
#pragma unroll
      for (int j = 0; j < 4; ++j) {
        const int row = trow + wr * 64 + m * 16 + fq * 4 + j;
        const float v = acc[m][n][j] + bc;
        if (EPI == 0) {
          const float sv = v / (1.f + __expf(-v));
          ((unsigned short*)Cout)[(size_t)row * N + col] = f2bf(sv);
        } else {
          ((float*)Cout)[(size_t)row * N + col] = v;
        }
      }
    }
}

// fc2 split-K x2: blocks [0,128) = K-half 0 (+bias) -> C0; [128,256) -> C1
__global__ __launch_bounds__(256) void gemm_bt1s(
    const unsigned short* __restrict__ A, const unsigned short* __restrict__ Bm,
    const float* __restrict__ bias, float* __restrict__ C0,
    float* __restrict__ C1)
{
  __shared__ __align__(16) char smem[32768];
  const int ntiles = (NTOK / 128) * (DDIM / 128);   // 128
  const int half = blockIdx.x / ntiles;
  const int tile = blockIdx.x % ntiles;
  gemm_body<1>((unsigned short*)smem, (unsigned short*)smem + 8192,
               tile, A + half * 1024, Bm + half * 1024, bias,
               half ? (void*)C1 : (void*)C0,
               NTOK, DDIM, 1024, HDIM, half == 0);
}

__global__ __launch_bounds__(256) void gemm_bt1f(
    const unsigned short* __restrict__ A, const unsigned short* __restrict__ Bm,
    const float* __restrict__ bias, void* __restrict__ Cout,
    int M, int N, int K)
{
  __shared__ __align__(16) char smem[32768];
  gemm_body<1>((unsigned short*)smem, (unsigned short*)smem + 8192,
               blockIdx.x, A, Bm, bias, Cout, M, N, K, K, 1);
}

// ---------------------------------------------------------------------------
// K5: per-token LoRA adapters + final combine + bulk routing outputs.
// Slot-parallel: half-block (128 thr) per expert-slot.
// ---------------------------------------------------------------------------
__global__ __launch_bounds__(256) void k5_lora(
    const float* __restrict__ z, const unsigned short* __restrict__ hpre,
    const float* __restrict__ outpre, const float* __restrict__ outpre2,
    int use2, const int* __restrict__ asgn, const float* __restrict__ asgnw,
    const unsigned short* __restrict__ a1, const unsigned short* __restrict__ b1,
    const unsigned short* __restrict__ a2, const unsigned short* __restrict__ b2,
    float* __restrict__ out0, float* __restrict__ out)
{
  __shared__ float zl[DDIM];            // 4 KB
  __shared__ float hl[2][HDIM];         // 16 KB
  __shared__ float d2a[2][DDIM];        // 8 KB
  __shared__ float t1s[2][8], t2s[2][8];
  const int b = blockIdx.x, tid = threadIdx.x;
  {
    float4 v = *(const float4*)&z[(size_t)b * DDIM + tid * 4];
    *(float4*)&zl[tid * 4] = v;
  }
#pragma unroll
  for (int j = 0; j < 8; ++j) ((float*)d2a)[tid + 256 * j] = 0.f;
  const int pk = asgn[b];
  const int sc = (pk >> 12) & 3;
  const int eA0 = pk & 15, eA1 = (pk >> 4) & 15;
  const int aA0 = (pk >> 8) & 3, aA1 = (pk >> 10) & 3;
  const float w0 = asgnw[b * 2 + 0], w1 = asgnw[b * 2 + 1];
  if (tid < 16)
    out[O_USED + (size_t)b * 16 + tid] =
        (float)((sc > 0 && tid == eA0) || (sc > 1 && tid == eA1));
  if (tid == 0) {
    out[O_AIDX + (size_t)b * 2 + 0] = sc > 0 ? (float)eA0 : -1.f;
    out[O_AIDX + (size_t)b * 2 + 1] = sc > 1 ? (float)eA1 : -1.f;
    out[O_AW + (size_t)b * 2 + 0] = w0;
    out[O_AW + (size_t)b * 2 + 1] = w1;
    out[O_EVE + b] = sc > 0 ? (float)eA0 : -1.f;
    out[O_EVE + NTOK + b] = sc > 1 ? (float)eA1 : -1.f;
    out[O_EVA + b] = sc > 0 ? (float)aA0 : -1.f;
    out[O_EVA + NTOK + b] = sc > 1 ? (float)aA1 : -1.f;
  }
  const int half = tid >> 7;
  const int ht = tid & 127;
  const int r4 = ht >> 5, l5 = ht & 31;
  const bool valid = half < sc;
  const float ww = half ? w1 : w0;
  const int ad = (half ? eA1 : eA0) * 4 + (half ? aA1 : aA0);
  const float4* zg = (const float4*)&z[(size_t)b * DDIM];
  __syncthreads();

  if (valid) {
#pragma unroll
    for (int rr = r4; rr < 8; rr += 4) {
      const us8v* pa1 = (const us8v*)(a1 + ((size_t)ad * 8 + rr) * DDIM);
      float sa = 0.f;
#pragma unroll
      for (int i = 0; i < 4; ++i) {
        const int g = l5 + 32 * i;
        us8v va = pa1[g];
        float4 z0 = zg[g * 2], z1 = zg[g * 2 + 1];
        sa += z0.x * bf2f(va[0]) + z0.y * bf2f(va[1]) +
              z0.z * bf2f(va[2]) + z0.w * bf2f(va[3]) +
              z1.x * bf2f(va[4]) + z1.y * bf2f(va[5]) +
              z1.z * bf2f(va[6]) + z1.w * bf2f(va[7]);
      }
#pragma unroll
      for (int o = 16; o; o >>= 1) sa += __shfl_xor(sa, o, 64);
      if (l5 == 0) t1s[half][rr] = sa;
    }
  }
  __syncthreads();
  if (valid) {
    float t1r[8];
#pragma unroll
    for (int q = 0; q < 8; ++q) t1r[q] = t1s[half][q];
    const unsigned short* pb1 = b1 + (size_t)ad * HDIM * 8;
    const unsigned short* ph = hpre + (size_t)b * HDIM;
#pragma unroll
    for (int j = 0; j < 16; ++j) {
      const int hh_i = ht + 128 * j;
      us8v row = *(const us8v*)&pb1[(size_t)hh_i * 8];
      float d1 = 0.f;
#pragma unroll
      for (int q = 0; q < 8; ++q) d1 += t1r[q] * bf2f(row[q]);
      const float hh = bf2f(ph[hh_i]) + d1;  // SCALE = 1
      hl[half][hh_i] = hh / (1.f + __expf(-hh));
    }
  }
  __syncthreads();
  if (valid) {
#pragma unroll
    for (int rr = r4; rr < 8; rr += 4) {
      const us8v* pa2 = (const us8v*)(a2 + ((size_t)ad * 8 + rr) * HDIM);
      float sa = 0.f;
#pragma unroll
      for (int i = 0; i < 8; ++i) {
        const int g = l5 + 32 * i;
        us8v va = pa2[g];
        const float* hp = &hl[half][g * 8];
        sa += hp[0] * bf2f(va[0]) + hp[1] * bf2f(va[1]) +
              hp[2] * bf2f(va[2]) + hp[3] * bf2f(va[3]) +
              hp[4] * bf2f(va[4]) + hp[5] * bf2f(va[5]) +
              hp[6] * bf2f(va[6]) + hp[7] * bf2f(va[7]);
      }
#pragma unroll
      for (int o = 16; o; o >>= 1) sa += __shfl_xor(sa, o, 64);
      if (l5 == 0) t2s[half][rr] = sa;
    }
  }
  __syncthreads();
  if (valid) {
    float t2r[8];
#pragma unroll
    for (int q = 0; q < 8; ++q) t2r[q] = t2s[half][q];
    const unsigned short* pb2 = b2 + (size_t)ad * DDIM * 8;
#pragma unroll
    for (int j = 0; j < 8; ++j) {
      const int d = ht + 128 * j;
      us8v row = *(const us8v*)&pb2[(size_t)d * 8];
      float d2 = 0.f;
#pragma unroll
      for (int q = 0; q < 8; ++q) d2 += t2r[q] * bf2f(row[q]);
      d2a[half][d] = ww * d2;  // SCALE = 1
    }
  }
  __syncthreads();
  const float wsum = (sc > 0 ? w0 : 0.f) + (sc > 1 ? w1 : 0.f);
#pragma unroll
  for (int j = 0; j < 4; ++j) {
    const int d = tid + 256 * j;
    float op = outpre[(size_t)b * DDIM + d];
    if (use2) op += outpre2[(size_t)b * DDIM + d];
    out0[(size_t)b * DDIM + d] = zl[d] + wsum * op + d2a[0][d] + d2a[1][d];
  }
}

// ---------------------------------------------------------------------------
extern "C" void kernel_launch(void* const* d_in, const int* in_sizes, int n_in,
                              void* d_out, int out_size, void* d_ws, size_t ws_size,
                              hipStream_t stream)
{
  (void)in_sizes; (void)n_in; (void)out_size;
  const float* z     = (const float*)d_in[0];
  const int*   p_cap = (const int*)d_in[2];
  const int*   p_ban = (const int*)d_in[3];
  const float* p_tau = (const float*)d_in[4];
  const float* p_eps = (const float*)d_in[5];
  const float* fc1w  = (const float*)d_in[6];
  const float* fc1b  = (const float*)d_in[7];
  const float* fc2w  = (const float*)d_in[8];
  const float* fc2b  = (const float*)d_in[9];
  const float* proto = (const float*)d_in[10];
  const float* ak    = (const float*)d_in[11];
  const float* ebias = (const float*)d_in[12];
  const float* a1    = (const float*)d_in[13];
  const float* b1    = (const float*)d_in[14];
  const float* a2    = (const float*)d_in[15];
  const float* b2    = (const float*)d_in[16];
  float* out = (float*)d_out;
  char* ws = (char*)d_ws;

  unsigned short* zbf    = (unsigned short*)(ws + WS_ZBF);
  unsigned short* fc1wbf = (unsigned short*)(ws + WS_FC1WBF);
  unsigned short* fc2wbf = (unsigned short*)(ws + WS_FC2WBF);
  unsigned short* hprebf = (unsigned short*)(ws + WS_HPREBF);
  float*          outpre = (float*)(ws + WS_OUTPRE);
  unsigned short* a1bf   = (unsigned short*)(ws + WS_A1BF);
  unsigned short* b1bf   = (unsigned short*)(ws + WS_B1BF);
  unsigned short* a2bf   = (unsigned short*)(ws + WS_A2BF);
  unsigned short* b2bf   = (unsigned short*)(ws + WS_B2BF);
  unsigned*       cands  = (unsigned*)(ws + WS_CANDS);
  float*          cvals  = (float*)(ws + WS_CVALS);
  unsigned*       argpk  = (unsigned*)(ws + WS_ARGPK);
  int*            asgn   = (int*)(ws + WS_ASGN);
  float*          asgnw  = (float*)(ws + WS_ASGNW);
  float*          outpr2 = (float*)(ws + WS_OUTPR2);
  const int splitk = (ws_size >= WS_TOTAL2) ? 1 : 0;

  k1_scores<<<512, 256, 0, stream>>>(
      z, proto, ebias, ak, p_tau, p_eps, p_ban, zbf, out, cands, cvals, argpk,
      fc1w, fc1wbf);

  // merged: router (block 0) + fc1 GEMM (128 tiles) + conv (64 blocks)
  k2_fc1_route_conv<<<193, 1024, 0, stream>>>(
      zbf, fc1wbf, fc1b, hprebf,
      cands, cvals, argpk, p_cap, out, asgn, asgnw,
      fc2w, a1, b1, a2, b2, fc2wbf, a1bf, b1bf, a2bf, b2bf);

  // fc2: [2048,2048] x [1024,2048]^T -> +bias -> f32 out_pre (split-K x2)
  if (splitk) {
    gemm_bt1s<<<2 * (NTOK / 128) * (DDIM / 128), 256, 0, stream>>>(
        hprebf, fc2wbf, fc2b, outpre, outpr2);
  } else {
    gemm_bt1f<<<(NTOK / 128) * (DDIM / 128), 256, 0, stream>>>(
        hprebf, fc2wbf, fc2b, (void*)outpre, NTOK, DDIM, HDIM);
  }

  k5_lora<<<NTOK, 256, 0, stream>>>(
      z, hprebf, outpre, outpr2, splitk, asgn, asgnw,
      a1bf, b1bf, a2bf, b2bf, out, out);
}